// Round 3
// baseline (622.953 us; speedup 1.0000x reference)
//
#include <hip/hip_runtime.h>

constexpr int N_NODES = 100000;
constexpr int E_EDGES = 3200000;
constexpr int F_IN    = 256;
constexpr int HID     = 32;
constexpr int NCLS    = 10;

// ---------------------------------------------------------------------------
// edge_index dtype hedge: reference says int64, harness convention says int32.
// If data is little-endian int64 with values < 2^31, every odd 32-bit word is 0.
// ---------------------------------------------------------------------------
__global__ void k_detect_idx64(const int* __restrict__ ei32, int* __restrict__ flag) {
    __shared__ int nz;
    if (threadIdx.x == 0) nz = 0;
    __syncthreads();
    int acc = 0;
    for (int i = threadIdx.x; i < 1024; i += 256) {
        acc |= ei32[2 * i + 1];           // odd words of first 1024 pairs
    }
    if (acc != 0) atomicOr(&nz, 1);
    __syncthreads();
    if (threadIdx.x == 0) flag[0] = (nz == 0) ? 1 : 0;   // 1 => int64 storage
}

__device__ __forceinline__ int load_idx(const void* ei, long long i, int is64) {
    if (is64) return (int)((const long long*)ei)[i];
    return ((const int*)ei)[i];
}

// ---------------------------------------------------------------------------
// degree kernels
// ---------------------------------------------------------------------------
__global__ void k_deg_init(float* __restrict__ deg) {
    int i = blockIdx.x * 256 + threadIdx.x;
    if (i < N_NODES) deg[i] = 1.0f;       // self-loop
}

__global__ void k_deg_count(const void* __restrict__ ei, const int* __restrict__ flag,
                            float* __restrict__ deg) {
    int i = blockIdx.x * 256 + threadIdx.x;
    if (i >= E_EDGES) return;
    int is64 = flag[0];
    int c = load_idx(ei, (long long)E_EDGES + i, is64);   // col = targets
    atomicAdd(&deg[c], 1.0f);
}

__global__ void k_deg_rsqrt(float* __restrict__ deg) {
    int i = blockIdx.x * 256 + threadIdx.x;
    if (i < N_NODES) deg[i] = rsqrtf(deg[i]);
}

// ---------------------------------------------------------------------------
// h = feature @ W1 ; hs = h * dinv ; agg = b1 + hs * dinv  (self-loop term)
// block: 256 threads = 8 nodes x 32 hid
// ---------------------------------------------------------------------------
__global__ __launch_bounds__(256) void k_h(const float* __restrict__ feat,
                                           const float* __restrict__ W1,
                                           const float* __restrict__ b1,
                                           const float* __restrict__ dinv,
                                           float* __restrict__ hs,
                                           float* __restrict__ agg) {
    __shared__ float W1s[F_IN * HID];     // 32 KB, layout [k][j]
    __shared__ float fs[8][F_IN];         // 8 KB

    int tid = threadIdx.x;

    // stage W1 (8192 floats = 2048 float4)
    {
        const float4* W1v  = (const float4*)W1;
        float4*       W1sv = (float4*)W1s;
        #pragma unroll
        for (int i = 0; i < 8; i++) W1sv[tid + 256 * i] = W1v[tid + 256 * i];
    }
    // stage 8 feature rows (2048 floats = 512 float4), fully coalesced
    int nodeBase = blockIdx.x * 8;
    {
        const float4* fv  = (const float4*)(feat + (size_t)nodeBase * F_IN);
        float4*       fsv = (float4*)fs;
        fsv[tid]       = fv[tid];
        fsv[tid + 256] = fv[tid + 256];
    }
    __syncthreads();

    int nl = tid >> 5;     // local node 0..7
    int j  = tid & 31;     // hid index

    const float4* frow = (const float4*)(&fs[nl][0]);
    float acc = 0.f;
    #pragma unroll 4
    for (int k4 = 0; k4 < F_IN / 4; k4++) {
        float4 f = frow[k4];               // broadcast within 32-lane group
        int kb = k4 * 4;
        acc = fmaf(f.x, W1s[(kb + 0) * HID + j], acc);
        acc = fmaf(f.y, W1s[(kb + 1) * HID + j], acc);
        acc = fmaf(f.z, W1s[(kb + 2) * HID + j], acc);
        acc = fmaf(f.w, W1s[(kb + 3) * HID + j], acc);
    }

    int node = nodeBase + nl;
    float di = dinv[node];
    float hsv = acc * di;
    hs[node * HID + j]  = hsv;
    agg[node * HID + j] = b1[j] + hsv * di;   // bias + self-loop contribution
}

// ---------------------------------------------------------------------------
// edge scatter: agg[col] += hs[row] * dinv[col]   (32 lanes per edge)
// ---------------------------------------------------------------------------
__global__ __launch_bounds__(256) void k_edge(const void* __restrict__ ei,
                                              const int* __restrict__ flag,
                                              const float* __restrict__ hs,
                                              const float* __restrict__ dinv,
                                              float* __restrict__ agg) {
    long long t = (long long)blockIdx.x * 256 + threadIdx.x;
    int e = (int)(t >> 5);
    if (e >= E_EDGES) return;
    int j = (int)(t & 31);
    int is64 = flag[0];
    int r = load_idx(ei, e, is64);
    int c = load_idx(ei, (long long)E_EDGES + e, is64);
    float v = hs[r * HID + j] * dinv[c];
    atomicAdd(&agg[c * HID + j], v);
}

// ---------------------------------------------------------------------------
// out = log_softmax(relu(agg) @ W2 + b2)
// ---------------------------------------------------------------------------
__global__ __launch_bounds__(256) void k_out(const float* __restrict__ agg,
                                             const float* __restrict__ W2,
                                             const float* __restrict__ b2,
                                             float* __restrict__ out) {
    __shared__ float W2s[HID * NCLS];   // [k][c], 320 floats
    __shared__ float b2s[NCLS];
    int tid = threadIdx.x;
    // BUGFIX (round 2): HID*NCLS = 320 > blockDim = 256; the old single-pass
    // `if (tid < 320)` left W2s[256..319] uninitialized -> absmax 0.52.
    for (int i = tid; i < HID * NCLS; i += 256) W2s[i] = W2[i];
    if (tid < NCLS) b2s[tid] = b2[tid];
    __syncthreads();

    int node = blockIdx.x * 256 + tid;
    if (node >= N_NODES) return;

    float a[HID];
    const float4* av = (const float4*)(agg + (size_t)node * HID);
    #pragma unroll
    for (int q = 0; q < HID / 4; q++) {
        float4 v = av[q];
        a[q * 4 + 0] = fmaxf(v.x, 0.f);
        a[q * 4 + 1] = fmaxf(v.y, 0.f);
        a[q * 4 + 2] = fmaxf(v.z, 0.f);
        a[q * 4 + 3] = fmaxf(v.w, 0.f);
    }

    float logits[NCLS];
    #pragma unroll
    for (int c = 0; c < NCLS; c++) {
        float s = b2s[c];
        #pragma unroll
        for (int k = 0; k < HID; k++) s = fmaf(a[k], W2s[k * NCLS + c], s);
        logits[c] = s;
    }

    float m = logits[0];
    #pragma unroll
    for (int c = 1; c < NCLS; c++) m = fmaxf(m, logits[c]);
    float se = 0.f;
    #pragma unroll
    for (int c = 0; c < NCLS; c++) se += expf(logits[c] - m);
    float lse = m + logf(se);
    #pragma unroll
    for (int c = 0; c < NCLS; c++) out[node * NCLS + c] = logits[c] - lse;
}

// ---------------------------------------------------------------------------
extern "C" void kernel_launch(void* const* d_in, const int* in_sizes, int n_in,
                              void* d_out, int out_size, void* d_ws, size_t ws_size,
                              hipStream_t stream) {
    const float* feat = (const float*)d_in[0];
    const void*  ei   = d_in[1];
    const float* W1   = (const float*)d_in[2];
    const float* b1   = (const float*)d_in[3];
    const float* W2   = (const float*)d_in[4];
    const float* b2   = (const float*)d_in[5];
    float* out = (float*)d_out;

    char* ws = (char*)d_ws;
    // layout: [flag: 64B][deg/dinv: 400KB -> 512KB][hs: 12.8MB][agg: 12.8MB]
    int*   flag = (int*)ws;
    float* deg  = (float*)(ws + 1024);
    float* hs   = (float*)(ws + 1024 + (512u << 10));
    float* agg  = (float*)(ws + 1024 + (512u << 10) + (13u << 20));

    k_detect_idx64<<<1, 256, 0, stream>>>((const int*)ei, flag);
    k_deg_init<<<(N_NODES + 255) / 256, 256, 0, stream>>>(deg);
    k_deg_count<<<(E_EDGES + 255) / 256, 256, 0, stream>>>(ei, flag, deg);
    k_deg_rsqrt<<<(N_NODES + 255) / 256, 256, 0, stream>>>(deg);
    k_h<<<N_NODES / 8, 256, 0, stream>>>(feat, W1, b1, deg, hs, agg);

    long long tot = (long long)E_EDGES * 32;
    k_edge<<<(int)((tot + 255) / 256), 256, 0, stream>>>(ei, flag, hs, deg, agg);

    k_out<<<(N_NODES + 255) / 256, 256, 0, stream>>>(agg, W2, b2, out);
}

// Round 5
// 537.566 us; speedup vs baseline: 1.1588x; 1.1588x over previous
//
#include <hip/hip_runtime.h>

constexpr int N_NODES = 100000;
constexpr int E_EDGES = 3200000;
constexpr int F_IN    = 256;
constexpr int HID     = 32;
constexpr int NCLS    = 10;

// ---------------- ws layout (byte offsets) ----------------
// flag   @ 0        (int)
// cnt    @ 1MB      (N int)     in-degree (no self-loop)
// off    @ 2MB      (N int)     CSR row starts
// cursor @ 3MB      (N int)     scatter cursors (init = off)
// bsum   @ 4MB      (4096 int)  block sums for scan
// dinv   @ 5MB      (N float)
// csr    @ 6MB      (E int)     source node per CSR slot
// hs     @ 20MB     (N*32 f)    h * dinv[row]
// agg    @ 33MB     (N*32 f)
constexpr size_t OFF_FLAG   = 0;
constexpr size_t OFF_CNT    = 1u << 20;
constexpr size_t OFF_OFF    = 2u << 20;
constexpr size_t OFF_CURSOR = 3u << 20;
constexpr size_t OFF_BSUM   = 4u << 20;
constexpr size_t OFF_DINV   = 5u << 20;
constexpr size_t OFF_CSR    = 6u << 20;
constexpr size_t OFF_HS     = 20u << 20;
constexpr size_t OFF_AGG    = 33u << 20;

// ---------------------------------------------------------------------------
// edge_index dtype hedge: int64 storage has all-zero odd 32-bit words.
// ---------------------------------------------------------------------------
__global__ void k_detect_idx64(const int* __restrict__ ei32, int* __restrict__ flag) {
    __shared__ int nz;
    if (threadIdx.x == 0) nz = 0;
    __syncthreads();
    int acc = 0;
    for (int i = threadIdx.x; i < 1024; i += 256) acc |= ei32[2 * i + 1];
    if (acc != 0) atomicOr(&nz, 1);
    __syncthreads();
    if (threadIdx.x == 0) flag[0] = (nz == 0) ? 1 : 0;   // 1 => int64 storage
}

__device__ __forceinline__ int load_idx(const void* ei, long long i, int is64) {
    if (is64) return (int)((const long long*)ei)[i];
    return ((const int*)ei)[i];
}

// ---------------------------------------------------------------------------
// CSR build
// ---------------------------------------------------------------------------
__global__ void k_zero_cnt(int* __restrict__ cnt) {
    int i = blockIdx.x * 256 + threadIdx.x;
    if (i < N_NODES) cnt[i] = 0;
}

__global__ void k_hist(const void* __restrict__ ei, const int* __restrict__ flag,
                       int* __restrict__ cnt) {
    int i = blockIdx.x * 256 + threadIdx.x;
    if (i >= E_EDGES) return;
    int is64 = flag[0];
    int c = load_idx(ei, (long long)E_EDGES + i, is64);   // target
    atomicAdd(&cnt[c], 1);
}

__global__ __launch_bounds__(256) void k_scan1(const int* __restrict__ cnt,
                                               int* __restrict__ off,
                                               int* __restrict__ bsum) {
    __shared__ int s[256];
    int tid = threadIdx.x;
    int i = blockIdx.x * 256 + tid;
    int v = (i < N_NODES) ? cnt[i] : 0;
    s[tid] = v;
    __syncthreads();
    for (int d = 1; d < 256; d <<= 1) {
        int t = (tid >= d) ? s[tid - d] : 0;
        __syncthreads();
        s[tid] += t;
        __syncthreads();
    }
    if (i < N_NODES) off[i] = s[tid] - v;       // exclusive, local
    if (tid == 255) bsum[blockIdx.x] = s[255];  // block total
}

__global__ __launch_bounds__(512) void k_scan2(int* __restrict__ bsum, int nb) {
    __shared__ int s[512];
    int tid = threadIdx.x;
    int v = (tid < nb) ? bsum[tid] : 0;
    s[tid] = v;
    __syncthreads();
    for (int d = 1; d < 512; d <<= 1) {
        int t = (tid >= d) ? s[tid - d] : 0;
        __syncthreads();
        s[tid] += t;
        __syncthreads();
    }
    if (tid < nb) bsum[tid] = s[tid] - v;       // exclusive block base
}

__global__ void k_scan3(const int* __restrict__ cnt, int* __restrict__ off,
                        int* __restrict__ cursor, const int* __restrict__ bsum,
                        float* __restrict__ dinv) {
    int i = blockIdx.x * 256 + threadIdx.x;
    if (i >= N_NODES) return;
    int o = off[i] + bsum[blockIdx.x];
    off[i]    = o;
    cursor[i] = o;
    dinv[i]   = rsqrtf((float)(cnt[i] + 1));    // +1 self-loop
}

__global__ void k_scatter(const void* __restrict__ ei, const int* __restrict__ flag,
                          int* __restrict__ cursor, int* __restrict__ csr) {
    int i = blockIdx.x * 256 + threadIdx.x;
    if (i >= E_EDGES) return;
    int is64 = flag[0];
    int r = load_idx(ei, i, is64);
    int c = load_idx(ei, (long long)E_EDGES + i, is64);
    int pos = atomicAdd(&cursor[c], 1);
    csr[pos] = r;
}

// ---------------------------------------------------------------------------
// h = feature @ W1 ; hs = h*dinv ; agg = b1 + hs*dinv  (self-loop + bias)
// Register tile: 256 threads, each computes 4 nodes x 4 cols.
// jq = tid&7 -> cols jq*4..jq*4+3 ; ng = tid>>3 -> nodes base + ng*4 (128/block)
// ---------------------------------------------------------------------------
__global__ __launch_bounds__(256) void k_h(const float* __restrict__ feat,
                                           const float* __restrict__ W1,
                                           const float* __restrict__ b1,
                                           const float* __restrict__ dinv,
                                           float* __restrict__ hs,
                                           float* __restrict__ agg) {
    __shared__ float4 W1s4[F_IN * HID / 4];   // 32 KB, float4 = W1[k][jq*4..+3]
    int tid = threadIdx.x;
    {
        const float4* W1g = (const float4*)W1;
        for (int i = tid; i < F_IN * HID / 4; i += 256) W1s4[i] = W1g[i];
    }
    __syncthreads();

    int jq = tid & 7;
    int ng = tid >> 3;
    int n0 = blockIdx.x * 128 + ng * 4;

    int nc0 = min(n0 + 0, N_NODES - 1);
    int nc1 = min(n0 + 1, N_NODES - 1);
    int nc2 = min(n0 + 2, N_NODES - 1);
    int nc3 = min(n0 + 3, N_NODES - 1);

    const float4* f4 = (const float4*)feat;
    float4 a0 = {0,0,0,0}, a1 = {0,0,0,0}, a2 = {0,0,0,0}, a3 = {0,0,0,0};

    #pragma unroll 4
    for (int k4 = 0; k4 < F_IN / 4; k4++) {
        float4 w0 = W1s4[(k4 * 4 + 0) * 8 + jq];
        float4 w1 = W1s4[(k4 * 4 + 1) * 8 + jq];
        float4 w2 = W1s4[(k4 * 4 + 2) * 8 + jq];
        float4 w3 = W1s4[(k4 * 4 + 3) * 8 + jq];
        float4 f0 = f4[(size_t)nc0 * (F_IN / 4) + k4];
        float4 f1 = f4[(size_t)nc1 * (F_IN / 4) + k4];
        float4 f2 = f4[(size_t)nc2 * (F_IN / 4) + k4];
        float4 f3 = f4[(size_t)nc3 * (F_IN / 4) + k4];

        #define ACC(A, F) \
            A.x = fmaf(F.x, w0.x, A.x); A.y = fmaf(F.x, w0.y, A.y); \
            A.z = fmaf(F.x, w0.z, A.z); A.w = fmaf(F.x, w0.w, A.w); \
            A.x = fmaf(F.y, w1.x, A.x); A.y = fmaf(F.y, w1.y, A.y); \
            A.z = fmaf(F.y, w1.z, A.z); A.w = fmaf(F.y, w1.w, A.w); \
            A.x = fmaf(F.z, w2.x, A.x); A.y = fmaf(F.z, w2.y, A.y); \
            A.z = fmaf(F.z, w2.z, A.z); A.w = fmaf(F.z, w2.w, A.w); \
            A.x = fmaf(F.w, w3.x, A.x); A.y = fmaf(F.w, w3.y, A.y); \
            A.z = fmaf(F.w, w3.z, A.z); A.w = fmaf(F.w, w3.w, A.w);
        ACC(a0, f0) ACC(a1, f1) ACC(a2, f2) ACC(a3, f3)
        #undef ACC
    }

    float4 b1v = *(const float4*)(b1 + jq * 4);
    float4* hs4  = (float4*)hs;
    float4* agg4 = (float4*)agg;

    #define EMIT(A, M) { int n = n0 + M; if (n < N_NODES) {                  \
        float di = dinv[n];                                                  \
        float4 h; h.x = A.x * di; h.y = A.y * di; h.z = A.z * di; h.w = A.w * di; \
        hs4[(size_t)n * 8 + jq] = h;                                         \
        float4 o; o.x = b1v.x + h.x * di; o.y = b1v.y + h.y * di;            \
        o.z = b1v.z + h.z * di; o.w = b1v.w + h.w * di;                      \
        agg4[(size_t)n * 8 + jq] = o; } }
    EMIT(a0, 0) EMIT(a1, 1) EMIT(a2, 2) EMIT(a3, 3)
    #undef EMIT
}

// ---------------------------------------------------------------------------
// CSR aggregation: agg[c] += dinv[c] * sum_{r in N(c)} hs[r]
// 256 threads = 4 waves; each 32-lane half-wave owns one node. 8 nodes/block.
// ---------------------------------------------------------------------------
__global__ __launch_bounds__(256) void k_agg(const int* __restrict__ off,
                                             const int* __restrict__ cnt,
                                             const int* __restrict__ csr,
                                             const float* __restrict__ hs,
                                             const float* __restrict__ dinv,
                                             float* __restrict__ agg) {
    int tid  = threadIdx.x;
    int j    = tid & 31;
    int half = tid >> 5;                 // 0..7 within block
    int node = blockIdx.x * 8 + half;
    if (node >= N_NODES) return;

    int o = off[node];
    int n = cnt[node];
    float acc = 0.f;
    int i = 0;
    for (; i + 4 <= n; i += 4) {
        int r0 = csr[o + i + 0];
        int r1 = csr[o + i + 1];
        int r2 = csr[o + i + 2];
        int r3 = csr[o + i + 3];
        float v0 = hs[(size_t)r0 * HID + j];
        float v1 = hs[(size_t)r1 * HID + j];
        float v2 = hs[(size_t)r2 * HID + j];
        float v3 = hs[(size_t)r3 * HID + j];
        acc += (v0 + v1) + (v2 + v3);
    }
    for (; i < n; i++) acc += hs[(size_t)csr[o + i] * HID + j];

    agg[(size_t)node * HID + j] += acc * dinv[node];
}

// ---------------------------------------------------------------------------
// out = log_softmax(relu(agg) @ W2 + b2)
// ---------------------------------------------------------------------------
__global__ __launch_bounds__(256) void k_out(const float* __restrict__ agg,
                                             const float* __restrict__ W2,
                                             const float* __restrict__ b2,
                                             float* __restrict__ out) {
    __shared__ float W2s[HID * NCLS];   // 320 floats
    __shared__ float b2s[NCLS];
    int tid = threadIdx.x;
    for (int i = tid; i < HID * NCLS; i += 256) W2s[i] = W2[i];
    if (tid < NCLS) b2s[tid] = b2[tid];
    __syncthreads();

    int node = blockIdx.x * 256 + tid;
    if (node >= N_NODES) return;

    float a[HID];
    const float4* av = (const float4*)(agg + (size_t)node * HID);
    #pragma unroll
    for (int q = 0; q < HID / 4; q++) {
        float4 v = av[q];
        a[q * 4 + 0] = fmaxf(v.x, 0.f);
        a[q * 4 + 1] = fmaxf(v.y, 0.f);
        a[q * 4 + 2] = fmaxf(v.z, 0.f);
        a[q * 4 + 3] = fmaxf(v.w, 0.f);
    }

    float logits[NCLS];
    #pragma unroll
    for (int c = 0; c < NCLS; c++) {
        float s = b2s[c];
        #pragma unroll
        for (int k = 0; k < HID; k++) s = fmaf(a[k], W2s[k * NCLS + c], s);
        logits[c] = s;
    }

    float m = logits[0];
    #pragma unroll
    for (int c = 1; c < NCLS; c++) m = fmaxf(m, logits[c]);
    float se = 0.f;
    #pragma unroll
    for (int c = 0; c < NCLS; c++) se += expf(logits[c] - m);
    float lse = m + logf(se);
    #pragma unroll
    for (int c = 0; c < NCLS; c++) out[node * NCLS + c] = logits[c] - lse;
}

// ---------------------------------------------------------------------------
extern "C" void kernel_launch(void* const* d_in, const int* in_sizes, int n_in,
                              void* d_out, int out_size, void* d_ws, size_t ws_size,
                              hipStream_t stream) {
    const float* feat = (const float*)d_in[0];
    const void*  ei   = d_in[1];
    const float* W1   = (const float*)d_in[2];
    const float* b1   = (const float*)d_in[3];
    const float* W2   = (const float*)d_in[4];
    const float* b2   = (const float*)d_in[5];
    float* out = (float*)d_out;

    char* ws = (char*)d_ws;
    int*   flag   = (int*)(ws + OFF_FLAG);
    int*   cnt    = (int*)(ws + OFF_CNT);
    int*   off    = (int*)(ws + OFF_OFF);
    int*   cursor = (int*)(ws + OFF_CURSOR);
    int*   bsum   = (int*)(ws + OFF_BSUM);
    float* dinv   = (float*)(ws + OFF_DINV);
    int*   csr    = (int*)(ws + OFF_CSR);
    float* hs     = (float*)(ws + OFF_HS);
    float* agg    = (float*)(ws + OFF_AGG);

    const int gN = (N_NODES + 255) / 256;   // 391
    const int gE = (E_EDGES + 255) / 256;

    k_detect_idx64<<<1, 256, 0, stream>>>((const int*)ei, flag);
    k_zero_cnt<<<gN, 256, 0, stream>>>(cnt);
    k_hist<<<gE, 256, 0, stream>>>(ei, flag, cnt);
    k_scan1<<<gN, 256, 0, stream>>>(cnt, off, bsum);
    k_scan2<<<1, 512, 0, stream>>>(bsum, gN);
    k_scan3<<<gN, 256, 0, stream>>>(cnt, off, cursor, bsum, dinv);
    k_scatter<<<gE, 256, 0, stream>>>(ei, flag, cursor, csr);

    k_h<<<(N_NODES + 127) / 128, 256, 0, stream>>>(feat, W1, b1, dinv, hs, agg);
    k_agg<<<(N_NODES + 7) / 8, 256, 0, stream>>>(off, cnt, csr, hs, dinv, agg);
    k_out<<<gN, 256, 0, stream>>>(agg, W2, b2, out);
}

// Round 9
// 255.043 us; speedup vs baseline: 2.4425x; 2.1077x over previous
//
#include <hip/hip_runtime.h>

constexpr int N_NODES = 100000;
constexpr int E_EDGES = 3200000;
constexpr int F_IN    = 256;
constexpr int HID     = 32;
constexpr int NCLS    = 10;

// bucketing: bucket = col >> 7  (128 target nodes per bucket)
constexpr int BUCK_SHIFT = 7;
constexpr int NPB        = 128;                          // nodes per bucket
constexpr int NBUCK      = (N_NODES + NPB - 1) / NPB;    // 782
constexpr int EPB        = 4096;                         // edges per pass-1 block
constexpr int NBLK1      = (E_EDGES + EPB - 1) / EPB;    // 782

// ---------------- ws layout (byte offsets) ----------------
// flag       @ 0
// bucketBase @ 4KB    (NBUCK+1 int)
// bucketTot  @ 16KB   (NBUCK int)
// Bhist      @ 1MB    (NBLK1*NBUCK int = 2.45MB)  -> [1MB,4MB)
// cnt  @ 4MB  (N int) ; off @ 5MB ; dinv @ 6MB
// csr  @ 7MB  (E int, 12.8MB)                     -> [7MB,20MB)
// binned @ 20MB (E uint2, 25.6MB)  OVERLAID by hs/agg after k_p2:
// hs   @ 20MB (N*32 f, 12.8MB) ; agg @ 33MB (N*32 f, 12.8MB)  -> ws top 45.8MB
constexpr size_t OFF_FLAG = 0;
constexpr size_t OFF_BB   = 4u << 10;
constexpr size_t OFF_BT   = 16u << 10;
constexpr size_t OFF_BH   = 1u << 20;
constexpr size_t OFF_CNT  = 4u << 20;
constexpr size_t OFF_OFF  = 5u << 20;
constexpr size_t OFF_DINV = 6u << 20;
constexpr size_t OFF_CSR  = 7u << 20;
constexpr size_t OFF_BIN  = 20u << 20;
constexpr size_t OFF_HS   = 20u << 20;   // overlays binned (dead after k_p2)
constexpr size_t OFF_AGG  = 33u << 20;

// ---------------------------------------------------------------------------
// edge_index dtype hedge: int64 storage has all-zero odd 32-bit words.
// ---------------------------------------------------------------------------
__global__ void k_detect_idx64(const int* __restrict__ ei32, int* __restrict__ flag) {
    __shared__ int nz;
    if (threadIdx.x == 0) nz = 0;
    __syncthreads();
    int acc = 0;
    for (int i = threadIdx.x; i < 1024; i += 256) acc |= ei32[2 * i + 1];
    if (acc != 0) atomicOr(&nz, 1);
    __syncthreads();
    if (threadIdx.x == 0) flag[0] = (nz == 0) ? 1 : 0;   // 1 => int64 storage
}

__device__ __forceinline__ int load_idx(const void* ei, long long i, int is64) {
    if (is64) return (int)((const long long*)ei)[i];
    return ((const int*)ei)[i];
}

// ---------------------------------------------------------------------------
// pass 1: bucket histogram (LDS), per-block dump
// ---------------------------------------------------------------------------
__global__ __launch_bounds__(256) void k_p1hist(const void* __restrict__ ei,
                                                const int* __restrict__ flag,
                                                int* __restrict__ Bhist) {
    __shared__ int h[NBUCK];
    int tid = threadIdx.x, blk = blockIdx.x;
    for (int i = tid; i < NBUCK; i += 256) h[i] = 0;
    __syncthreads();
    int is64 = flag[0];
    int base = blk * EPB;
    for (int k = tid; k < EPB; k += 256) {
        int i = base + k;
        if (i >= E_EDGES) break;
        int c = load_idx(ei, (long long)E_EDGES + i, is64);
        atomicAdd(&h[c >> BUCK_SHIFT], 1);
    }
    __syncthreads();
    for (int i = tid; i < NBUCK; i += 256) Bhist[blk * NBUCK + i] = h[i];
}

// per-bucket exclusive scan across blocks (in place); bucket totals out
__global__ __launch_bounds__(256) void k_colscan(int* __restrict__ Bhist,
                                                 int* __restrict__ bucketTot) {
    int j = blockIdx.x * 256 + threadIdx.x;
    if (j >= NBUCK) return;
    int acc = 0;
    int blk = 0;
    for (; blk + 4 <= NBLK1; blk += 4) {
        int i0 = (blk + 0) * NBUCK + j, i1 = (blk + 1) * NBUCK + j;
        int i2 = (blk + 2) * NBUCK + j, i3 = (blk + 3) * NBUCK + j;
        int v0 = Bhist[i0], v1 = Bhist[i1], v2 = Bhist[i2], v3 = Bhist[i3];
        Bhist[i0] = acc; acc += v0;
        Bhist[i1] = acc; acc += v1;
        Bhist[i2] = acc; acc += v2;
        Bhist[i3] = acc; acc += v3;
    }
    for (; blk < NBLK1; blk++) {
        int i0 = blk * NBUCK + j;
        int v = Bhist[i0]; Bhist[i0] = acc; acc += v;
    }
    bucketTot[j] = acc;
}

// exclusive scan of bucket totals -> bucketBase[0..NBUCK]
__global__ __launch_bounds__(1024) void k_totscan(const int* __restrict__ bucketTot,
                                                  int* __restrict__ bucketBase) {
    __shared__ int s[1024];
    int tid = threadIdx.x;
    int v = (tid < NBUCK) ? bucketTot[tid] : 0;
    s[tid] = v;
    __syncthreads();
    for (int d = 1; d < 1024; d <<= 1) {
        int t = (tid >= d) ? s[tid - d] : 0;
        __syncthreads();
        s[tid] += t;
        __syncthreads();
    }
    if (tid < NBUCK) bucketBase[tid] = s[tid] - v;
    if (tid == 1023) bucketBase[NBUCK] = s[1023];   // = E_EDGES
}

// pass 1 scatter: (r,c) pairs into bucket segments, LDS cursors, no global atomics
__global__ __launch_bounds__(256) void k_p1scat(const void* __restrict__ ei,
                                                const int* __restrict__ flag,
                                                const int* __restrict__ Bhist,
                                                const int* __restrict__ bucketBase,
                                                uint2* __restrict__ binned) {
    __shared__ int cur[NBUCK];
    int tid = threadIdx.x, blk = blockIdx.x;
    for (int i = tid; i < NBUCK; i += 256)
        cur[i] = bucketBase[i] + Bhist[blk * NBUCK + i];
    __syncthreads();
    int is64 = flag[0];
    int base = blk * EPB;
    for (int k = tid; k < EPB; k += 256) {
        int i = base + k;
        if (i >= E_EDGES) break;
        int r = load_idx(ei, i, is64);
        int c = load_idx(ei, (long long)E_EDGES + i, is64);
        int d = atomicAdd(&cur[c >> BUCK_SHIFT], 1);
        binned[d] = make_uint2((unsigned)r, (unsigned)c);
    }
}

// pass 2: per bucket (128 nodes) counting-sort into csr; emits cnt/off/dinv
__global__ __launch_bounds__(256) void k_p2(const uint2* __restrict__ binned,
                                            const int* __restrict__ bucketBase,
                                            int* __restrict__ cnt,
                                            int* __restrict__ off,
                                            float* __restrict__ dinv,
                                            int* __restrict__ csr) {
    __shared__ int lcnt[NPB], sc[NPB], lcur[NPB];
    int b = blockIdx.x, tid = threadIdx.x;
    int s = bucketBase[b], e = bucketBase[b + 1];
    if (tid < NPB) lcnt[tid] = 0;
    __syncthreads();
    for (int i = s + tid; i < e; i += 256)
        atomicAdd(&lcnt[binned[i].y & (NPB - 1)], 1);
    __syncthreads();
    if (tid < NPB) sc[tid] = lcnt[tid];
    __syncthreads();
    for (int d = 1; d < NPB; d <<= 1) {
        int t = 0;
        if (tid < NPB && tid >= d) t = sc[tid - d];
        __syncthreads();
        if (tid < NPB) sc[tid] += t;
        __syncthreads();
    }
    if (tid < NPB) {
        int o = s + sc[tid] - lcnt[tid];     // exclusive
        lcur[tid] = o;
        int node = b * NPB + tid;
        if (node < N_NODES) {
            off[node]  = o;
            cnt[node]  = lcnt[tid];
            dinv[node] = rsqrtf((float)lcnt[tid] + 1.0f);   // +1 self-loop
        }
    }
    __syncthreads();
    for (int i = s + tid; i < e; i += 256) {
        uint2 p = binned[i];
        int pos = atomicAdd(&lcur[p.y & (NPB - 1)], 1);
        csr[pos] = (int)p.x;
    }
}

// ---------------------------------------------------------------------------
// h = feature @ W1 ; hs = h*dinv ; agg = b1 + hs*dinv  (self-loop + bias)
// Register tile: 256 threads, each computes 4 nodes x 4 cols.
// ---------------------------------------------------------------------------
__global__ __launch_bounds__(256) void k_h(const float* __restrict__ feat,
                                           const float* __restrict__ W1,
                                           const float* __restrict__ b1,
                                           const float* __restrict__ dinv,
                                           float* __restrict__ hs,
                                           float* __restrict__ agg) {
    __shared__ float4 W1s4[F_IN * HID / 4];   // 32 KB
    int tid = threadIdx.x;
    {
        const float4* W1g = (const float4*)W1;
        for (int i = tid; i < F_IN * HID / 4; i += 256) W1s4[i] = W1g[i];
    }
    __syncthreads();

    int jq = tid & 7;
    int ng = tid >> 3;
    int n0 = blockIdx.x * 128 + ng * 4;

    int nc0 = min(n0 + 0, N_NODES - 1);
    int nc1 = min(n0 + 1, N_NODES - 1);
    int nc2 = min(n0 + 2, N_NODES - 1);
    int nc3 = min(n0 + 3, N_NODES - 1);

    const float4* f4 = (const float4*)feat;
    float4 a0 = {0,0,0,0}, a1 = {0,0,0,0}, a2 = {0,0,0,0}, a3 = {0,0,0,0};

    #pragma unroll 4
    for (int k4 = 0; k4 < F_IN / 4; k4++) {
        float4 w0 = W1s4[(k4 * 4 + 0) * 8 + jq];
        float4 w1 = W1s4[(k4 * 4 + 1) * 8 + jq];
        float4 w2 = W1s4[(k4 * 4 + 2) * 8 + jq];
        float4 w3 = W1s4[(k4 * 4 + 3) * 8 + jq];
        float4 f0 = f4[(size_t)nc0 * (F_IN / 4) + k4];
        float4 f1 = f4[(size_t)nc1 * (F_IN / 4) + k4];
        float4 f2 = f4[(size_t)nc2 * (F_IN / 4) + k4];
        float4 f3 = f4[(size_t)nc3 * (F_IN / 4) + k4];

        #define ACC(A, F) \
            A.x = fmaf(F.x, w0.x, A.x); A.y = fmaf(F.x, w0.y, A.y); \
            A.z = fmaf(F.x, w0.z, A.z); A.w = fmaf(F.x, w0.w, A.w); \
            A.x = fmaf(F.y, w1.x, A.x); A.y = fmaf(F.y, w1.y, A.y); \
            A.z = fmaf(F.y, w1.z, A.z); A.w = fmaf(F.y, w1.w, A.w); \
            A.x = fmaf(F.z, w2.x, A.x); A.y = fmaf(F.z, w2.y, A.y); \
            A.z = fmaf(F.z, w2.z, A.z); A.w = fmaf(F.z, w2.w, A.w); \
            A.x = fmaf(F.w, w3.x, A.x); A.y = fmaf(F.w, w3.y, A.y); \
            A.z = fmaf(F.w, w3.z, A.z); A.w = fmaf(F.w, w3.w, A.w);
        ACC(a0, f0) ACC(a1, f1) ACC(a2, f2) ACC(a3, f3)
        #undef ACC
    }

    float4 b1v = *(const float4*)(b1 + jq * 4);
    float4* hs4  = (float4*)hs;
    float4* agg4 = (float4*)agg;

    #define EMIT(A, M) { int n = n0 + M; if (n < N_NODES) {                  \
        float di = dinv[n];                                                  \
        float4 h; h.x = A.x * di; h.y = A.y * di; h.z = A.z * di; h.w = A.w * di; \
        hs4[(size_t)n * 8 + jq] = h;                                         \
        float4 o; o.x = b1v.x + h.x * di; o.y = b1v.y + h.y * di;            \
        o.z = b1v.z + h.z * di; o.w = b1v.w + h.w * di;                      \
        agg4[(size_t)n * 8 + jq] = o; } }
    EMIT(a0, 0) EMIT(a1, 1) EMIT(a2, 2) EMIT(a3, 3)
    #undef EMIT
}

// ---------------------------------------------------------------------------
// CSR aggregation: agg[c] += dinv[c] * sum_{r in N(c)} hs[r]
// 32-lane half-wave per node, 8 nodes per 256-thread block.
// ---------------------------------------------------------------------------
__global__ __launch_bounds__(256) void k_agg(const int* __restrict__ off,
                                             const int* __restrict__ cnt,
                                             const int* __restrict__ csr,
                                             const float* __restrict__ hs,
                                             const float* __restrict__ dinv,
                                             float* __restrict__ agg) {
    int tid  = threadIdx.x;
    int j    = tid & 31;
    int half = tid >> 5;
    int node = blockIdx.x * 8 + half;
    if (node >= N_NODES) return;

    int o = off[node];
    int n = cnt[node];
    float acc = 0.f;
    int i = 0;
    for (; i + 4 <= n; i += 4) {
        int r0 = csr[o + i + 0];
        int r1 = csr[o + i + 1];
        int r2 = csr[o + i + 2];
        int r3 = csr[o + i + 3];
        float v0 = hs[(size_t)r0 * HID + j];
        float v1 = hs[(size_t)r1 * HID + j];
        float v2 = hs[(size_t)r2 * HID + j];
        float v3 = hs[(size_t)r3 * HID + j];
        acc += (v0 + v1) + (v2 + v3);
    }
    for (; i < n; i++) acc += hs[(size_t)csr[o + i] * HID + j];

    agg[(size_t)node * HID + j] += acc * dinv[node];
}

// ---------------------------------------------------------------------------
// out = log_softmax(relu(agg) @ W2 + b2)
// ---------------------------------------------------------------------------
__global__ __launch_bounds__(256) void k_out(const float* __restrict__ agg,
                                             const float* __restrict__ W2,
                                             const float* __restrict__ b2,
                                             float* __restrict__ out) {
    __shared__ float W2s[HID * NCLS];
    __shared__ float b2s[NCLS];
    int tid = threadIdx.x;
    for (int i = tid; i < HID * NCLS; i += 256) W2s[i] = W2[i];
    if (tid < NCLS) b2s[tid] = b2[tid];
    __syncthreads();

    int node = blockIdx.x * 256 + tid;
    if (node >= N_NODES) return;

    float a[HID];
    const float4* av = (const float4*)(agg + (size_t)node * HID);
    #pragma unroll
    for (int q = 0; q < HID / 4; q++) {
        float4 v = av[q];
        a[q * 4 + 0] = fmaxf(v.x, 0.f);
        a[q * 4 + 1] = fmaxf(v.y, 0.f);
        a[q * 4 + 2] = fmaxf(v.z, 0.f);
        a[q * 4 + 3] = fmaxf(v.w, 0.f);
    }

    float logits[NCLS];
    #pragma unroll
    for (int c = 0; c < NCLS; c++) {
        float s = b2s[c];
        #pragma unroll
        for (int k = 0; k < HID; k++) s = fmaf(a[k], W2s[k * NCLS + c], s);
        logits[c] = s;
    }

    float m = logits[0];
    #pragma unroll
    for (int c = 1; c < NCLS; c++) m = fmaxf(m, logits[c]);
    float se = 0.f;
    #pragma unroll
    for (int c = 0; c < NCLS; c++) se += expf(logits[c] - m);
    float lse = m + logf(se);
    #pragma unroll
    for (int c = 0; c < NCLS; c++) out[node * NCLS + c] = logits[c] - lse;
}

// ---------------------------------------------------------------------------
extern "C" void kernel_launch(void* const* d_in, const int* in_sizes, int n_in,
                              void* d_out, int out_size, void* d_ws, size_t ws_size,
                              hipStream_t stream) {
    const float* feat = (const float*)d_in[0];
    const void*  ei   = d_in[1];
    const float* W1   = (const float*)d_in[2];
    const float* b1   = (const float*)d_in[3];
    const float* W2   = (const float*)d_in[4];
    const float* b2   = (const float*)d_in[5];
    float* out = (float*)d_out;

    char* ws = (char*)d_ws;
    int*   flag   = (int*)(ws + OFF_FLAG);
    int*   bbase  = (int*)(ws + OFF_BB);
    int*   btot   = (int*)(ws + OFF_BT);
    int*   Bhist  = (int*)(ws + OFF_BH);
    int*   cnt    = (int*)(ws + OFF_CNT);
    int*   off    = (int*)(ws + OFF_OFF);
    float* dinv   = (float*)(ws + OFF_DINV);
    int*   csr    = (int*)(ws + OFF_CSR);
    uint2* binned = (uint2*)(ws + OFF_BIN);
    float* hs     = (float*)(ws + OFF_HS);    // overlays binned after k_p2
    float* agg    = (float*)(ws + OFF_AGG);

    k_detect_idx64<<<1, 256, 0, stream>>>((const int*)ei, flag);
    k_p1hist<<<NBLK1, 256, 0, stream>>>(ei, flag, Bhist);
    k_colscan<<<(NBUCK + 255) / 256, 256, 0, stream>>>(Bhist, btot);
    k_totscan<<<1, 1024, 0, stream>>>(btot, bbase);
    k_p1scat<<<NBLK1, 256, 0, stream>>>(ei, flag, Bhist, bbase, binned);
    k_p2<<<NBUCK, 256, 0, stream>>>(binned, bbase, cnt, off, dinv, csr);

    k_h<<<(N_NODES + 127) / 128, 256, 0, stream>>>(feat, W1, b1, dinv, hs, agg);
    k_agg<<<(N_NODES + 7) / 8, 256, 0, stream>>>(off, cnt, csr, hs, dinv, agg);
    k_out<<<(N_NODES + 255) / 256, 256, 0, stream>>>(agg, W2, b2, out);
}

// Round 10
// 247.933 us; speedup vs baseline: 2.5126x; 1.0287x over previous
//
#include <hip/hip_runtime.h>

constexpr int N_NODES = 100000;
constexpr int E_EDGES = 3200000;
constexpr int F_IN    = 256;
constexpr int HID     = 32;
constexpr int NCLS    = 10;

// bucketing: bucket = col >> 7  (128 target nodes per bucket)
constexpr int BUCK_SHIFT = 7;
constexpr int NPB        = 128;                          // nodes per bucket
constexpr int NBUCK      = (N_NODES + NPB - 1) / NPB;    // 782
constexpr int EPB        = 4096;                         // edges per pass-1 block
constexpr int NBLK1      = (E_EDGES + EPB - 1) / EPB;    // 782

// ---------------- ws layout (byte offsets) ----------------
constexpr size_t OFF_FLAG = 0;
constexpr size_t OFF_BB   = 4u << 10;
constexpr size_t OFF_BT   = 16u << 10;
constexpr size_t OFF_BH   = 1u << 20;
constexpr size_t OFF_CNT  = 4u << 20;
constexpr size_t OFF_OFF  = 5u << 20;
constexpr size_t OFF_DINV = 6u << 20;
constexpr size_t OFF_CSR  = 7u << 20;
constexpr size_t OFF_BIN  = 20u << 20;
constexpr size_t OFF_HS   = 20u << 20;   // overlays binned (dead after k_p2)
constexpr size_t OFF_AGG  = 33u << 20;

// ---------------------------------------------------------------------------
// edge_index dtype hedge: int64 storage has all-zero odd 32-bit words.
// ---------------------------------------------------------------------------
__global__ void k_detect_idx64(const int* __restrict__ ei32, int* __restrict__ flag) {
    __shared__ int nz;
    if (threadIdx.x == 0) nz = 0;
    __syncthreads();
    int acc = 0;
    for (int i = threadIdx.x; i < 1024; i += 256) acc |= ei32[2 * i + 1];
    if (acc != 0) atomicOr(&nz, 1);
    __syncthreads();
    if (threadIdx.x == 0) flag[0] = (nz == 0) ? 1 : 0;   // 1 => int64 storage
}

__device__ __forceinline__ int load_idx(const void* ei, long long i, int is64) {
    if (is64) return (int)((const long long*)ei)[i];
    return ((const int*)ei)[i];
}

// ---------------------------------------------------------------------------
// pass 1: bucket histogram (LDS), per-block dump
// ---------------------------------------------------------------------------
__global__ __launch_bounds__(256) void k_p1hist(const void* __restrict__ ei,
                                                const int* __restrict__ flag,
                                                int* __restrict__ Bhist) {
    __shared__ int h[NBUCK];
    int tid = threadIdx.x, blk = blockIdx.x;
    for (int i = tid; i < NBUCK; i += 256) h[i] = 0;
    __syncthreads();
    int is64 = flag[0];
    int base = blk * EPB;
    for (int k = tid; k < EPB; k += 256) {
        int i = base + k;
        if (i >= E_EDGES) break;
        int c = load_idx(ei, (long long)E_EDGES + i, is64);
        atomicAdd(&h[c >> BUCK_SHIFT], 1);
    }
    __syncthreads();
    for (int i = tid; i < NBUCK; i += 256) Bhist[blk * NBUCK + i] = h[i];
}

// per-bucket exclusive scan across blocks (in place); bucket totals out
__global__ __launch_bounds__(256) void k_colscan(int* __restrict__ Bhist,
                                                 int* __restrict__ bucketTot) {
    int j = blockIdx.x * 256 + threadIdx.x;
    if (j >= NBUCK) return;
    int acc = 0;
    int blk = 0;
    for (; blk + 4 <= NBLK1; blk += 4) {
        int i0 = (blk + 0) * NBUCK + j, i1 = (blk + 1) * NBUCK + j;
        int i2 = (blk + 2) * NBUCK + j, i3 = (blk + 3) * NBUCK + j;
        int v0 = Bhist[i0], v1 = Bhist[i1], v2 = Bhist[i2], v3 = Bhist[i3];
        Bhist[i0] = acc; acc += v0;
        Bhist[i1] = acc; acc += v1;
        Bhist[i2] = acc; acc += v2;
        Bhist[i3] = acc; acc += v3;
    }
    for (; blk < NBLK1; blk++) {
        int i0 = blk * NBUCK + j;
        int v = Bhist[i0]; Bhist[i0] = acc; acc += v;
    }
    bucketTot[j] = acc;
}

// exclusive scan of bucket totals -> bucketBase[0..NBUCK]
__global__ __launch_bounds__(1024) void k_totscan(const int* __restrict__ bucketTot,
                                                  int* __restrict__ bucketBase) {
    __shared__ int s[1024];
    int tid = threadIdx.x;
    int v = (tid < NBUCK) ? bucketTot[tid] : 0;
    s[tid] = v;
    __syncthreads();
    for (int d = 1; d < 1024; d <<= 1) {
        int t = (tid >= d) ? s[tid - d] : 0;
        __syncthreads();
        s[tid] += t;
        __syncthreads();
    }
    if (tid < NBUCK) bucketBase[tid] = s[tid] - v;
    if (tid == 1023) bucketBase[NBUCK] = s[1023];   // = E_EDGES
}

// pass 1 scatter: (r,c) pairs into bucket segments, LDS cursors, no global atomics
__global__ __launch_bounds__(256) void k_p1scat(const void* __restrict__ ei,
                                                const int* __restrict__ flag,
                                                const int* __restrict__ Bhist,
                                                const int* __restrict__ bucketBase,
                                                uint2* __restrict__ binned) {
    __shared__ int cur[NBUCK];
    int tid = threadIdx.x, blk = blockIdx.x;
    for (int i = tid; i < NBUCK; i += 256)
        cur[i] = bucketBase[i] + Bhist[blk * NBUCK + i];
    __syncthreads();
    int is64 = flag[0];
    int base = blk * EPB;
    for (int k = tid; k < EPB; k += 256) {
        int i = base + k;
        if (i >= E_EDGES) break;
        int r = load_idx(ei, i, is64);
        int c = load_idx(ei, (long long)E_EDGES + i, is64);
        int d = atomicAdd(&cur[c >> BUCK_SHIFT], 1);
        binned[d] = make_uint2((unsigned)r, (unsigned)c);
    }
}

// pass 2: per bucket (128 nodes) counting-sort into csr; emits cnt/off/dinv
__global__ __launch_bounds__(256) void k_p2(const uint2* __restrict__ binned,
                                            const int* __restrict__ bucketBase,
                                            int* __restrict__ cnt,
                                            int* __restrict__ off,
                                            float* __restrict__ dinv,
                                            int* __restrict__ csr) {
    __shared__ int lcnt[NPB], sc[NPB], lcur[NPB];
    int b = blockIdx.x, tid = threadIdx.x;
    int s = bucketBase[b], e = bucketBase[b + 1];
    if (tid < NPB) lcnt[tid] = 0;
    __syncthreads();
    for (int i = s + tid; i < e; i += 256)
        atomicAdd(&lcnt[binned[i].y & (NPB - 1)], 1);
    __syncthreads();
    if (tid < NPB) sc[tid] = lcnt[tid];
    __syncthreads();
    for (int d = 1; d < NPB; d <<= 1) {
        int t = 0;
        if (tid < NPB && tid >= d) t = sc[tid - d];
        __syncthreads();
        if (tid < NPB) sc[tid] += t;
        __syncthreads();
    }
    if (tid < NPB) {
        int o = s + sc[tid] - lcnt[tid];     // exclusive
        lcur[tid] = o;
        int node = b * NPB + tid;
        if (node < N_NODES) {
            off[node]  = o;
            cnt[node]  = lcnt[tid];
            dinv[node] = rsqrtf((float)lcnt[tid] + 1.0f);   // +1 self-loop
        }
    }
    __syncthreads();
    for (int i = s + tid; i < e; i += 256) {
        uint2 p = binned[i];
        int pos = atomicAdd(&lcur[p.y & (NPB - 1)], 1);
        csr[pos] = (int)p.x;
    }
}

// ---------------------------------------------------------------------------
// h = feature @ W1 ; hs = h*dinv ; agg = b1 + hs*dinv  (self-loop + bias)
// Round 9 -> 10: occupancy fix. 512 threads/block, each thread 2 nodes x 4
// cols (was 256 threads x 4 nodes: 12 waves/CU cap, measured Occupancy 23%,
// latency-bound at 985 GB/s / VALUBusy 15.6%). Same 128 nodes/block, same
// grid (782), same 32 KB LDS -> 8 waves/block, ~24 waves/CU cap.
// ---------------------------------------------------------------------------
__global__ __launch_bounds__(512) void k_h(const float* __restrict__ feat,
                                           const float* __restrict__ W1,
                                           const float* __restrict__ b1,
                                           const float* __restrict__ dinv,
                                           float* __restrict__ hs,
                                           float* __restrict__ agg) {
    __shared__ float4 W1s4[F_IN * HID / 4];   // 32 KB, float4 = W1[k][jq*4..+3]
    int tid = threadIdx.x;
    {
        const float4* W1g = (const float4*)W1;
        #pragma unroll
        for (int i = 0; i < 4; i++) W1s4[tid + 512 * i] = W1g[tid + 512 * i];
    }
    __syncthreads();

    int jq = tid & 7;        // col group: cols jq*4..jq*4+3
    int ng = tid >> 3;       // 0..63 node group
    int n0 = blockIdx.x * 128 + ng * 2;

    int nc0 = min(n0 + 0, N_NODES - 1);
    int nc1 = min(n0 + 1, N_NODES - 1);

    const float4* f4 = (const float4*)feat;
    float4 a0 = {0,0,0,0}, a1 = {0,0,0,0};

    #pragma unroll 4
    for (int k4 = 0; k4 < F_IN / 4; k4++) {
        float4 w0 = W1s4[(k4 * 4 + 0) * 8 + jq];
        float4 w1 = W1s4[(k4 * 4 + 1) * 8 + jq];
        float4 w2 = W1s4[(k4 * 4 + 2) * 8 + jq];
        float4 w3 = W1s4[(k4 * 4 + 3) * 8 + jq];
        float4 f0 = f4[(size_t)nc0 * (F_IN / 4) + k4];
        float4 f1 = f4[(size_t)nc1 * (F_IN / 4) + k4];

        #define ACC(A, F) \
            A.x = fmaf(F.x, w0.x, A.x); A.y = fmaf(F.x, w0.y, A.y); \
            A.z = fmaf(F.x, w0.z, A.z); A.w = fmaf(F.x, w0.w, A.w); \
            A.x = fmaf(F.y, w1.x, A.x); A.y = fmaf(F.y, w1.y, A.y); \
            A.z = fmaf(F.y, w1.z, A.z); A.w = fmaf(F.y, w1.w, A.w); \
            A.x = fmaf(F.z, w2.x, A.x); A.y = fmaf(F.z, w2.y, A.y); \
            A.z = fmaf(F.z, w2.z, A.z); A.w = fmaf(F.z, w2.w, A.w); \
            A.x = fmaf(F.w, w3.x, A.x); A.y = fmaf(F.w, w3.y, A.y); \
            A.z = fmaf(F.w, w3.z, A.z); A.w = fmaf(F.w, w3.w, A.w);
        ACC(a0, f0) ACC(a1, f1)
        #undef ACC
    }

    float4 b1v = *(const float4*)(b1 + jq * 4);
    float4* hs4  = (float4*)hs;
    float4* agg4 = (float4*)agg;

    #define EMIT(A, M) { int n = n0 + M; if (n < N_NODES) {                  \
        float di = dinv[n];                                                  \
        float4 h; h.x = A.x * di; h.y = A.y * di; h.z = A.z * di; h.w = A.w * di; \
        hs4[(size_t)n * 8 + jq] = h;                                         \
        float4 o; o.x = b1v.x + h.x * di; o.y = b1v.y + h.y * di;            \
        o.z = b1v.z + h.z * di; o.w = b1v.w + h.w * di;                      \
        agg4[(size_t)n * 8 + jq] = o; } }
    EMIT(a0, 0) EMIT(a1, 1)
    #undef EMIT
}

// ---------------------------------------------------------------------------
// CSR aggregation: agg[c] += dinv[c] * sum_{r in N(c)} hs[r]
// 32-lane half-wave per node, 8 nodes per 256-thread block.
// ---------------------------------------------------------------------------
__global__ __launch_bounds__(256) void k_agg(const int* __restrict__ off,
                                             const int* __restrict__ cnt,
                                             const int* __restrict__ csr,
                                             const float* __restrict__ hs,
                                             const float* __restrict__ dinv,
                                             float* __restrict__ agg) {
    int tid  = threadIdx.x;
    int j    = tid & 31;
    int half = tid >> 5;
    int node = blockIdx.x * 8 + half;
    if (node >= N_NODES) return;

    int o = off[node];
    int n = cnt[node];
    float acc = 0.f;
    int i = 0;
    for (; i + 4 <= n; i += 4) {
        int r0 = csr[o + i + 0];
        int r1 = csr[o + i + 1];
        int r2 = csr[o + i + 2];
        int r3 = csr[o + i + 3];
        float v0 = hs[(size_t)r0 * HID + j];
        float v1 = hs[(size_t)r1 * HID + j];
        float v2 = hs[(size_t)r2 * HID + j];
        float v3 = hs[(size_t)r3 * HID + j];
        acc += (v0 + v1) + (v2 + v3);
    }
    for (; i < n; i++) acc += hs[(size_t)csr[o + i] * HID + j];

    agg[(size_t)node * HID + j] += acc * dinv[node];
}

// ---------------------------------------------------------------------------
// out = log_softmax(relu(agg) @ W2 + b2)
// ---------------------------------------------------------------------------
__global__ __launch_bounds__(256) void k_out(const float* __restrict__ agg,
                                             const float* __restrict__ W2,
                                             const float* __restrict__ b2,
                                             float* __restrict__ out) {
    __shared__ float W2s[HID * NCLS];
    __shared__ float b2s[NCLS];
    int tid = threadIdx.x;
    for (int i = tid; i < HID * NCLS; i += 256) W2s[i] = W2[i];
    if (tid < NCLS) b2s[tid] = b2[tid];
    __syncthreads();

    int node = blockIdx.x * 256 + tid;
    if (node >= N_NODES) return;

    float a[HID];
    const float4* av = (const float4*)(agg + (size_t)node * HID);
    #pragma unroll
    for (int q = 0; q < HID / 4; q++) {
        float4 v = av[q];
        a[q * 4 + 0] = fmaxf(v.x, 0.f);
        a[q * 4 + 1] = fmaxf(v.y, 0.f);
        a[q * 4 + 2] = fmaxf(v.z, 0.f);
        a[q * 4 + 3] = fmaxf(v.w, 0.f);
    }

    float logits[NCLS];
    #pragma unroll
    for (int c = 0; c < NCLS; c++) {
        float s = b2s[c];
        #pragma unroll
        for (int k = 0; k < HID; k++) s = fmaf(a[k], W2s[k * NCLS + c], s);
        logits[c] = s;
    }

    float m = logits[0];
    #pragma unroll
    for (int c = 1; c < NCLS; c++) m = fmaxf(m, logits[c]);
    float se = 0.f;
    #pragma unroll
    for (int c = 0; c < NCLS; c++) se += expf(logits[c] - m);
    float lse = m + logf(se);
    #pragma unroll
    for (int c = 0; c < NCLS; c++) out[node * NCLS + c] = logits[c] - lse;
}

// ---------------------------------------------------------------------------
extern "C" void kernel_launch(void* const* d_in, const int* in_sizes, int n_in,
                              void* d_out, int out_size, void* d_ws, size_t ws_size,
                              hipStream_t stream) {
    const float* feat = (const float*)d_in[0];
    const void*  ei   = d_in[1];
    const float* W1   = (const float*)d_in[2];
    const float* b1   = (const float*)d_in[3];
    const float* W2   = (const float*)d_in[4];
    const float* b2   = (const float*)d_in[5];
    float* out = (float*)d_out;

    char* ws = (char*)d_ws;
    int*   flag   = (int*)(ws + OFF_FLAG);
    int*   bbase  = (int*)(ws + OFF_BB);
    int*   btot   = (int*)(ws + OFF_BT);
    int*   Bhist  = (int*)(ws + OFF_BH);
    int*   cnt    = (int*)(ws + OFF_CNT);
    int*   off    = (int*)(ws + OFF_OFF);
    float* dinv   = (float*)(ws + OFF_DINV);
    int*   csr    = (int*)(ws + OFF_CSR);
    uint2* binned = (uint2*)(ws + OFF_BIN);
    float* hs     = (float*)(ws + OFF_HS);    // overlays binned after k_p2
    float* agg    = (float*)(ws + OFF_AGG);

    k_detect_idx64<<<1, 256, 0, stream>>>((const int*)ei, flag);
    k_p1hist<<<NBLK1, 256, 0, stream>>>(ei, flag, Bhist);
    k_colscan<<<(NBUCK + 255) / 256, 256, 0, stream>>>(Bhist, btot);
    k_totscan<<<1, 1024, 0, stream>>>(btot, bbase);
    k_p1scat<<<NBLK1, 256, 0, stream>>>(ei, flag, Bhist, bbase, binned);
    k_p2<<<NBUCK, 256, 0, stream>>>(binned, bbase, cnt, off, dinv, csr);

    k_h<<<(N_NODES + 127) / 128, 512, 0, stream>>>(feat, W1, b1, dinv, hs, agg);
    k_agg<<<(N_NODES + 7) / 8, 256, 0, stream>>>(off, cnt, csr, hs, dinv, agg);
    k_out<<<(N_NODES + 255) / 256, 256, 0, stream>>>(agg, W2, b2, out);
}

// Round 11
// 237.213 us; speedup vs baseline: 2.6261x; 1.0452x over previous
//
#include <hip/hip_runtime.h>

constexpr int N_NODES = 100000;
constexpr int E_EDGES = 3200000;
constexpr int F_IN    = 256;
constexpr int HID     = 32;
constexpr int NCLS    = 10;

// bucketing: bucket = col >> 7  (128 target nodes per bucket)
constexpr int BUCK_SHIFT = 7;
constexpr int NPB        = 128;                          // nodes per bucket
constexpr int NBUCK      = (N_NODES + NPB - 1) / NPB;    // 782
constexpr int EPB        = 4096;                         // edges per pass-1 block
constexpr int NBLK1      = (E_EDGES + EPB - 1) / EPB;    // 782

// ---------------- ws layout (byte offsets) ----------------
// binned is now PACKED uint32: (r << 7) | (col & 127)  -> 12.8 MB
constexpr size_t OFF_FLAG = 0;
constexpr size_t OFF_BB   = 4u << 10;
constexpr size_t OFF_BT   = 16u << 10;
constexpr size_t OFF_BH   = 1u << 20;
constexpr size_t OFF_CNT  = 4u << 20;
constexpr size_t OFF_OFF  = 5u << 20;
constexpr size_t OFF_DINV = 6u << 20;
constexpr size_t OFF_CSR  = 7u << 20;
constexpr size_t OFF_BIN  = 20u << 20;   // 12.8 MB packed
constexpr size_t OFF_HS   = 20u << 20;   // overlays binned (dead after k_p2)
constexpr size_t OFF_AGG  = 33u << 20;

// ---------------------------------------------------------------------------
// edge_index dtype hedge: int64 storage has all-zero odd 32-bit words.
// ---------------------------------------------------------------------------
__global__ void k_detect_idx64(const int* __restrict__ ei32, int* __restrict__ flag) {
    __shared__ int nz;
    if (threadIdx.x == 0) nz = 0;
    __syncthreads();
    int acc = 0;
    for (int i = threadIdx.x; i < 1024; i += 256) acc |= ei32[2 * i + 1];
    if (acc != 0) atomicOr(&nz, 1);
    __syncthreads();
    if (threadIdx.x == 0) flag[0] = (nz == 0) ? 1 : 0;   // 1 => int64 storage
}

__device__ __forceinline__ int load_idx(const void* ei, long long i, int is64) {
    if (is64) return (int)((const long long*)ei)[i];
    return ((const int*)ei)[i];
}

// ---------------------------------------------------------------------------
// pass 1: bucket histogram (LDS), per-block dump.
// Round 10->11: 1024 threads (was 256) -> 16 waves/block, occupancy fix.
// ---------------------------------------------------------------------------
__global__ __launch_bounds__(1024) void k_p1hist(const void* __restrict__ ei,
                                                 const int* __restrict__ flag,
                                                 int* __restrict__ Bhist) {
    __shared__ int h[NBUCK];
    int tid = threadIdx.x, blk = blockIdx.x;
    for (int i = tid; i < NBUCK; i += 1024) h[i] = 0;
    __syncthreads();
    int is64 = flag[0];
    int base = blk * EPB;
    for (int k = tid; k < EPB; k += 1024) {
        int i = base + k;
        if (i >= E_EDGES) break;
        int c = load_idx(ei, (long long)E_EDGES + i, is64);
        atomicAdd(&h[c >> BUCK_SHIFT], 1);
    }
    __syncthreads();
    for (int i = tid; i < NBUCK; i += 1024) Bhist[blk * NBUCK + i] = h[i];
}

// per-bucket exclusive scan across blocks (in place); bucket totals out
__global__ __launch_bounds__(256) void k_colscan(int* __restrict__ Bhist,
                                                 int* __restrict__ bucketTot) {
    int j = blockIdx.x * 256 + threadIdx.x;
    if (j >= NBUCK) return;
    int acc = 0;
    int blk = 0;
    for (; blk + 4 <= NBLK1; blk += 4) {
        int i0 = (blk + 0) * NBUCK + j, i1 = (blk + 1) * NBUCK + j;
        int i2 = (blk + 2) * NBUCK + j, i3 = (blk + 3) * NBUCK + j;
        int v0 = Bhist[i0], v1 = Bhist[i1], v2 = Bhist[i2], v3 = Bhist[i3];
        Bhist[i0] = acc; acc += v0;
        Bhist[i1] = acc; acc += v1;
        Bhist[i2] = acc; acc += v2;
        Bhist[i3] = acc; acc += v3;
    }
    for (; blk < NBLK1; blk++) {
        int i0 = blk * NBUCK + j;
        int v = Bhist[i0]; Bhist[i0] = acc; acc += v;
    }
    bucketTot[j] = acc;
}

// exclusive scan of bucket totals -> bucketBase[0..NBUCK]
__global__ __launch_bounds__(1024) void k_totscan(const int* __restrict__ bucketTot,
                                                  int* __restrict__ bucketBase) {
    __shared__ int s[1024];
    int tid = threadIdx.x;
    int v = (tid < NBUCK) ? bucketTot[tid] : 0;
    s[tid] = v;
    __syncthreads();
    for (int d = 1; d < 1024; d <<= 1) {
        int t = (tid >= d) ? s[tid - d] : 0;
        __syncthreads();
        s[tid] += t;
        __syncthreads();
    }
    if (tid < NBUCK) bucketBase[tid] = s[tid] - v;
    if (tid == 1023) bucketBase[NBUCK] = s[1023];   // = E_EDGES
}

// pass 1 scatter: PACKED (r<<7 | c&127) into bucket segments, LDS cursors.
// Round 10->11: 4B packed payload (was 8B uint2, WRITE_SIZE 89MB -> ~45MB)
// + 1024 threads for latency hiding (Occupancy was 25%).
__global__ __launch_bounds__(1024) void k_p1scat(const void* __restrict__ ei,
                                                 const int* __restrict__ flag,
                                                 const int* __restrict__ Bhist,
                                                 const int* __restrict__ bucketBase,
                                                 unsigned* __restrict__ binned) {
    __shared__ int cur[NBUCK];
    int tid = threadIdx.x, blk = blockIdx.x;
    for (int i = tid; i < NBUCK; i += 1024)
        cur[i] = bucketBase[i] + Bhist[blk * NBUCK + i];
    __syncthreads();
    int is64 = flag[0];
    int base = blk * EPB;
    for (int k = tid; k < EPB; k += 1024) {
        int i = base + k;
        if (i >= E_EDGES) break;
        int r = load_idx(ei, i, is64);
        int c = load_idx(ei, (long long)E_EDGES + i, is64);
        int d = atomicAdd(&cur[c >> BUCK_SHIFT], 1);
        binned[d] = ((unsigned)r << BUCK_SHIFT) | ((unsigned)c & (NPB - 1));
    }
}

// pass 2: per bucket (128 nodes) counting-sort into csr; emits cnt/off/dinv
__global__ __launch_bounds__(256) void k_p2(const unsigned* __restrict__ binned,
                                            const int* __restrict__ bucketBase,
                                            int* __restrict__ cnt,
                                            int* __restrict__ off,
                                            float* __restrict__ dinv,
                                            int* __restrict__ csr) {
    __shared__ int lcnt[NPB], sc[NPB], lcur[NPB];
    int b = blockIdx.x, tid = threadIdx.x;
    int s = bucketBase[b], e = bucketBase[b + 1];
    if (tid < NPB) lcnt[tid] = 0;
    __syncthreads();
    for (int i = s + tid; i < e; i += 256)
        atomicAdd(&lcnt[binned[i] & (NPB - 1)], 1);
    __syncthreads();
    if (tid < NPB) sc[tid] = lcnt[tid];
    __syncthreads();
    for (int d = 1; d < NPB; d <<= 1) {
        int t = 0;
        if (tid < NPB && tid >= d) t = sc[tid - d];
        __syncthreads();
        if (tid < NPB) sc[tid] += t;
        __syncthreads();
    }
    if (tid < NPB) {
        int o = s + sc[tid] - lcnt[tid];     // exclusive
        lcur[tid] = o;
        int node = b * NPB + tid;
        if (node < N_NODES) {
            off[node]  = o;
            cnt[node]  = lcnt[tid];
            dinv[node] = rsqrtf((float)lcnt[tid] + 1.0f);   // +1 self-loop
        }
    }
    __syncthreads();
    for (int i = s + tid; i < e; i += 256) {
        unsigned p = binned[i];
        int pos = atomicAdd(&lcur[p & (NPB - 1)], 1);
        csr[pos] = (int)(p >> BUCK_SHIFT);
    }
}

// ---------------------------------------------------------------------------
// h = feature @ W1 ; hs = h*dinv ; agg = b1 + hs*dinv  (self-loop + bias)
// 512 threads/block, 2 nodes x 4 cols per thread (round-10 shape, unchanged).
// ---------------------------------------------------------------------------
__global__ __launch_bounds__(512) void k_h(const float* __restrict__ feat,
                                           const float* __restrict__ W1,
                                           const float* __restrict__ b1,
                                           const float* __restrict__ dinv,
                                           float* __restrict__ hs,
                                           float* __restrict__ agg) {
    __shared__ float4 W1s4[F_IN * HID / 4];   // 32 KB, float4 = W1[k][jq*4..+3]
    int tid = threadIdx.x;
    {
        const float4* W1g = (const float4*)W1;
        #pragma unroll
        for (int i = 0; i < 4; i++) W1s4[tid + 512 * i] = W1g[tid + 512 * i];
    }
    __syncthreads();

    int jq = tid & 7;        // col group: cols jq*4..jq*4+3
    int ng = tid >> 3;       // 0..63 node group
    int n0 = blockIdx.x * 128 + ng * 2;

    int nc0 = min(n0 + 0, N_NODES - 1);
    int nc1 = min(n0 + 1, N_NODES - 1);

    const float4* f4 = (const float4*)feat;
    float4 a0 = {0,0,0,0}, a1 = {0,0,0,0};

    #pragma unroll 4
    for (int k4 = 0; k4 < F_IN / 4; k4++) {
        float4 w0 = W1s4[(k4 * 4 + 0) * 8 + jq];
        float4 w1 = W1s4[(k4 * 4 + 1) * 8 + jq];
        float4 w2 = W1s4[(k4 * 4 + 2) * 8 + jq];
        float4 w3 = W1s4[(k4 * 4 + 3) * 8 + jq];
        float4 f0 = f4[(size_t)nc0 * (F_IN / 4) + k4];
        float4 f1 = f4[(size_t)nc1 * (F_IN / 4) + k4];

        #define ACC(A, F) \
            A.x = fmaf(F.x, w0.x, A.x); A.y = fmaf(F.x, w0.y, A.y); \
            A.z = fmaf(F.x, w0.z, A.z); A.w = fmaf(F.x, w0.w, A.w); \
            A.x = fmaf(F.y, w1.x, A.x); A.y = fmaf(F.y, w1.y, A.y); \
            A.z = fmaf(F.y, w1.z, A.z); A.w = fmaf(F.y, w1.w, A.w); \
            A.x = fmaf(F.z, w2.x, A.x); A.y = fmaf(F.z, w2.y, A.y); \
            A.z = fmaf(F.z, w2.z, A.z); A.w = fmaf(F.z, w2.w, A.w); \
            A.x = fmaf(F.w, w3.x, A.x); A.y = fmaf(F.w, w3.y, A.y); \
            A.z = fmaf(F.w, w3.z, A.z); A.w = fmaf(F.w, w3.w, A.w);
        ACC(a0, f0) ACC(a1, f1)
        #undef ACC
    }

    float4 b1v = *(const float4*)(b1 + jq * 4);
    float4* hs4  = (float4*)hs;
    float4* agg4 = (float4*)agg;

    #define EMIT(A, M) { int n = n0 + M; if (n < N_NODES) {                  \
        float di = dinv[n];                                                  \
        float4 h; h.x = A.x * di; h.y = A.y * di; h.z = A.z * di; h.w = A.w * di; \
        hs4[(size_t)n * 8 + jq] = h;                                         \
        float4 o; o.x = b1v.x + h.x * di; o.y = b1v.y + h.y * di;            \
        o.z = b1v.z + h.z * di; o.w = b1v.w + h.w * di;                      \
        agg4[(size_t)n * 8 + jq] = o; } }
    EMIT(a0, 0) EMIT(a1, 1)
    #undef EMIT
}

// ---------------------------------------------------------------------------
// CSR aggregation: agg[c] += dinv[c] * sum_{r in N(c)} hs[r]
// 32-lane half-wave per node, 8 nodes per 256-thread block.
// ---------------------------------------------------------------------------
__global__ __launch_bounds__(256) void k_agg(const int* __restrict__ off,
                                             const int* __restrict__ cnt,
                                             const int* __restrict__ csr,
                                             const float* __restrict__ hs,
                                             const float* __restrict__ dinv,
                                             float* __restrict__ agg) {
    int tid  = threadIdx.x;
    int j    = tid & 31;
    int half = tid >> 5;
    int node = blockIdx.x * 8 + half;
    if (node >= N_NODES) return;

    int o = off[node];
    int n = cnt[node];
    float acc = 0.f;
    int i = 0;
    for (; i + 4 <= n; i += 4) {
        int r0 = csr[o + i + 0];
        int r1 = csr[o + i + 1];
        int r2 = csr[o + i + 2];
        int r3 = csr[o + i + 3];
        float v0 = hs[(size_t)r0 * HID + j];
        float v1 = hs[(size_t)r1 * HID + j];
        float v2 = hs[(size_t)r2 * HID + j];
        float v3 = hs[(size_t)r3 * HID + j];
        acc += (v0 + v1) + (v2 + v3);
    }
    for (; i < n; i++) acc += hs[(size_t)csr[o + i] * HID + j];

    agg[(size_t)node * HID + j] += acc * dinv[node];
}

// ---------------------------------------------------------------------------
// out = log_softmax(relu(agg) @ W2 + b2)
// ---------------------------------------------------------------------------
__global__ __launch_bounds__(256) void k_out(const float* __restrict__ agg,
                                             const float* __restrict__ W2,
                                             const float* __restrict__ b2,
                                             float* __restrict__ out) {
    __shared__ float W2s[HID * NCLS];
    __shared__ float b2s[NCLS];
    int tid = threadIdx.x;
    for (int i = tid; i < HID * NCLS; i += 256) W2s[i] = W2[i];
    if (tid < NCLS) b2s[tid] = b2[tid];
    __syncthreads();

    int node = blockIdx.x * 256 + tid;
    if (node >= N_NODES) return;

    float a[HID];
    const float4* av = (const float4*)(agg + (size_t)node * HID);
    #pragma unroll
    for (int q = 0; q < HID / 4; q++) {
        float4 v = av[q];
        a[q * 4 + 0] = fmaxf(v.x, 0.f);
        a[q * 4 + 1] = fmaxf(v.y, 0.f);
        a[q * 4 + 2] = fmaxf(v.z, 0.f);
        a[q * 4 + 3] = fmaxf(v.w, 0.f);
    }

    float logits[NCLS];
    #pragma unroll
    for (int c = 0; c < NCLS; c++) {
        float s = b2s[c];
        #pragma unroll
        for (int k = 0; k < HID; k++) s = fmaf(a[k], W2s[k * NCLS + c], s);
        logits[c] = s;
    }

    float m = logits[0];
    #pragma unroll
    for (int c = 1; c < NCLS; c++) m = fmaxf(m, logits[c]);
    float se = 0.f;
    #pragma unroll
    for (int c = 0; c < NCLS; c++) se += expf(logits[c] - m);
    float lse = m + logf(se);
    #pragma unroll
    for (int c = 0; c < NCLS; c++) out[node * NCLS + c] = logits[c] - lse;
}

// ---------------------------------------------------------------------------
extern "C" void kernel_launch(void* const* d_in, const int* in_sizes, int n_in,
                              void* d_out, int out_size, void* d_ws, size_t ws_size,
                              hipStream_t stream) {
    const float* feat = (const float*)d_in[0];
    const void*  ei   = d_in[1];
    const float* W1   = (const float*)d_in[2];
    const float* b1   = (const float*)d_in[3];
    const float* W2   = (const float*)d_in[4];
    const float* b2   = (const float*)d_in[5];
    float* out = (float*)d_out;

    char* ws = (char*)d_ws;
    int*      flag   = (int*)(ws + OFF_FLAG);
    int*      bbase  = (int*)(ws + OFF_BB);
    int*      btot   = (int*)(ws + OFF_BT);
    int*      Bhist  = (int*)(ws + OFF_BH);
    int*      cnt    = (int*)(ws + OFF_CNT);
    int*      off    = (int*)(ws + OFF_OFF);
    float*    dinv   = (float*)(ws + OFF_DINV);
    int*      csr    = (int*)(ws + OFF_CSR);
    unsigned* binned = (unsigned*)(ws + OFF_BIN);
    float*    hs     = (float*)(ws + OFF_HS);    // overlays binned after k_p2
    float*    agg    = (float*)(ws + OFF_AGG);

    k_detect_idx64<<<1, 256, 0, stream>>>((const int*)ei, flag);
    k_p1hist<<<NBLK1, 1024, 0, stream>>>(ei, flag, Bhist);
    k_colscan<<<(NBUCK + 255) / 256, 256, 0, stream>>>(Bhist, btot);
    k_totscan<<<1, 1024, 0, stream>>>(btot, bbase);
    k_p1scat<<<NBLK1, 1024, 0, stream>>>(ei, flag, Bhist, bbase, binned);
    k_p2<<<NBUCK, 256, 0, stream>>>(binned, bbase, cnt, off, dinv, csr);

    k_h<<<(N_NODES + 127) / 128, 512, 0, stream>>>(feat, W1, b1, dinv, hs, agg);
    k_agg<<<(N_NODES + 7) / 8, 256, 0, stream>>>(off, cnt, csr, hs, dinv, agg);
    k_out<<<(N_NODES + 255) / 256, 256, 0, stream>>>(agg, W2, b2, out);
}

// Round 12
// 223.491 us; speedup vs baseline: 2.7874x; 1.0614x over previous
//
#include <hip/hip_runtime.h>

constexpr int N_NODES = 100000;
constexpr int E_EDGES = 3200000;
constexpr int F_IN    = 256;
constexpr int HID     = 32;
constexpr int NCLS    = 10;

// bucketing: bucket = col >> 7  (128 target nodes per bucket)
constexpr int BUCK_SHIFT = 7;
constexpr int NPB        = 128;                          // nodes per bucket
constexpr int NBUCK      = (N_NODES + NPB - 1) / NPB;    // 782
constexpr int EPB        = 4096;                         // edges per pass-1 block
constexpr int NBLK1      = (E_EDGES + EPB - 1) / EPB;    // 782

// ---------------- ws layout (byte offsets) ----------------
// binned: PACKED uint32 (r<<7 | col&127), 12.8 MB. hs16 overlays it after k_p2
// (bf16 x2 per uint32, N*16 u32 = 6.4 MB). agg fp32 at 33MB.
constexpr size_t OFF_FLAG = 0;
constexpr size_t OFF_BB   = 4u << 10;
constexpr size_t OFF_BT   = 16u << 10;
constexpr size_t OFF_BH   = 1u << 20;
constexpr size_t OFF_CNT  = 4u << 20;
constexpr size_t OFF_OFF  = 5u << 20;
constexpr size_t OFF_DINV = 6u << 20;
constexpr size_t OFF_CSR  = 7u << 20;
constexpr size_t OFF_BIN  = 20u << 20;   // 12.8 MB packed edges
constexpr size_t OFF_HS   = 20u << 20;   // overlays binned (dead after k_p2)
constexpr size_t OFF_AGG  = 33u << 20;

// bf16 helpers (RNE pack, cheap unpack)
__device__ __forceinline__ unsigned pack_bf16x2(float a, float b) {
    unsigned ua = __float_as_uint(a), ub = __float_as_uint(b);
    ua = (ua + 0x7FFFu + ((ua >> 16) & 1u)) >> 16;
    ub = (ub + 0x7FFFu + ((ub >> 16) & 1u)) >> 16;
    return ua | (ub << 16);
}
__device__ __forceinline__ float bf16_lo(unsigned p) { return __uint_as_float(p << 16); }
__device__ __forceinline__ float bf16_hi(unsigned p) { return __uint_as_float(p & 0xFFFF0000u); }

// ---------------------------------------------------------------------------
// edge_index dtype hedge: int64 storage has all-zero odd 32-bit words.
// ---------------------------------------------------------------------------
__global__ void k_detect_idx64(const int* __restrict__ ei32, int* __restrict__ flag) {
    __shared__ int nz;
    if (threadIdx.x == 0) nz = 0;
    __syncthreads();
    int acc = 0;
    for (int i = threadIdx.x; i < 1024; i += 256) acc |= ei32[2 * i + 1];
    if (acc != 0) atomicOr(&nz, 1);
    __syncthreads();
    if (threadIdx.x == 0) flag[0] = (nz == 0) ? 1 : 0;   // 1 => int64 storage
}

__device__ __forceinline__ int load_idx(const void* ei, long long i, int is64) {
    if (is64) return (int)((const long long*)ei)[i];
    return ((const int*)ei)[i];
}

// ---------------------------------------------------------------------------
// pass 1: bucket histogram (LDS), per-block dump. 1024 threads.
// ---------------------------------------------------------------------------
__global__ __launch_bounds__(1024) void k_p1hist(const void* __restrict__ ei,
                                                 const int* __restrict__ flag,
                                                 int* __restrict__ Bhist) {
    __shared__ int h[NBUCK];
    int tid = threadIdx.x, blk = blockIdx.x;
    for (int i = tid; i < NBUCK; i += 1024) h[i] = 0;
    __syncthreads();
    int is64 = flag[0];
    int base = blk * EPB;
    for (int k = tid; k < EPB; k += 1024) {
        int i = base + k;
        if (i >= E_EDGES) break;
        int c = load_idx(ei, (long long)E_EDGES + i, is64);
        atomicAdd(&h[c >> BUCK_SHIFT], 1);
    }
    __syncthreads();
    for (int i = tid; i < NBUCK; i += 1024) Bhist[blk * NBUCK + i] = h[i];
}

// per-bucket exclusive scan across blocks (in place); bucket totals out
__global__ __launch_bounds__(256) void k_colscan(int* __restrict__ Bhist,
                                                 int* __restrict__ bucketTot) {
    int j = blockIdx.x * 256 + threadIdx.x;
    if (j >= NBUCK) return;
    int acc = 0;
    int blk = 0;
    for (; blk + 4 <= NBLK1; blk += 4) {
        int i0 = (blk + 0) * NBUCK + j, i1 = (blk + 1) * NBUCK + j;
        int i2 = (blk + 2) * NBUCK + j, i3 = (blk + 3) * NBUCK + j;
        int v0 = Bhist[i0], v1 = Bhist[i1], v2 = Bhist[i2], v3 = Bhist[i3];
        Bhist[i0] = acc; acc += v0;
        Bhist[i1] = acc; acc += v1;
        Bhist[i2] = acc; acc += v2;
        Bhist[i3] = acc; acc += v3;
    }
    for (; blk < NBLK1; blk++) {
        int i0 = blk * NBUCK + j;
        int v = Bhist[i0]; Bhist[i0] = acc; acc += v;
    }
    bucketTot[j] = acc;
}

// exclusive scan of bucket totals -> bucketBase[0..NBUCK]
__global__ __launch_bounds__(1024) void k_totscan(const int* __restrict__ bucketTot,
                                                  int* __restrict__ bucketBase) {
    __shared__ int s[1024];
    int tid = threadIdx.x;
    int v = (tid < NBUCK) ? bucketTot[tid] : 0;
    s[tid] = v;
    __syncthreads();
    for (int d = 1; d < 1024; d <<= 1) {
        int t = (tid >= d) ? s[tid - d] : 0;
        __syncthreads();
        s[tid] += t;
        __syncthreads();
    }
    if (tid < NBUCK) bucketBase[tid] = s[tid] - v;
    if (tid == 1023) bucketBase[NBUCK] = s[1023];   // = E_EDGES
}

// pass 1 scatter: PACKED (r<<7 | c&127) into bucket segments, LDS cursors.
__global__ __launch_bounds__(1024) void k_p1scat(const void* __restrict__ ei,
                                                 const int* __restrict__ flag,
                                                 const int* __restrict__ Bhist,
                                                 const int* __restrict__ bucketBase,
                                                 unsigned* __restrict__ binned) {
    __shared__ int cur[NBUCK];
    int tid = threadIdx.x, blk = blockIdx.x;
    for (int i = tid; i < NBUCK; i += 1024)
        cur[i] = bucketBase[i] + Bhist[blk * NBUCK + i];
    __syncthreads();
    int is64 = flag[0];
    int base = blk * EPB;
    for (int k = tid; k < EPB; k += 1024) {
        int i = base + k;
        if (i >= E_EDGES) break;
        int r = load_idx(ei, i, is64);
        int c = load_idx(ei, (long long)E_EDGES + i, is64);
        int d = atomicAdd(&cur[c >> BUCK_SHIFT], 1);
        binned[d] = ((unsigned)r << BUCK_SHIFT) | ((unsigned)c & (NPB - 1));
    }
}

// pass 2: per bucket (128 nodes) counting-sort into csr; emits cnt/off/dinv
__global__ __launch_bounds__(256) void k_p2(const unsigned* __restrict__ binned,
                                            const int* __restrict__ bucketBase,
                                            int* __restrict__ cnt,
                                            int* __restrict__ off,
                                            float* __restrict__ dinv,
                                            int* __restrict__ csr) {
    __shared__ int lcnt[NPB], sc[NPB], lcur[NPB];
    int b = blockIdx.x, tid = threadIdx.x;
    int s = bucketBase[b], e = bucketBase[b + 1];
    if (tid < NPB) lcnt[tid] = 0;
    __syncthreads();
    for (int i = s + tid; i < e; i += 256)
        atomicAdd(&lcnt[binned[i] & (NPB - 1)], 1);
    __syncthreads();
    if (tid < NPB) sc[tid] = lcnt[tid];
    __syncthreads();
    for (int d = 1; d < NPB; d <<= 1) {
        int t = 0;
        if (tid < NPB && tid >= d) t = sc[tid - d];
        __syncthreads();
        if (tid < NPB) sc[tid] += t;
        __syncthreads();
    }
    if (tid < NPB) {
        int o = s + sc[tid] - lcnt[tid];     // exclusive
        lcur[tid] = o;
        int node = b * NPB + tid;
        if (node < N_NODES) {
            off[node]  = o;
            cnt[node]  = lcnt[tid];
            dinv[node] = rsqrtf((float)lcnt[tid] + 1.0f);   // +1 self-loop
        }
    }
    __syncthreads();
    for (int i = s + tid; i < e; i += 256) {
        unsigned p = binned[i];
        int pos = atomicAdd(&lcur[p & (NPB - 1)], 1);
        csr[pos] = (int)(p >> BUCK_SHIFT);
    }
}

// ---------------------------------------------------------------------------
// h = feature @ W1 ; hs16 = bf16(h * dinv_row)  (packed 2/uint32)
// Round 11->12: 64 nodes/block (grid 1563, was 782 -> was grid-limited at
// 3 blk/CU, Occupancy 37%), 1 node x 4 cols per thread; writes only bf16 hs
// (agg init moved into k_agg).
// ---------------------------------------------------------------------------
__global__ __launch_bounds__(512) void k_h(const float* __restrict__ feat,
                                           const float* __restrict__ W1,
                                           const float* __restrict__ dinv,
                                           unsigned* __restrict__ hs16) {
    __shared__ float4 W1s4[F_IN * HID / 4];   // 32 KB, float4 = W1[k][jq*4..+3]
    int tid = threadIdx.x;
    {
        const float4* W1g = (const float4*)W1;
        #pragma unroll
        for (int i = 0; i < 4; i++) W1s4[tid + 512 * i] = W1g[tid + 512 * i];
    }
    __syncthreads();

    int jq = tid & 7;        // col group: cols jq*4..jq*4+3
    int ng = tid >> 3;       // 0..63
    int n  = blockIdx.x * 64 + ng;
    int nc = min(n, N_NODES - 1);

    const float4* f4 = (const float4*)feat;
    float4 a0 = {0, 0, 0, 0};

    #pragma unroll 8
    for (int k4 = 0; k4 < F_IN / 4; k4++) {
        float4 w0 = W1s4[(k4 * 4 + 0) * 8 + jq];
        float4 w1 = W1s4[(k4 * 4 + 1) * 8 + jq];
        float4 w2 = W1s4[(k4 * 4 + 2) * 8 + jq];
        float4 w3 = W1s4[(k4 * 4 + 3) * 8 + jq];
        float4 f0 = f4[(size_t)nc * (F_IN / 4) + k4];
        a0.x = fmaf(f0.x, w0.x, a0.x); a0.y = fmaf(f0.x, w0.y, a0.y);
        a0.z = fmaf(f0.x, w0.z, a0.z); a0.w = fmaf(f0.x, w0.w, a0.w);
        a0.x = fmaf(f0.y, w1.x, a0.x); a0.y = fmaf(f0.y, w1.y, a0.y);
        a0.z = fmaf(f0.y, w1.z, a0.z); a0.w = fmaf(f0.y, w1.w, a0.w);
        a0.x = fmaf(f0.z, w2.x, a0.x); a0.y = fmaf(f0.z, w2.y, a0.y);
        a0.z = fmaf(f0.z, w2.z, a0.z); a0.w = fmaf(f0.z, w2.w, a0.w);
        a0.x = fmaf(f0.w, w3.x, a0.x); a0.y = fmaf(f0.w, w3.y, a0.y);
        a0.z = fmaf(f0.w, w3.z, a0.z); a0.w = fmaf(f0.w, w3.w, a0.w);
    }

    if (n < N_NODES) {
        float di = dinv[n];
        unsigned p0 = pack_bf16x2(a0.x * di, a0.y * di);
        unsigned p1 = pack_bf16x2(a0.z * di, a0.w * di);
        *(uint2*)&hs16[(size_t)n * (HID / 2) + jq * 2] = make_uint2(p0, p1);
    }
}

// ---------------------------------------------------------------------------
// agg[c] = b1 + dinv[c] * (hs[c] + sum_{r in N(c)} hs[r])   (bf16 gathers)
// 16 lanes per node (each lane owns a hid PAIR in one uint32); 16 nodes per
// 256-thread block. One 64B line per edge gather.
// ---------------------------------------------------------------------------
__global__ __launch_bounds__(256) void k_agg(const int* __restrict__ off,
                                             const int* __restrict__ cnt,
                                             const int* __restrict__ csr,
                                             const unsigned* __restrict__ hs16,
                                             const float* __restrict__ dinv,
                                             const float* __restrict__ b1,
                                             float* __restrict__ agg) {
    int tid  = threadIdx.x;
    int j2   = tid & 15;                 // uint32 index in row (hid pair)
    int g    = tid >> 4;                 // 0..15
    int node = blockIdx.x * 16 + g;
    if (node >= N_NODES) return;

    int o = off[node];
    int n = cnt[node];

    unsigned ps = hs16[(size_t)node * 16 + j2];    // self-loop term
    float acc0 = bf16_lo(ps), acc1 = bf16_hi(ps);

    int i = 0;
    for (; i + 4 <= n; i += 4) {
        int r0 = csr[o + i + 0];
        int r1 = csr[o + i + 1];
        int r2 = csr[o + i + 2];
        int r3 = csr[o + i + 3];
        unsigned p0 = hs16[(size_t)r0 * 16 + j2];
        unsigned p1 = hs16[(size_t)r1 * 16 + j2];
        unsigned p2 = hs16[(size_t)r2 * 16 + j2];
        unsigned p3 = hs16[(size_t)r3 * 16 + j2];
        acc0 += (bf16_lo(p0) + bf16_lo(p1)) + (bf16_lo(p2) + bf16_lo(p3));
        acc1 += (bf16_hi(p0) + bf16_hi(p1)) + (bf16_hi(p2) + bf16_hi(p3));
    }
    for (; i < n; i++) {
        unsigned p = hs16[(size_t)csr[o + i] * 16 + j2];
        acc0 += bf16_lo(p);
        acc1 += bf16_hi(p);
    }

    float di = dinv[node];
    float2 ov;
    ov.x = b1[2 * j2 + 0] + acc0 * di;
    ov.y = b1[2 * j2 + 1] + acc1 * di;
    *(float2*)&agg[(size_t)node * HID + j2 * 2] = ov;
}

// ---------------------------------------------------------------------------
// out = log_softmax(relu(agg) @ W2 + b2)
// ---------------------------------------------------------------------------
__global__ __launch_bounds__(256) void k_out(const float* __restrict__ agg,
                                             const float* __restrict__ W2,
                                             const float* __restrict__ b2,
                                             float* __restrict__ out) {
    __shared__ float W2s[HID * NCLS];
    __shared__ float b2s[NCLS];
    int tid = threadIdx.x;
    for (int i = tid; i < HID * NCLS; i += 256) W2s[i] = W2[i];
    if (tid < NCLS) b2s[tid] = b2[tid];
    __syncthreads();

    int node = blockIdx.x * 256 + tid;
    if (node >= N_NODES) return;

    float a[HID];
    const float4* av = (const float4*)(agg + (size_t)node * HID);
    #pragma unroll
    for (int q = 0; q < HID / 4; q++) {
        float4 v = av[q];
        a[q * 4 + 0] = fmaxf(v.x, 0.f);
        a[q * 4 + 1] = fmaxf(v.y, 0.f);
        a[q * 4 + 2] = fmaxf(v.z, 0.f);
        a[q * 4 + 3] = fmaxf(v.w, 0.f);
    }

    float logits[NCLS];
    #pragma unroll
    for (int c = 0; c < NCLS; c++) {
        float s = b2s[c];
        #pragma unroll
        for (int k = 0; k < HID; k++) s = fmaf(a[k], W2s[k * NCLS + c], s);
        logits[c] = s;
    }

    float m = logits[0];
    #pragma unroll
    for (int c = 1; c < NCLS; c++) m = fmaxf(m, logits[c]);
    float se = 0.f;
    #pragma unroll
    for (int c = 0; c < NCLS; c++) se += expf(logits[c] - m);
    float lse = m + logf(se);
    #pragma unroll
    for (int c = 0; c < NCLS; c++) out[node * NCLS + c] = logits[c] - lse;
}

// ---------------------------------------------------------------------------
extern "C" void kernel_launch(void* const* d_in, const int* in_sizes, int n_in,
                              void* d_out, int out_size, void* d_ws, size_t ws_size,
                              hipStream_t stream) {
    const float* feat = (const float*)d_in[0];
    const void*  ei   = d_in[1];
    const float* W1   = (const float*)d_in[2];
    const float* b1   = (const float*)d_in[3];
    const float* W2   = (const float*)d_in[4];
    const float* b2   = (const float*)d_in[5];
    float* out = (float*)d_out;

    char* ws = (char*)d_ws;
    int*      flag   = (int*)(ws + OFF_FLAG);
    int*      bbase  = (int*)(ws + OFF_BB);
    int*      btot   = (int*)(ws + OFF_BT);
    int*      Bhist  = (int*)(ws + OFF_BH);
    int*      cnt    = (int*)(ws + OFF_CNT);
    int*      off    = (int*)(ws + OFF_OFF);
    float*    dinv   = (float*)(ws + OFF_DINV);
    int*      csr    = (int*)(ws + OFF_CSR);
    unsigned* binned = (unsigned*)(ws + OFF_BIN);
    unsigned* hs16   = (unsigned*)(ws + OFF_HS);   // overlays binned after k_p2
    float*    agg    = (float*)(ws + OFF_AGG);

    k_detect_idx64<<<1, 256, 0, stream>>>((const int*)ei, flag);
    k_p1hist<<<NBLK1, 1024, 0, stream>>>(ei, flag, Bhist);
    k_colscan<<<(NBUCK + 255) / 256, 256, 0, stream>>>(Bhist, btot);
    k_totscan<<<1, 1024, 0, stream>>>(btot, bbase);
    k_p1scat<<<NBLK1, 1024, 0, stream>>>(ei, flag, Bhist, bbase, binned);
    k_p2<<<NBUCK, 256, 0, stream>>>(binned, bbase, cnt, off, dinv, csr);

    k_h<<<(N_NODES + 63) / 64, 512, 0, stream>>>(feat, W1, dinv, hs16);
    k_agg<<<(N_NODES + 15) / 16, 256, 0, stream>>>(off, cnt, csr, hs16, dinv, b1, agg);
    k_out<<<(N_NODES + 255) / 256, 256, 0, stream>>>(agg, W2, b2, out);
}

// Round 13
// 203.247 us; speedup vs baseline: 3.0650x; 1.0996x over previous
//
#include <hip/hip_runtime.h>

constexpr int N_NODES = 100000;
constexpr int E_EDGES = 3200000;
constexpr int F_IN    = 256;
constexpr int HID     = 32;
constexpr int NCLS    = 10;

// bucketing: bucket = col >> 7  (128 target nodes per bucket)
constexpr int BUCK_SHIFT = 7;
constexpr int NPB        = 128;                          // nodes per bucket
constexpr int NBUCK      = (N_NODES + NPB - 1) / NPB;    // 782
constexpr int EPB        = 4096;                         // edges per pass-1 block
constexpr int NBLK1      = (E_EDGES + EPB - 1) / EPB;    // 782

// ---------------- ws layout (byte offsets) ----------------
constexpr size_t OFF_FLAG = 0;
constexpr size_t OFF_BB   = 4u << 10;
constexpr size_t OFF_BT   = 16u << 10;
constexpr size_t OFF_W1F  = 32u << 10;   // 16 KB fragment-ordered bf16 W1
constexpr size_t OFF_BH   = 1u << 20;
constexpr size_t OFF_CNT  = 4u << 20;
constexpr size_t OFF_OFF  = 5u << 20;
constexpr size_t OFF_DINV = 6u << 20;
constexpr size_t OFF_CSR  = 7u << 20;
constexpr size_t OFF_BIN  = 20u << 20;   // 12.8 MB packed edges
constexpr size_t OFF_HS   = 20u << 20;   // overlays binned (dead after k_p2)
constexpr size_t OFF_AGG  = 33u << 20;

typedef __attribute__((ext_vector_type(8))) short bf16x8;
typedef __attribute__((ext_vector_type(4))) float f32x4;

// bf16 helpers (RNE)
__device__ __forceinline__ unsigned pack_bf16x2(float a, float b) {
    unsigned ua = __float_as_uint(a), ub = __float_as_uint(b);
    ua = (ua + 0x7FFFu + ((ua >> 16) & 1u)) >> 16;
    ub = (ub + 0x7FFFu + ((ub >> 16) & 1u)) >> 16;
    return ua | (ub << 16);
}
__device__ __forceinline__ unsigned short bf16_rne(float x) {
    unsigned u = __float_as_uint(x);
    return (unsigned short)((u + 0x7FFFu + ((u >> 16) & 1u)) >> 16);
}
__device__ __forceinline__ float bf16_lo(unsigned p) { return __uint_as_float(p << 16); }
__device__ __forceinline__ float bf16_hi(unsigned p) { return __uint_as_float(p & 0xFFFF0000u); }

// ---------------------------------------------------------------------------
// edge_index dtype hedge: int64 storage has all-zero odd 32-bit words.
// ---------------------------------------------------------------------------
__global__ void k_detect_idx64(const int* __restrict__ ei32, int* __restrict__ flag) {
    __shared__ int nz;
    if (threadIdx.x == 0) nz = 0;
    __syncthreads();
    int acc = 0;
    for (int i = threadIdx.x; i < 1024; i += 256) acc |= ei32[2 * i + 1];
    if (acc != 0) atomicOr(&nz, 1);
    __syncthreads();
    if (threadIdx.x == 0) flag[0] = (nz == 0) ? 1 : 0;   // 1 => int64 storage
}

__device__ __forceinline__ int load_idx(const void* ei, long long i, int is64) {
    if (is64) return (int)((const long long*)ei)[i];
    return ((const int*)ei)[i];
}

// ---------------------------------------------------------------------------
// W1 -> bf16 in MFMA B-fragment order. frag f = ks*2 + t (ks = k-step, t =
// col-tile); lane l (kg=l>>4, col=l&15) holds W1[ks*32+kg*8+e][t*16+col],
// e=0..7 packed 2/u32. u32 index = (f*64 + lane)*4 + p, e = 2p, 2p+1.
// ---------------------------------------------------------------------------
__global__ void k_w1frag(const float* __restrict__ W1, unsigned* __restrict__ w1f) {
    int tid = threadIdx.x;
    for (int i = tid; i < 16 * 64 * 4; i += 256) {
        int p    = i & 3;
        int lane = (i >> 2) & 63;
        int f    = i >> 8;
        int ks = f >> 1, t = f & 1;
        int kg = lane >> 4, col = lane & 15;
        int k0 = ks * 32 + kg * 8 + p * 2;
        float w0 = W1[k0 * HID + t * 16 + col];
        float w1 = W1[(k0 + 1) * HID + t * 16 + col];
        w1f[i] = pack_bf16x2(w0, w1);
    }
}

// ---------------------------------------------------------------------------
// pass 1: bucket histogram (LDS), per-block dump. 1024 threads.
// ---------------------------------------------------------------------------
__global__ __launch_bounds__(1024) void k_p1hist(const void* __restrict__ ei,
                                                 const int* __restrict__ flag,
                                                 int* __restrict__ Bhist) {
    __shared__ int h[NBUCK];
    int tid = threadIdx.x, blk = blockIdx.x;
    for (int i = tid; i < NBUCK; i += 1024) h[i] = 0;
    __syncthreads();
    int is64 = flag[0];
    int base = blk * EPB;
    for (int k = tid; k < EPB; k += 1024) {
        int i = base + k;
        if (i >= E_EDGES) break;
        int c = load_idx(ei, (long long)E_EDGES + i, is64);
        atomicAdd(&h[c >> BUCK_SHIFT], 1);
    }
    __syncthreads();
    for (int i = tid; i < NBUCK; i += 1024) Bhist[blk * NBUCK + i] = h[i];
}

// per-bucket exclusive scan across blocks (in place); bucket totals out
__global__ __launch_bounds__(256) void k_colscan(int* __restrict__ Bhist,
                                                 int* __restrict__ bucketTot) {
    int j = blockIdx.x * 256 + threadIdx.x;
    if (j >= NBUCK) return;
    int acc = 0;
    int blk = 0;
    for (; blk + 4 <= NBLK1; blk += 4) {
        int i0 = (blk + 0) * NBUCK + j, i1 = (blk + 1) * NBUCK + j;
        int i2 = (blk + 2) * NBUCK + j, i3 = (blk + 3) * NBUCK + j;
        int v0 = Bhist[i0], v1 = Bhist[i1], v2 = Bhist[i2], v3 = Bhist[i3];
        Bhist[i0] = acc; acc += v0;
        Bhist[i1] = acc; acc += v1;
        Bhist[i2] = acc; acc += v2;
        Bhist[i3] = acc; acc += v3;
    }
    for (; blk < NBLK1; blk++) {
        int i0 = blk * NBUCK + j;
        int v = Bhist[i0]; Bhist[i0] = acc; acc += v;
    }
    bucketTot[j] = acc;
}

// exclusive scan of bucket totals -> bucketBase[0..NBUCK]
__global__ __launch_bounds__(1024) void k_totscan(const int* __restrict__ bucketTot,
                                                  int* __restrict__ bucketBase) {
    __shared__ int s[1024];
    int tid = threadIdx.x;
    int v = (tid < NBUCK) ? bucketTot[tid] : 0;
    s[tid] = v;
    __syncthreads();
    for (int d = 1; d < 1024; d <<= 1) {
        int t = (tid >= d) ? s[tid - d] : 0;
        __syncthreads();
        s[tid] += t;
        __syncthreads();
    }
    if (tid < NBUCK) bucketBase[tid] = s[tid] - v;
    if (tid == 1023) bucketBase[NBUCK] = s[1023];   // = E_EDGES
}

// pass 1 scatter: PACKED (r<<7 | c&127) into bucket segments, LDS cursors.
__global__ __launch_bounds__(1024) void k_p1scat(const void* __restrict__ ei,
                                                 const int* __restrict__ flag,
                                                 const int* __restrict__ Bhist,
                                                 const int* __restrict__ bucketBase,
                                                 unsigned* __restrict__ binned) {
    __shared__ int cur[NBUCK];
    int tid = threadIdx.x, blk = blockIdx.x;
    for (int i = tid; i < NBUCK; i += 1024)
        cur[i] = bucketBase[i] + Bhist[blk * NBUCK + i];
    __syncthreads();
    int is64 = flag[0];
    int base = blk * EPB;
    for (int k = tid; k < EPB; k += 1024) {
        int i = base + k;
        if (i >= E_EDGES) break;
        int r = load_idx(ei, i, is64);
        int c = load_idx(ei, (long long)E_EDGES + i, is64);
        int d = atomicAdd(&cur[c >> BUCK_SHIFT], 1);
        binned[d] = ((unsigned)r << BUCK_SHIFT) | ((unsigned)c & (NPB - 1));
    }
}

// pass 2: per bucket (128 nodes) counting-sort into csr; emits cnt/off/dinv
__global__ __launch_bounds__(256) void k_p2(const unsigned* __restrict__ binned,
                                            const int* __restrict__ bucketBase,
                                            int* __restrict__ cnt,
                                            int* __restrict__ off,
                                            float* __restrict__ dinv,
                                            int* __restrict__ csr) {
    __shared__ int lcnt[NPB], sc[NPB], lcur[NPB];
    int b = blockIdx.x, tid = threadIdx.x;
    int s = bucketBase[b], e = bucketBase[b + 1];
    if (tid < NPB) lcnt[tid] = 0;
    __syncthreads();
    for (int i = s + tid; i < e; i += 256)
        atomicAdd(&lcnt[binned[i] & (NPB - 1)], 1);
    __syncthreads();
    if (tid < NPB) sc[tid] = lcnt[tid];
    __syncthreads();
    for (int d = 1; d < NPB; d <<= 1) {
        int t = 0;
        if (tid < NPB && tid >= d) t = sc[tid - d];
        __syncthreads();
        if (tid < NPB) sc[tid] += t;
        __syncthreads();
    }
    if (tid < NPB) {
        int o = s + sc[tid] - lcnt[tid];     // exclusive
        lcur[tid] = o;
        int node = b * NPB + tid;
        if (node < N_NODES) {
            off[node]  = o;
            cnt[node]  = lcnt[tid];
            dinv[node] = rsqrtf((float)lcnt[tid] + 1.0f);   // +1 self-loop
        }
    }
    __syncthreads();
    for (int i = s + tid; i < e; i += 256) {
        unsigned p = binned[i];
        int pos = atomicAdd(&lcur[p & (NPB - 1)], 1);
        csr[pos] = (int)(p >> BUCK_SHIFT);
    }
}

// ---------------------------------------------------------------------------
// h = feature @ W1 via MFMA bf16; hs16 = bf16(h * dinv_row), ushort [node][32].
// One wave per 16-node batch (6250 batches). No LDS. B-frags (W1) loaded once
// per wave as 16 coalesced uint4 from w1f; A built inline from fp32 feature.
// mfma_f32_16x16x32_bf16 layouts: A row=lane&15 k=(lane>>4)*8+e; B col=lane&15
// same k; D col=lane&15 row=(lane>>4)*4+reg (m89-verified).
// ---------------------------------------------------------------------------
__global__ __launch_bounds__(256) void k_h(const float* __restrict__ feat,
                                           const unsigned* __restrict__ w1f,
                                           const float* __restrict__ dinv,
                                           unsigned short* __restrict__ hs16s) {
    int tid  = threadIdx.x;
    int lane = tid & 63;
    long wid = (long)blockIdx.x * 4 + (tid >> 6);
    int n0 = (int)(wid * 16);
    if (n0 >= N_NODES) return;

    // B fragments: 16 x coalesced uint4
    bf16x8 bfrag[16];
    const bf16x8* wv = (const bf16x8*)w1f;
    #pragma unroll
    for (int f = 0; f < 16; f++) bfrag[f] = wv[f * 64 + lane];

    int arow = lane & 15;     // A row / D col
    int kg   = lane >> 4;     // k-group
    const float4* fr = (const float4*)(feat + (size_t)(n0 + arow) * F_IN);

    f32x4 acc0 = {0.f, 0.f, 0.f, 0.f};
    f32x4 acc1 = {0.f, 0.f, 0.f, 0.f};

    #pragma unroll
    for (int ks = 0; ks < 8; ks++) {
        float4 fa = fr[ks * 8 + kg * 2 + 0];
        float4 fb = fr[ks * 8 + kg * 2 + 1];
        unsigned au[4];
        au[0] = pack_bf16x2(fa.x, fa.y);
        au[1] = pack_bf16x2(fa.z, fa.w);
        au[2] = pack_bf16x2(fb.x, fb.y);
        au[3] = pack_bf16x2(fb.z, fb.w);
        bf16x8 af = *(bf16x8*)au;
        acc0 = __builtin_amdgcn_mfma_f32_16x16x32_bf16(af, bfrag[ks * 2 + 0], acc0, 0, 0, 0);
        acc1 = __builtin_amdgcn_mfma_f32_16x16x32_bf16(af, bfrag[ks * 2 + 1], acc1, 0, 0, 0);
    }

    int rb = kg * 4;
    #pragma unroll
    for (int r = 0; r < 4; r++) {
        int node = n0 + rb + r;
        float di = dinv[node];
        hs16s[(size_t)node * HID + arow]      = bf16_rne(acc0[r] * di);
        hs16s[(size_t)node * HID + 16 + arow] = bf16_rne(acc1[r] * di);
    }
}

// ---------------------------------------------------------------------------
// agg[c] = b1 + dinv[c] * (hs[c] + sum_{r in N(c)} hs[r])   (bf16 gathers)
// 16 lanes per node (lane owns a hid PAIR as one uint32); 16 nodes/block.
// ---------------------------------------------------------------------------
__global__ __launch_bounds__(256) void k_agg(const int* __restrict__ off,
                                             const int* __restrict__ cnt,
                                             const int* __restrict__ csr,
                                             const unsigned* __restrict__ hs16,
                                             const float* __restrict__ dinv,
                                             const float* __restrict__ b1,
                                             float* __restrict__ agg) {
    int tid  = threadIdx.x;
    int j2   = tid & 15;                 // uint32 index in row (hid pair)
    int g    = tid >> 4;                 // 0..15
    int node = blockIdx.x * 16 + g;
    if (node >= N_NODES) return;

    int o = off[node];
    int n = cnt[node];

    unsigned ps = hs16[(size_t)node * 16 + j2];    // self-loop term
    float acc0 = bf16_lo(ps), acc1 = bf16_hi(ps);

    int i = 0;
    for (; i + 4 <= n; i += 4) {
        int r0 = csr[o + i + 0];
        int r1 = csr[o + i + 1];
        int r2 = csr[o + i + 2];
        int r3 = csr[o + i + 3];
        unsigned p0 = hs16[(size_t)r0 * 16 + j2];
        unsigned p1 = hs16[(size_t)r1 * 16 + j2];
        unsigned p2 = hs16[(size_t)r2 * 16 + j2];
        unsigned p3 = hs16[(size_t)r3 * 16 + j2];
        acc0 += (bf16_lo(p0) + bf16_lo(p1)) + (bf16_lo(p2) + bf16_lo(p3));
        acc1 += (bf16_hi(p0) + bf16_hi(p1)) + (bf16_hi(p2) + bf16_hi(p3));
    }
    for (; i < n; i++) {
        unsigned p = hs16[(size_t)csr[o + i] * 16 + j2];
        acc0 += bf16_lo(p);
        acc1 += bf16_hi(p);
    }

    float di = dinv[node];
    float2 ov;
    ov.x = b1[2 * j2 + 0] + acc0 * di;
    ov.y = b1[2 * j2 + 1] + acc1 * di;
    *(float2*)&agg[(size_t)node * HID + j2 * 2] = ov;
}

// ---------------------------------------------------------------------------
// out = log_softmax(relu(agg) @ W2 + b2)
// ---------------------------------------------------------------------------
__global__ __launch_bounds__(256) void k_out(const float* __restrict__ agg,
                                             const float* __restrict__ W2,
                                             const float* __restrict__ b2,
                                             float* __restrict__ out) {
    __shared__ float W2s[HID * NCLS];
    __shared__ float b2s[NCLS];
    int tid = threadIdx.x;
    for (int i = tid; i < HID * NCLS; i += 256) W2s[i] = W2[i];
    if (tid < NCLS) b2s[tid] = b2[tid];
    __syncthreads();

    int node = blockIdx.x * 256 + tid;
    if (node >= N_NODES) return;

    float a[HID];
    const float4* av = (const float4*)(agg + (size_t)node * HID);
    #pragma unroll
    for (int q = 0; q < HID / 4; q++) {
        float4 v = av[q];
        a[q * 4 + 0] = fmaxf(v.x, 0.f);
        a[q * 4 + 1] = fmaxf(v.y, 0.f);
        a[q * 4 + 2] = fmaxf(v.z, 0.f);
        a[q * 4 + 3] = fmaxf(v.w, 0.f);
    }

    float logits[NCLS];
    #pragma unroll
    for (int c = 0; c < NCLS; c++) {
        float s = b2s[c];
        #pragma unroll
        for (int k = 0; k < HID; k++) s = fmaf(a[k], W2s[k * NCLS + c], s);
        logits[c] = s;
    }

    float m = logits[0];
    #pragma unroll
    for (int c = 1; c < NCLS; c++) m = fmaxf(m, logits[c]);
    float se = 0.f;
    #pragma unroll
    for (int c = 0; c < NCLS; c++) se += expf(logits[c] - m);
    float lse = m + logf(se);
    #pragma unroll
    for (int c = 0; c < NCLS; c++) out[node * NCLS + c] = logits[c] - lse;
}

// ---------------------------------------------------------------------------
extern "C" void kernel_launch(void* const* d_in, const int* in_sizes, int n_in,
                              void* d_out, int out_size, void* d_ws, size_t ws_size,
                              hipStream_t stream) {
    const float* feat = (const float*)d_in[0];
    const void*  ei   = d_in[1];
    const float* W1   = (const float*)d_in[2];
    const float* b1   = (const float*)d_in[3];
    const float* W2   = (const float*)d_in[4];
    const float* b2   = (const float*)d_in[5];
    float* out = (float*)d_out;

    char* ws = (char*)d_ws;
    int*      flag   = (int*)(ws + OFF_FLAG);
    int*      bbase  = (int*)(ws + OFF_BB);
    int*      btot   = (int*)(ws + OFF_BT);
    unsigned* w1f    = (unsigned*)(ws + OFF_W1F);
    int*      Bhist  = (int*)(ws + OFF_BH);
    int*      cnt    = (int*)(ws + OFF_CNT);
    int*      off    = (int*)(ws + OFF_OFF);
    float*    dinv   = (float*)(ws + OFF_DINV);
    int*      csr    = (int*)(ws + OFF_CSR);
    unsigned* binned = (unsigned*)(ws + OFF_BIN);
    unsigned* hs16   = (unsigned*)(ws + OFF_HS);   // overlays binned after k_p2
    float*    agg    = (float*)(ws + OFF_AGG);

    k_detect_idx64<<<1, 256, 0, stream>>>((const int*)ei, flag);
    k_w1frag<<<1, 256, 0, stream>>>(W1, w1f);
    k_p1hist<<<NBLK1, 1024, 0, stream>>>(ei, flag, Bhist);
    k_colscan<<<(NBUCK + 255) / 256, 256, 0, stream>>>(Bhist, btot);
    k_totscan<<<1, 1024, 0, stream>>>(btot, bbase);
    k_p1scat<<<NBLK1, 1024, 0, stream>>>(ei, flag, Bhist, bbase, binned);
    k_p2<<<NBUCK, 256, 0, stream>>>(binned, bbase, cnt, off, dinv, csr);

    k_h<<<(N_NODES / 16 + 3) / 4, 256, 0, stream>>>(feat, w1f, dinv,
                                                    (unsigned short*)hs16);
    k_agg<<<(N_NODES + 15) / 16, 256, 0, stream>>>(off, cnt, csr, hs16, dinv, b1, agg);
    k_out<<<(N_NODES + 255) / 256, 256, 0, stream>>>(agg, W2, b2, out);
}

// Round 14
// 160.073 us; speedup vs baseline: 3.8917x; 1.2697x over previous
//
#include <hip/hip_runtime.h>

constexpr int N_NODES = 100000;
constexpr int E_EDGES = 3200000;
constexpr int F_IN    = 256;
constexpr int HID     = 32;
constexpr int NCLS    = 10;

// bucketing: bucket = col >> 7  (128 target nodes per bucket)
constexpr int BUCK_SHIFT = 7;
constexpr int NPB        = 128;                          // nodes per bucket
constexpr int NBUCK      = (N_NODES + NPB - 1) / NPB;    // 782
constexpr int EPB        = 4096;                         // edges per pass-1 block
constexpr int NBLK1      = (E_EDGES + EPB - 1) / EPB;    // 782

// ---------------- ws layout (byte offsets) ----------------
constexpr size_t OFF_FLAG = 0;
constexpr size_t OFF_BB   = 4u << 10;
constexpr size_t OFF_BT   = 16u << 10;
constexpr size_t OFF_W1F  = 32u << 10;   // 16 KB fragment-ordered bf16 W1
constexpr size_t OFF_BH   = 1u << 20;
constexpr size_t OFF_CNT  = 4u << 20;
constexpr size_t OFF_OFF  = 5u << 20;
constexpr size_t OFF_DINV = 6u << 20;
constexpr size_t OFF_CSR  = 7u << 20;
constexpr size_t OFF_BIN  = 20u << 20;   // 12.8 MB packed edges
constexpr size_t OFF_HS   = 20u << 20;   // overlays binned (dead after k_p2)

typedef __attribute__((ext_vector_type(8))) short bf16x8;
typedef __attribute__((ext_vector_type(4))) float f32x4;

// bf16 helpers (RNE)
__device__ __forceinline__ unsigned pack_bf16x2(float a, float b) {
    unsigned ua = __float_as_uint(a), ub = __float_as_uint(b);
    ua = (ua + 0x7FFFu + ((ua >> 16) & 1u)) >> 16;
    ub = (ub + 0x7FFFu + ((ub >> 16) & 1u)) >> 16;
    return ua | (ub << 16);
}
__device__ __forceinline__ unsigned short bf16_rne(float x) {
    unsigned u = __float_as_uint(x);
    return (unsigned short)((u + 0x7FFFu + ((u >> 16) & 1u)) >> 16);
}
__device__ __forceinline__ float bf16_lo(unsigned p) { return __uint_as_float(p << 16); }
__device__ __forceinline__ float bf16_hi(unsigned p) { return __uint_as_float(p & 0xFFFF0000u); }

// ---------------------------------------------------------------------------
// edge_index dtype hedge: int64 storage has all-zero odd 32-bit words.
// ---------------------------------------------------------------------------
__global__ void k_detect_idx64(const int* __restrict__ ei32, int* __restrict__ flag) {
    __shared__ int nz;
    if (threadIdx.x == 0) nz = 0;
    __syncthreads();
    int acc = 0;
    for (int i = threadIdx.x; i < 1024; i += 256) acc |= ei32[2 * i + 1];
    if (acc != 0) atomicOr(&nz, 1);
    __syncthreads();
    if (threadIdx.x == 0) flag[0] = (nz == 0) ? 1 : 0;   // 1 => int64 storage
}

__device__ __forceinline__ int load_idx(const void* ei, long long i, int is64) {
    if (is64) return (int)((const long long*)ei)[i];
    return ((const int*)ei)[i];
}

// ---------------------------------------------------------------------------
// W1 -> bf16 in MFMA B-fragment order (see k_h).
// ---------------------------------------------------------------------------
__global__ void k_w1frag(const float* __restrict__ W1, unsigned* __restrict__ w1f) {
    int tid = threadIdx.x;
    for (int i = tid; i < 16 * 64 * 4; i += 256) {
        int p    = i & 3;
        int lane = (i >> 2) & 63;
        int f    = i >> 8;
        int ks = f >> 1, t = f & 1;
        int kg = lane >> 4, col = lane & 15;
        int k0 = ks * 32 + kg * 8 + p * 2;
        float w0 = W1[k0 * HID + t * 16 + col];
        float w1 = W1[(k0 + 1) * HID + t * 16 + col];
        w1f[i] = pack_bf16x2(w0, w1);
    }
}

// ---------------------------------------------------------------------------
// pass 1: bucket histogram (LDS), per-block dump. 1024 threads.
// ---------------------------------------------------------------------------
__global__ __launch_bounds__(1024) void k_p1hist(const void* __restrict__ ei,
                                                 const int* __restrict__ flag,
                                                 int* __restrict__ Bhist) {
    __shared__ int h[NBUCK];
    int tid = threadIdx.x, blk = blockIdx.x;
    for (int i = tid; i < NBUCK; i += 1024) h[i] = 0;
    __syncthreads();
    int is64 = flag[0];
    int base = blk * EPB;
    for (int k = tid; k < EPB; k += 1024) {
        int i = base + k;
        if (i >= E_EDGES) break;
        int c = load_idx(ei, (long long)E_EDGES + i, is64);
        atomicAdd(&h[c >> BUCK_SHIFT], 1);
    }
    __syncthreads();
    for (int i = tid; i < NBUCK; i += 1024) Bhist[blk * NBUCK + i] = h[i];
}

// ---------------------------------------------------------------------------
// per-bucket exclusive scan across blocks (in place); bucket totals out.
// Round 13->14: one 64-lane WAVE per bucket (was one THREAD per bucket --
// 782 threads total on a 256-CU chip, pure latency). Shuffle scan + carry.
// ---------------------------------------------------------------------------
__global__ __launch_bounds__(256) void k_colscan(int* __restrict__ Bhist,
                                                 int* __restrict__ bucketTot) {
    int lane = threadIdx.x & 63;
    int j = blockIdx.x * 4 + (threadIdx.x >> 6);   // bucket
    if (j >= NBUCK) return;
    int carry = 0;
    for (int base = 0; base < NBLK1; base += 64) {
        int blk = base + lane;
        int v = (blk < NBLK1) ? Bhist[blk * NBUCK + j] : 0;
        int s = v;
        #pragma unroll
        for (int d = 1; d < 64; d <<= 1) {
            int t = __shfl_up(s, d, 64);
            if (lane >= d) s += t;
        }
        if (blk < NBLK1) Bhist[blk * NBUCK + j] = carry + s - v;   // exclusive
        carry += __shfl(s, 63, 64);
    }
    if (lane == 63) bucketTot[j] = carry;
}

// exclusive scan of bucket totals -> bucketBase[0..NBUCK]
__global__ __launch_bounds__(1024) void k_totscan(const int* __restrict__ bucketTot,
                                                  int* __restrict__ bucketBase) {
    __shared__ int s[1024];
    int tid = threadIdx.x;
    int v = (tid < NBUCK) ? bucketTot[tid] : 0;
    s[tid] = v;
    __syncthreads();
    for (int d = 1; d < 1024; d <<= 1) {
        int t = (tid >= d) ? s[tid - d] : 0;
        __syncthreads();
        s[tid] += t;
        __syncthreads();
    }
    if (tid < NBUCK) bucketBase[tid] = s[tid] - v;
    if (tid == 1023) bucketBase[NBUCK] = s[1023];   // = E_EDGES
}

// pass 1 scatter: PACKED (r<<7 | c&127) into bucket segments, LDS cursors.
__global__ __launch_bounds__(1024) void k_p1scat(const void* __restrict__ ei,
                                                 const int* __restrict__ flag,
                                                 const int* __restrict__ Bhist,
                                                 const int* __restrict__ bucketBase,
                                                 unsigned* __restrict__ binned) {
    __shared__ int cur[NBUCK];
    int tid = threadIdx.x, blk = blockIdx.x;
    for (int i = tid; i < NBUCK; i += 1024)
        cur[i] = bucketBase[i] + Bhist[blk * NBUCK + i];
    __syncthreads();
    int is64 = flag[0];
    int base = blk * EPB;
    for (int k = tid; k < EPB; k += 1024) {
        int i = base + k;
        if (i >= E_EDGES) break;
        int r = load_idx(ei, i, is64);
        int c = load_idx(ei, (long long)E_EDGES + i, is64);
        int d = atomicAdd(&cur[c >> BUCK_SHIFT], 1);
        binned[d] = ((unsigned)r << BUCK_SHIFT) | ((unsigned)c & (NPB - 1));
    }
}

// pass 2: per bucket (128 nodes) counting-sort into csr; emits cnt/off/dinv
__global__ __launch_bounds__(256) void k_p2(const unsigned* __restrict__ binned,
                                            const int* __restrict__ bucketBase,
                                            int* __restrict__ cnt,
                                            int* __restrict__ off,
                                            float* __restrict__ dinv,
                                            int* __restrict__ csr) {
    __shared__ int lcnt[NPB], sc[NPB], lcur[NPB];
    int b = blockIdx.x, tid = threadIdx.x;
    int s = bucketBase[b], e = bucketBase[b + 1];
    if (tid < NPB) lcnt[tid] = 0;
    __syncthreads();
    for (int i = s + tid; i < e; i += 256)
        atomicAdd(&lcnt[binned[i] & (NPB - 1)], 1);
    __syncthreads();
    if (tid < NPB) sc[tid] = lcnt[tid];
    __syncthreads();
    for (int d = 1; d < NPB; d <<= 1) {
        int t = 0;
        if (tid < NPB && tid >= d) t = sc[tid - d];
        __syncthreads();
        if (tid < NPB) sc[tid] += t;
        __syncthreads();
    }
    if (tid < NPB) {
        int o = s + sc[tid] - lcnt[tid];     // exclusive
        lcur[tid] = o;
        int node = b * NPB + tid;
        if (node < N_NODES) {
            off[node]  = o;
            cnt[node]  = lcnt[tid];
            dinv[node] = rsqrtf((float)lcnt[tid] + 1.0f);   // +1 self-loop
        }
    }
    __syncthreads();
    for (int i = s + tid; i < e; i += 256) {
        unsigned p = binned[i];
        int pos = atomicAdd(&lcur[p & (NPB - 1)], 1);
        csr[pos] = (int)(p >> BUCK_SHIFT);
    }
}

// ---------------------------------------------------------------------------
// h = feature @ W1 via MFMA bf16; hs16 = bf16(h * dinv_row), ushort [node][32].
// One wave per 16-node batch; no LDS (round-13 kernel, verified).
// ---------------------------------------------------------------------------
__global__ __launch_bounds__(256) void k_h(const float* __restrict__ feat,
                                           const unsigned* __restrict__ w1f,
                                           const float* __restrict__ dinv,
                                           unsigned short* __restrict__ hs16s) {
    int tid  = threadIdx.x;
    int lane = tid & 63;
    long wid = (long)blockIdx.x * 4 + (tid >> 6);
    int n0 = (int)(wid * 16);
    if (n0 >= N_NODES) return;

    bf16x8 bfrag[16];
    const bf16x8* wv = (const bf16x8*)w1f;
    #pragma unroll
    for (int f = 0; f < 16; f++) bfrag[f] = wv[f * 64 + lane];

    int arow = lane & 15;
    int kg   = lane >> 4;
    const float4* fr = (const float4*)(feat + (size_t)(n0 + arow) * F_IN);

    f32x4 acc0 = {0.f, 0.f, 0.f, 0.f};
    f32x4 acc1 = {0.f, 0.f, 0.f, 0.f};

    #pragma unroll
    for (int ks = 0; ks < 8; ks++) {
        float4 fa = fr[ks * 8 + kg * 2 + 0];
        float4 fb = fr[ks * 8 + kg * 2 + 1];
        unsigned au[4];
        au[0] = pack_bf16x2(fa.x, fa.y);
        au[1] = pack_bf16x2(fa.z, fa.w);
        au[2] = pack_bf16x2(fb.x, fb.y);
        au[3] = pack_bf16x2(fb.z, fb.w);
        bf16x8 af = *(bf16x8*)au;
        acc0 = __builtin_amdgcn_mfma_f32_16x16x32_bf16(af, bfrag[ks * 2 + 0], acc0, 0, 0, 0);
        acc1 = __builtin_amdgcn_mfma_f32_16x16x32_bf16(af, bfrag[ks * 2 + 1], acc1, 0, 0, 0);
    }

    int rb = kg * 4;
    #pragma unroll
    for (int r = 0; r < 4; r++) {
        int node = n0 + rb + r;
        float di = dinv[node];
        hs16s[(size_t)node * HID + arow]      = bf16_rne(acc0[r] * di);
        hs16s[(size_t)node * HID + 16 + arow] = bf16_rne(acc1[r] * di);
    }
}

// ---------------------------------------------------------------------------
// FUSED agg + relu + W2 matvec + log_softmax (round 13->14: deletes the
// 12.8MB agg intermediate). 16 lanes per node (lane owns a hid PAIR);
// 16 nodes per 256-thread block; grid 6250 (100000 % 16 == 0).
// Partial logits per lane -> shfl_xor(width=16) tree -> lanes 0..9 write.
// ---------------------------------------------------------------------------
__global__ __launch_bounds__(256) void k_aggout(const int* __restrict__ off,
                                                const int* __restrict__ cnt,
                                                const int* __restrict__ csr,
                                                const unsigned* __restrict__ hs16,
                                                const float* __restrict__ dinv,
                                                const float* __restrict__ b1,
                                                const float* __restrict__ W2,
                                                const float* __restrict__ b2,
                                                float* __restrict__ out) {
    __shared__ float W2s[HID * NCLS];   // [k][c]
    __shared__ float b2s[NCLS];
    int tid = threadIdx.x;
    for (int i = tid; i < HID * NCLS; i += 256) W2s[i] = W2[i];
    if (tid < NCLS) b2s[tid] = b2[tid];
    __syncthreads();

    int j2   = tid & 15;                 // hid pair index
    int g    = tid >> 4;
    int node = blockIdx.x * 16 + g;      // always < N_NODES (grid exact)

    int o = off[node];
    int n = cnt[node];

    unsigned ps = hs16[(size_t)node * 16 + j2];    // self-loop term
    float acc0 = bf16_lo(ps), acc1 = bf16_hi(ps);

    int i = 0;
    for (; i + 4 <= n; i += 4) {
        int r0 = csr[o + i + 0];
        int r1 = csr[o + i + 1];
        int r2 = csr[o + i + 2];
        int r3 = csr[o + i + 3];
        unsigned p0 = hs16[(size_t)r0 * 16 + j2];
        unsigned p1 = hs16[(size_t)r1 * 16 + j2];
        unsigned p2 = hs16[(size_t)r2 * 16 + j2];
        unsigned p3 = hs16[(size_t)r3 * 16 + j2];
        acc0 += (bf16_lo(p0) + bf16_lo(p1)) + (bf16_lo(p2) + bf16_lo(p3));
        acc1 += (bf16_hi(p0) + bf16_hi(p1)) + (bf16_hi(p2) + bf16_hi(p3));
    }
    for (; i < n; i++) {
        unsigned p = hs16[(size_t)csr[o + i] * 16 + j2];
        acc0 += bf16_lo(p);
        acc1 += bf16_hi(p);
    }

    float di = dinv[node];
    float a0 = fmaxf(b1[2 * j2 + 0] + acc0 * di, 0.f);
    float a1 = fmaxf(b1[2 * j2 + 1] + acc1 * di, 0.f);

    // partial logits for this lane's two k-slices
    float p[NCLS];
    #pragma unroll
    for (int c = 0; c < NCLS; c++)
        p[c] = a0 * W2s[(2 * j2 + 0) * NCLS + c] + a1 * W2s[(2 * j2 + 1) * NCLS + c];

    // reduce across the 16-lane group
    #pragma unroll
    for (int d = 1; d < 16; d <<= 1) {
        #pragma unroll
        for (int c = 0; c < NCLS; c++) p[c] += __shfl_xor(p[c], d, 16);
    }

    // all lanes now hold full logits (+bias); log_softmax
    #pragma unroll
    for (int c = 0; c < NCLS; c++) p[c] += b2s[c];
    float m = p[0];
    #pragma unroll
    for (int c = 1; c < NCLS; c++) m = fmaxf(m, p[c]);
    float se = 0.f;
    #pragma unroll
    for (int c = 0; c < NCLS; c++) se += expf(p[c] - m);
    float lse = m + logf(se);

    if (j2 < NCLS) {
        float myv = p[0];                 // static select chain (no dyn index)
        #pragma unroll
        for (int c = 1; c < NCLS; c++) myv = (j2 == c) ? p[c] : myv;
        out[(size_t)node * NCLS + j2] = myv - lse;
    }
}

// ---------------------------------------------------------------------------
extern "C" void kernel_launch(void* const* d_in, const int* in_sizes, int n_in,
                              void* d_out, int out_size, void* d_ws, size_t ws_size,
                              hipStream_t stream) {
    const float* feat = (const float*)d_in[0];
    const void*  ei   = d_in[1];
    const float* W1   = (const float*)d_in[2];
    const float* b1   = (const float*)d_in[3];
    const float* W2   = (const float*)d_in[4];
    const float* b2   = (const float*)d_in[5];
    float* out = (float*)d_out;

    char* ws = (char*)d_ws;
    int*      flag   = (int*)(ws + OFF_FLAG);
    int*      bbase  = (int*)(ws + OFF_BB);
    int*      btot   = (int*)(ws + OFF_BT);
    unsigned* w1f    = (unsigned*)(ws + OFF_W1F);
    int*      Bhist  = (int*)(ws + OFF_BH);
    int*      cnt    = (int*)(ws + OFF_CNT);
    int*      off    = (int*)(ws + OFF_OFF);
    float*    dinv   = (float*)(ws + OFF_DINV);
    int*      csr    = (int*)(ws + OFF_CSR);
    unsigned* binned = (unsigned*)(ws + OFF_BIN);
    unsigned* hs16   = (unsigned*)(ws + OFF_HS);   // overlays binned after k_p2

    k_detect_idx64<<<1, 256, 0, stream>>>((const int*)ei, flag);
    k_w1frag<<<1, 256, 0, stream>>>(W1, w1f);
    k_p1hist<<<NBLK1, 1024, 0, stream>>>(ei, flag, Bhist);
    k_colscan<<<(NBUCK + 3) / 4, 256, 0, stream>>>(Bhist, btot);
    k_totscan<<<1, 1024, 0, stream>>>(btot, bbase);
    k_p1scat<<<NBLK1, 1024, 0, stream>>>(ei, flag, Bhist, bbase, binned);
    k_p2<<<NBUCK, 256, 0, stream>>>(binned, bbase, cnt, off, dinv, csr);

    k_h<<<(N_NODES / 16 + 3) / 4, 256, 0, stream>>>(feat, w1f, dinv,
                                                    (unsigned short*)hs16);
    k_aggout<<<N_NODES / 16, 256, 0, stream>>>(off, cnt, csr, hs16, dinv,
                                               b1, W2, b2, out);
}

// Round 15
// 143.160 us; speedup vs baseline: 4.3514x; 1.1181x over previous
//
#include <hip/hip_runtime.h>

constexpr int N_NODES = 100000;
constexpr int E_EDGES = 3200000;
constexpr int F_IN    = 256;
constexpr int HID     = 32;
constexpr int NCLS    = 10;

// bucketing: bucket = col >> 7  (128 target nodes per bucket)
constexpr int BUCK_SHIFT = 7;
constexpr int NPB        = 128;                          // nodes per bucket
constexpr int NBUCK      = (N_NODES + NPB - 1) / NPB;    // 782
constexpr int EPB        = 4096;                         // edges per scat block
constexpr int NBLK1      = (E_EDGES + EPB - 1) / EPB;    // 782
constexpr int CAP        = 6144;   // fixed bucket capacity (mean 4092, sigma 64 -> 32-sigma margin)

// ---------------- ws layout (byte offsets) ----------------
constexpr size_t OFF_FLAG = 0;
constexpr size_t OFF_GCUR = 4u << 10;    // 782 ints
constexpr size_t OFF_BB   = 8u << 10;    // 783 ints dense bucket bases
constexpr size_t OFF_W1F  = 32u << 10;   // 16 KB fragment-ordered bf16 W1
constexpr size_t OFF_CNT  = 4u << 20;
constexpr size_t OFF_OFF  = 5u << 20;
constexpr size_t OFF_DINV = 6u << 20;
constexpr size_t OFF_CSR  = 7u << 20;    // dense, 12.8 MB
constexpr size_t OFF_BIN  = 20u << 20;   // sparse segments, 782*6144*4 = 19.2 MB
constexpr size_t OFF_HS   = 20u << 20;   // overlays binned (dead after k_p2)

typedef __attribute__((ext_vector_type(8))) short bf16x8;
typedef __attribute__((ext_vector_type(4))) float f32x4;

// bf16 helpers (RNE)
__device__ __forceinline__ unsigned pack_bf16x2(float a, float b) {
    unsigned ua = __float_as_uint(a), ub = __float_as_uint(b);
    ua = (ua + 0x7FFFu + ((ua >> 16) & 1u)) >> 16;
    ub = (ub + 0x7FFFu + ((ub >> 16) & 1u)) >> 16;
    return ua | (ub << 16);
}
__device__ __forceinline__ unsigned short bf16_rne(float x) {
    unsigned u = __float_as_uint(x);
    return (unsigned short)((u + 0x7FFFu + ((u >> 16) & 1u)) >> 16);
}
__device__ __forceinline__ float bf16_lo(unsigned p) { return __uint_as_float(p << 16); }
__device__ __forceinline__ float bf16_hi(unsigned p) { return __uint_as_float(p & 0xFFFF0000u); }

__device__ __forceinline__ int load_idx(const void* ei, long long i, int is64) {
    if (is64) return (int)((const long long*)ei)[i];
    return ((const int*)ei)[i];
}

// ---------------------------------------------------------------------------
// init: edge_index dtype detect (int64 storage has all-zero odd 32b words)
// + fixed-capacity bucket cursor init gcur[j] = j*CAP.
// ---------------------------------------------------------------------------
__global__ __launch_bounds__(1024) void k_init(const int* __restrict__ ei32,
                                               int* __restrict__ flag,
                                               int* __restrict__ gcur) {
    __shared__ int nz;
    int tid = threadIdx.x;
    if (tid == 0) nz = 0;
    __syncthreads();
    if (tid < 1024) {
        if (ei32[2 * tid + 1] != 0) atomicOr(&nz, 1);
    }
    __syncthreads();
    if (tid == 0) flag[0] = (nz == 0) ? 1 : 0;   // 1 => int64 storage
    if (tid < NBUCK) gcur[tid] = tid * CAP;
}

// ---------------------------------------------------------------------------
// W1 -> bf16 in MFMA B-fragment order (see k_h).
// ---------------------------------------------------------------------------
__global__ void k_w1frag(const float* __restrict__ W1, unsigned* __restrict__ w1f) {
    int tid = threadIdx.x;
    for (int i = tid; i < 16 * 64 * 4; i += 256) {
        int p    = i & 3;
        int lane = (i >> 2) & 63;
        int f    = i >> 8;
        int ks = f >> 1, t = f & 1;
        int kg = lane >> 4, col = lane & 15;
        int k0 = ks * 32 + kg * 8 + p * 2;
        float w0 = W1[k0 * HID + t * 16 + col];
        float w1 = W1[(k0 + 1) * HID + t * 16 + col];
        w1f[i] = pack_bf16x2(w0, w1);
    }
}

// ---------------------------------------------------------------------------
// ONE-PASS bucketed scatter (round 14->15: replaces p1hist+colscan+totscan+
// p1scat; edge_index read exactly once). Per 4096-edge block: stage (val,
// bucket) in LDS, LDS histogram, reserve a range per bucket with ONE global
// atomicAdd into the bucket's fixed segment, LDS-cursor scatter.
// ---------------------------------------------------------------------------
__global__ __launch_bounds__(1024) void k_scat(const void* __restrict__ ei,
                                               const int* __restrict__ flag,
                                               int* __restrict__ gcur,
                                               unsigned* __restrict__ binned) {
    __shared__ unsigned       sval[EPB];     // 16 KB packed (r<<7 | c&127)
    __shared__ unsigned short sbuck[EPB];    // 8 KB bucket ids
    __shared__ int h[NBUCK];                 // 3.1 KB
    __shared__ int cur[NBUCK];               // 3.1 KB
    int tid = threadIdx.x, blk = blockIdx.x;
    for (int i = tid; i < NBUCK; i += 1024) h[i] = 0;
    __syncthreads();

    int is64 = flag[0];
    int base = blk * EPB;
    int nedge = min(EPB, E_EDGES - base);
    for (int k = tid; k < nedge; k += 1024) {
        int i = base + k;
        int r = load_idx(ei, i, is64);
        int c = load_idx(ei, (long long)E_EDGES + i, is64);
        int b = c >> BUCK_SHIFT;
        sval[k]  = ((unsigned)r << BUCK_SHIFT) | ((unsigned)c & (NPB - 1));
        sbuck[k] = (unsigned short)b;
        atomicAdd(&h[b], 1);
    }
    __syncthreads();

    for (int j = tid; j < NBUCK; j += 1024) {
        int c = h[j];
        cur[j] = (c > 0) ? atomicAdd(&gcur[j], c) : 0;
    }
    __syncthreads();

    for (int k = tid; k < nedge; k += 1024) {
        int d = atomicAdd(&cur[sbuck[k]], 1);
        binned[d] = sval[k];
    }
}

// dense exclusive scan of final bucket counts (gcur[b] - b*CAP) -> bucketBase
__global__ __launch_bounds__(1024) void k_bscan(const int* __restrict__ gcur,
                                                int* __restrict__ bucketBase) {
    __shared__ int s[1024];
    int tid = threadIdx.x;
    int v = (tid < NBUCK) ? (gcur[tid] - tid * CAP) : 0;
    s[tid] = v;
    __syncthreads();
    for (int d = 1; d < 1024; d <<= 1) {
        int t = (tid >= d) ? s[tid - d] : 0;
        __syncthreads();
        s[tid] += t;
        __syncthreads();
    }
    if (tid < NBUCK) bucketBase[tid] = s[tid] - v;
    if (tid == 1023) bucketBase[NBUCK] = s[1023];   // = E_EDGES
}

// ---------------------------------------------------------------------------
// pass 2: per bucket (128 nodes) counting-sort sparse binned segment ->
// dense csr; emits cnt/off/dinv.
// ---------------------------------------------------------------------------
__global__ __launch_bounds__(256) void k_p2(const unsigned* __restrict__ binned,
                                            const int* __restrict__ gcur,
                                            const int* __restrict__ bucketBase,
                                            int* __restrict__ cnt,
                                            int* __restrict__ off,
                                            float* __restrict__ dinv,
                                            int* __restrict__ csr) {
    __shared__ int lcnt[NPB], sc[NPB], lcur[NPB];
    int b = blockIdx.x, tid = threadIdx.x;
    int s = b * CAP, e = gcur[b];        // sparse segment
    int db = bucketBase[b];              // dense base
    if (tid < NPB) lcnt[tid] = 0;
    __syncthreads();
    for (int i = s + tid; i < e; i += 256)
        atomicAdd(&lcnt[binned[i] & (NPB - 1)], 1);
    __syncthreads();
    if (tid < NPB) sc[tid] = lcnt[tid];
    __syncthreads();
    for (int d = 1; d < NPB; d <<= 1) {
        int t = 0;
        if (tid < NPB && tid >= d) t = sc[tid - d];
        __syncthreads();
        if (tid < NPB) sc[tid] += t;
        __syncthreads();
    }
    if (tid < NPB) {
        int o = db + sc[tid] - lcnt[tid];     // dense exclusive
        lcur[tid] = o;
        int node = b * NPB + tid;
        if (node < N_NODES) {
            off[node]  = o;
            cnt[node]  = lcnt[tid];
            dinv[node] = rsqrtf((float)lcnt[tid] + 1.0f);   // +1 self-loop
        }
    }
    __syncthreads();
    for (int i = s + tid; i < e; i += 256) {
        unsigned p = binned[i];
        int pos = atomicAdd(&lcur[p & (NPB - 1)], 1);
        csr[pos] = (int)(p >> BUCK_SHIFT);
    }
}

// ---------------------------------------------------------------------------
// h = feature @ W1 via MFMA bf16; hs16 = bf16(h * dinv_row), ushort [node][32].
// One wave per 16-node batch; no LDS (round-13 kernel, verified).
// ---------------------------------------------------------------------------
__global__ __launch_bounds__(256) void k_h(const float* __restrict__ feat,
                                           const unsigned* __restrict__ w1f,
                                           const float* __restrict__ dinv,
                                           unsigned short* __restrict__ hs16s) {
    int tid  = threadIdx.x;
    int lane = tid & 63;
    long wid = (long)blockIdx.x * 4 + (tid >> 6);
    int n0 = (int)(wid * 16);
    if (n0 >= N_NODES) return;

    bf16x8 bfrag[16];
    const bf16x8* wv = (const bf16x8*)w1f;
    #pragma unroll
    for (int f = 0; f < 16; f++) bfrag[f] = wv[f * 64 + lane];

    int arow = lane & 15;
    int kg   = lane >> 4;
    const float4* fr = (const float4*)(feat + (size_t)(n0 + arow) * F_IN);

    f32x4 acc0 = {0.f, 0.f, 0.f, 0.f};
    f32x4 acc1 = {0.f, 0.f, 0.f, 0.f};

    #pragma unroll
    for (int ks = 0; ks < 8; ks++) {
        float4 fa = fr[ks * 8 + kg * 2 + 0];
        float4 fb = fr[ks * 8 + kg * 2 + 1];
        unsigned au[4];
        au[0] = pack_bf16x2(fa.x, fa.y);
        au[1] = pack_bf16x2(fa.z, fa.w);
        au[2] = pack_bf16x2(fb.x, fb.y);
        au[3] = pack_bf16x2(fb.z, fb.w);
        bf16x8 af = *(bf16x8*)au;
        acc0 = __builtin_amdgcn_mfma_f32_16x16x32_bf16(af, bfrag[ks * 2 + 0], acc0, 0, 0, 0);
        acc1 = __builtin_amdgcn_mfma_f32_16x16x32_bf16(af, bfrag[ks * 2 + 1], acc1, 0, 0, 0);
    }

    int rb = kg * 4;
    #pragma unroll
    for (int r = 0; r < 4; r++) {
        int node = n0 + rb + r;
        float di = dinv[node];
        hs16s[(size_t)node * HID + arow]      = bf16_rne(acc0[r] * di);
        hs16s[(size_t)node * HID + 16 + arow] = bf16_rne(acc1[r] * di);
    }
}

// ---------------------------------------------------------------------------
// FUSED agg + relu + W2 matvec + log_softmax. 16 lanes per node (lane owns a
// hid PAIR); 16 nodes per 256-thread block; grid 6250 exact.
// ---------------------------------------------------------------------------
__global__ __launch_bounds__(256) void k_aggout(const int* __restrict__ off,
                                                const int* __restrict__ cnt,
                                                const int* __restrict__ csr,
                                                const unsigned* __restrict__ hs16,
                                                const float* __restrict__ dinv,
                                                const float* __restrict__ b1,
                                                const float* __restrict__ W2,
                                                const float* __restrict__ b2,
                                                float* __restrict__ out) {
    __shared__ float W2s[HID * NCLS];   // [k][c]
    __shared__ float b2s[NCLS];
    int tid = threadIdx.x;
    for (int i = tid; i < HID * NCLS; i += 256) W2s[i] = W2[i];
    if (tid < NCLS) b2s[tid] = b2[tid];
    __syncthreads();

    int j2   = tid & 15;                 // hid pair index
    int g    = tid >> 4;
    int node = blockIdx.x * 16 + g;      // always < N_NODES (grid exact)

    int o = off[node];
    int n = cnt[node];

    unsigned ps = hs16[(size_t)node * 16 + j2];    // self-loop term
    float acc0 = bf16_lo(ps), acc1 = bf16_hi(ps);

    int i = 0;
    for (; i + 4 <= n; i += 4) {
        int r0 = csr[o + i + 0];
        int r1 = csr[o + i + 1];
        int r2 = csr[o + i + 2];
        int r3 = csr[o + i + 3];
        unsigned p0 = hs16[(size_t)r0 * 16 + j2];
        unsigned p1 = hs16[(size_t)r1 * 16 + j2];
        unsigned p2 = hs16[(size_t)r2 * 16 + j2];
        unsigned p3 = hs16[(size_t)r3 * 16 + j2];
        acc0 += (bf16_lo(p0) + bf16_lo(p1)) + (bf16_lo(p2) + bf16_lo(p3));
        acc1 += (bf16_hi(p0) + bf16_hi(p1)) + (bf16_hi(p2) + bf16_hi(p3));
    }
    for (; i < n; i++) {
        unsigned p = hs16[(size_t)csr[o + i] * 16 + j2];
        acc0 += bf16_lo(p);
        acc1 += bf16_hi(p);
    }

    float di = dinv[node];
    float a0 = fmaxf(b1[2 * j2 + 0] + acc0 * di, 0.f);
    float a1 = fmaxf(b1[2 * j2 + 1] + acc1 * di, 0.f);

    float p[NCLS];
    #pragma unroll
    for (int c = 0; c < NCLS; c++)
        p[c] = a0 * W2s[(2 * j2 + 0) * NCLS + c] + a1 * W2s[(2 * j2 + 1) * NCLS + c];

    #pragma unroll
    for (int d = 1; d < 16; d <<= 1) {
        #pragma unroll
        for (int c = 0; c < NCLS; c++) p[c] += __shfl_xor(p[c], d, 16);
    }

    #pragma unroll
    for (int c = 0; c < NCLS; c++) p[c] += b2s[c];
    float m = p[0];
    #pragma unroll
    for (int c = 1; c < NCLS; c++) m = fmaxf(m, p[c]);
    float se = 0.f;
    #pragma unroll
    for (int c = 0; c < NCLS; c++) se += expf(p[c] - m);
    float lse = m + logf(se);

    if (j2 < NCLS) {
        float myv = p[0];
        #pragma unroll
        for (int c = 1; c < NCLS; c++) myv = (j2 == c) ? p[c] : myv;
        out[(size_t)node * NCLS + j2] = myv - lse;
    }
}

// ---------------------------------------------------------------------------
extern "C" void kernel_launch(void* const* d_in, const int* in_sizes, int n_in,
                              void* d_out, int out_size, void* d_ws, size_t ws_size,
                              hipStream_t stream) {
    const float* feat = (const float*)d_in[0];
    const void*  ei   = d_in[1];
    const float* W1   = (const float*)d_in[2];
    const float* b1   = (const float*)d_in[3];
    const float* W2   = (const float*)d_in[4];
    const float* b2   = (const float*)d_in[5];
    float* out = (float*)d_out;

    char* ws = (char*)d_ws;
    int*      flag   = (int*)(ws + OFF_FLAG);
    int*      gcur   = (int*)(ws + OFF_GCUR);
    int*      bbase  = (int*)(ws + OFF_BB);
    unsigned* w1f    = (unsigned*)(ws + OFF_W1F);
    int*      cnt    = (int*)(ws + OFF_CNT);
    int*      off    = (int*)(ws + OFF_OFF);
    float*    dinv   = (float*)(ws + OFF_DINV);
    int*      csr    = (int*)(ws + OFF_CSR);
    unsigned* binned = (unsigned*)(ws + OFF_BIN);
    unsigned* hs16   = (unsigned*)(ws + OFF_HS);   // overlays binned after k_p2

    k_init<<<1, 1024, 0, stream>>>((const int*)ei, flag, gcur);
    k_w1frag<<<1, 256, 0, stream>>>(W1, w1f);
    k_scat<<<NBLK1, 1024, 0, stream>>>(ei, flag, gcur, binned);
    k_bscan<<<1, 1024, 0, stream>>>(gcur, bbase);
    k_p2<<<NBUCK, 256, 0, stream>>>(binned, gcur, bbase, cnt, off, dinv, csr);

    k_h<<<(N_NODES / 16 + 3) / 4, 256, 0, stream>>>(feat, w1f, dinv,
                                                    (unsigned short*)hs16);
    k_aggout<<<N_NODES / 16, 256, 0, stream>>>(off, cnt, csr, hs16, dinv,
                                               b1, W2, b2, out);
}

// Round 16
// 132.899 us; speedup vs baseline: 4.6874x; 1.0772x over previous
//
#include <hip/hip_runtime.h>

constexpr int N_NODES = 100000;
constexpr int E_EDGES = 3200000;
constexpr int F_IN    = 256;
constexpr int HID     = 32;
constexpr int NCLS    = 10;

// bucketing: bucket = col >> 7  (128 target nodes per bucket)
constexpr int BUCK_SHIFT = 7;
constexpr int NPB        = 128;                          // nodes per bucket
constexpr int NBUCK      = (N_NODES + NPB - 1) / NPB;    // 782
constexpr int EPB        = 8192;                         // edges per scat block
constexpr int NBLK1      = (E_EDGES + EPB - 1) / EPB;    // 391
constexpr int CAP        = 6144;   // fixed bucket capacity (mean 4092, sigma 64)

// ---------------- ws layout (byte offsets) ----------------
constexpr size_t OFF_FLAG = 0;
constexpr size_t OFF_GCUR = 4u << 10;    // 782 ints
constexpr size_t OFF_BB   = 8u << 10;    // 783 ints dense bucket bases
constexpr size_t OFF_W1F  = 32u << 10;   // 16 KB fragment-ordered bf16 W1
constexpr size_t OFF_CNT  = 4u << 20;
constexpr size_t OFF_OFF  = 5u << 20;
constexpr size_t OFF_DINV = 6u << 20;
constexpr size_t OFF_CSR  = 7u << 20;    // dense, 12.8 MB
constexpr size_t OFF_BIN  = 20u << 20;   // sparse segments, 782*6144*4 = 19.2 MB
constexpr size_t OFF_HS   = 20u << 20;   // overlays binned (dead after k_p2)

typedef __attribute__((ext_vector_type(8))) short bf16x8;
typedef __attribute__((ext_vector_type(4))) float f32x4;

// bf16 helpers (RNE)
__device__ __forceinline__ unsigned pack_bf16x2(float a, float b) {
    unsigned ua = __float_as_uint(a), ub = __float_as_uint(b);
    ua = (ua + 0x7FFFu + ((ua >> 16) & 1u)) >> 16;
    ub = (ub + 0x7FFFu + ((ub >> 16) & 1u)) >> 16;
    return ua | (ub << 16);
}
__device__ __forceinline__ unsigned short bf16_rne(float x) {
    unsigned u = __float_as_uint(x);
    return (unsigned short)((u + 0x7FFFu + ((u >> 16) & 1u)) >> 16);
}
__device__ __forceinline__ float bf16_lo(unsigned p) { return __uint_as_float(p << 16); }
__device__ __forceinline__ float bf16_hi(unsigned p) { return __uint_as_float(p & 0xFFFF0000u); }

__device__ __forceinline__ int load_idx(const void* ei, long long i, int is64) {
    if (is64) return (int)((const long long*)ei)[i];
    return ((const int*)ei)[i];
}

// ---------------------------------------------------------------------------
// init: edge_index dtype detect + bucket cursor init gcur[j] = j*CAP.
// ---------------------------------------------------------------------------
__global__ __launch_bounds__(1024) void k_init(const int* __restrict__ ei32,
                                               int* __restrict__ flag,
                                               int* __restrict__ gcur) {
    __shared__ int nz;
    int tid = threadIdx.x;
    if (tid == 0) nz = 0;
    __syncthreads();
    if (ei32[2 * tid + 1] != 0) atomicOr(&nz, 1);
    __syncthreads();
    if (tid == 0) flag[0] = (nz == 0) ? 1 : 0;   // 1 => int64 storage
    if (tid < NBUCK) gcur[tid] = tid * CAP;
}

// ---------------------------------------------------------------------------
// W1 -> bf16 in MFMA B-fragment order (see k_h).
// ---------------------------------------------------------------------------
__global__ void k_w1frag(const float* __restrict__ W1, unsigned* __restrict__ w1f) {
    int tid = threadIdx.x;
    for (int i = tid; i < 16 * 64 * 4; i += 256) {
        int p    = i & 3;
        int lane = (i >> 2) & 63;
        int f    = i >> 8;
        int ks = f >> 1, t = f & 1;
        int kg = lane >> 4, col = lane & 15;
        int k0 = ks * 32 + kg * 8 + p * 2;
        float w0 = W1[k0 * HID + t * 16 + col];
        float w1 = W1[(k0 + 1) * HID + t * 16 + col];
        w1f[i] = pack_bf16x2(w0, w1);
    }
}

// ---------------------------------------------------------------------------
// ONE-PASS bucketed scatter. Round 15->16: EPB 4096->8192 (halves binned
// write fragmentation: ~21B -> ~42B mean runs; halves reservation atomics).
// ---------------------------------------------------------------------------
__global__ __launch_bounds__(1024) void k_scat(const void* __restrict__ ei,
                                               const int* __restrict__ flag,
                                               int* __restrict__ gcur,
                                               unsigned* __restrict__ binned) {
    __shared__ unsigned       sval[EPB];     // 32 KB packed (r<<7 | c&127)
    __shared__ unsigned short sbuck[EPB];    // 16 KB bucket ids
    __shared__ int h[NBUCK];                 // 3.1 KB
    __shared__ int cur[NBUCK];               // 3.1 KB
    int tid = threadIdx.x, blk = blockIdx.x;
    for (int i = tid; i < NBUCK; i += 1024) h[i] = 0;
    __syncthreads();

    int is64 = flag[0];
    int base = blk * EPB;
    int nedge = min(EPB, E_EDGES - base);
    for (int k = tid; k < nedge; k += 1024) {
        int i = base + k;
        int r = load_idx(ei, i, is64);
        int c = load_idx(ei, (long long)E_EDGES + i, is64);
        int b = c >> BUCK_SHIFT;
        sval[k]  = ((unsigned)r << BUCK_SHIFT) | ((unsigned)c & (NPB - 1));
        sbuck[k] = (unsigned short)b;
        atomicAdd(&h[b], 1);
    }
    __syncthreads();

    for (int j = tid; j < NBUCK; j += 1024) {
        int c = h[j];
        cur[j] = (c > 0) ? atomicAdd(&gcur[j], c) : 0;
    }
    __syncthreads();

    for (int k = tid; k < nedge; k += 1024) {
        int d = atomicAdd(&cur[sbuck[k]], 1);
        binned[d] = sval[k];
    }
}

// dense exclusive scan of final bucket counts (gcur[b] - b*CAP) -> bucketBase
__global__ __launch_bounds__(1024) void k_bscan(const int* __restrict__ gcur,
                                                int* __restrict__ bucketBase) {
    __shared__ int s[1024];
    int tid = threadIdx.x;
    int v = (tid < NBUCK) ? (gcur[tid] - tid * CAP) : 0;
    s[tid] = v;
    __syncthreads();
    for (int d = 1; d < 1024; d <<= 1) {
        int t = (tid >= d) ? s[tid - d] : 0;
        __syncthreads();
        s[tid] += t;
        __syncthreads();
    }
    if (tid < NBUCK) bucketBase[tid] = s[tid] - v;
    if (tid == 1023) bucketBase[NBUCK] = s[1023];   // = E_EDGES
}

// ---------------------------------------------------------------------------
// pass 2: per bucket (128 nodes) counting-sort sparse binned segment ->
// dense csr; emits cnt/off/dinv. Round 15->16: 512 threads.
// ---------------------------------------------------------------------------
__global__ __launch_bounds__(512) void k_p2(const unsigned* __restrict__ binned,
                                            const int* __restrict__ gcur,
                                            const int* __restrict__ bucketBase,
                                            int* __restrict__ cnt,
                                            int* __restrict__ off,
                                            float* __restrict__ dinv,
                                            int* __restrict__ csr) {
    __shared__ int lcnt[NPB], sc[NPB], lcur[NPB];
    int b = blockIdx.x, tid = threadIdx.x;
    int s = b * CAP, e = gcur[b];        // sparse segment
    int db = bucketBase[b];              // dense base
    if (tid < NPB) lcnt[tid] = 0;
    __syncthreads();
    for (int i = s + tid; i < e; i += 512)
        atomicAdd(&lcnt[binned[i] & (NPB - 1)], 1);
    __syncthreads();
    if (tid < NPB) sc[tid] = lcnt[tid];
    __syncthreads();
    for (int d = 1; d < NPB; d <<= 1) {
        int t = 0;
        if (tid < NPB && tid >= d) t = sc[tid - d];
        __syncthreads();
        if (tid < NPB) sc[tid] += t;
        __syncthreads();
    }
    if (tid < NPB) {
        int o = db + sc[tid] - lcnt[tid];     // dense exclusive
        lcur[tid] = o;
        int node = b * NPB + tid;
        if (node < N_NODES) {
            off[node]  = o;
            cnt[node]  = lcnt[tid];
            dinv[node] = rsqrtf((float)lcnt[tid] + 1.0f);   // +1 self-loop
        }
    }
    __syncthreads();
    for (int i = s + tid; i < e; i += 512) {
        unsigned p = binned[i];
        int pos = atomicAdd(&lcur[p & (NPB - 1)], 1);
        csr[pos] = (int)(p >> BUCK_SHIFT);
    }
}

// ---------------------------------------------------------------------------
// h = feature @ W1 via MFMA bf16; hs16 = bf16(h * dinv_row), ushort [node][32].
// One wave per 16-node batch; no LDS (round-13 kernel, verified).
// ---------------------------------------------------------------------------
__global__ __launch_bounds__(256) void k_h(const float* __restrict__ feat,
                                           const unsigned* __restrict__ w1f,
                                           const float* __restrict__ dinv,
                                           unsigned short* __restrict__ hs16s) {
    int tid  = threadIdx.x;
    int lane = tid & 63;
    long wid = (long)blockIdx.x * 4 + (tid >> 6);
    int n0 = (int)(wid * 16);
    if (n0 >= N_NODES) return;

    bf16x8 bfrag[16];
    const bf16x8* wv = (const bf16x8*)w1f;
    #pragma unroll
    for (int f = 0; f < 16; f++) bfrag[f] = wv[f * 64 + lane];

    int arow = lane & 15;
    int kg   = lane >> 4;
    const float4* fr = (const float4*)(feat + (size_t)(n0 + arow) * F_IN);

    f32x4 acc0 = {0.f, 0.f, 0.f, 0.f};
    f32x4 acc1 = {0.f, 0.f, 0.f, 0.f};

    #pragma unroll
    for (int ks = 0; ks < 8; ks++) {
        float4 fa = fr[ks * 8 + kg * 2 + 0];
        float4 fb = fr[ks * 8 + kg * 2 + 1];
        unsigned au[4];
        au[0] = pack_bf16x2(fa.x, fa.y);
        au[1] = pack_bf16x2(fa.z, fa.w);
        au[2] = pack_bf16x2(fb.x, fb.y);
        au[3] = pack_bf16x2(fb.z, fb.w);
        bf16x8 af = *(bf16x8*)au;
        acc0 = __builtin_amdgcn_mfma_f32_16x16x32_bf16(af, bfrag[ks * 2 + 0], acc0, 0, 0, 0);
        acc1 = __builtin_amdgcn_mfma_f32_16x16x32_bf16(af, bfrag[ks * 2 + 1], acc1, 0, 0, 0);
    }

    int rb = kg * 4;
    #pragma unroll
    for (int r = 0; r < 4; r++) {
        int node = n0 + rb + r;
        float di = dinv[node];
        hs16s[(size_t)node * HID + arow]      = bf16_rne(acc0[r] * di);
        hs16s[(size_t)node * HID + 16 + arow] = bf16_rne(acc1[r] * di);
    }
}

// ---------------------------------------------------------------------------
// FUSED agg + relu + W2 matvec + log_softmax.
// Round 15->16: 4 lanes per node, uint4 (16B) gathers -- 4x fewer VMEM
// instructions, 64B in flight per lane (was 16B). 64 nodes per 256-thread
// block; logits reduced over 4 lanes; lane l2 writes classes {l2, l2+4, l2+8}.
// ---------------------------------------------------------------------------
__global__ __launch_bounds__(256) void k_aggout(const int* __restrict__ off,
                                                const int* __restrict__ cnt,
                                                const int* __restrict__ csr,
                                                const unsigned* __restrict__ hs16,
                                                const float* __restrict__ dinv,
                                                const float* __restrict__ b1,
                                                const float* __restrict__ W2,
                                                const float* __restrict__ b2,
                                                float* __restrict__ out) {
    __shared__ float W2s[HID * NCLS];   // [k][c]
    __shared__ float b2s[NCLS];
    int tid = threadIdx.x;
    for (int i = tid; i < HID * NCLS; i += 256) W2s[i] = W2[i];
    if (tid < NCLS) b2s[tid] = b2[tid];
    __syncthreads();

    int l2   = tid & 3;                  // quarter-row: hid 8*l2 .. 8*l2+7
    int g    = tid >> 2;                 // 0..63
    int node = blockIdx.x * 64 + g;
    if (node >= N_NODES) return;

    int o = off[node];
    int n = cnt[node];

    const uint4* hsv = (const uint4*)hs16;     // row = 4 uint4
    uint4 ps = hsv[(size_t)node * 4 + l2];     // self-loop term
    float a0 = bf16_lo(ps.x), a1 = bf16_hi(ps.x);
    float a2 = bf16_lo(ps.y), a3 = bf16_hi(ps.y);
    float a4 = bf16_lo(ps.z), a5 = bf16_hi(ps.z);
    float a6 = bf16_lo(ps.w), a7 = bf16_hi(ps.w);

    #define ADDQ(Q) \
        a0 += bf16_lo(Q.x); a1 += bf16_hi(Q.x); a2 += bf16_lo(Q.y); a3 += bf16_hi(Q.y); \
        a4 += bf16_lo(Q.z); a5 += bf16_hi(Q.z); a6 += bf16_lo(Q.w); a7 += bf16_hi(Q.w);

    int i = 0;
    for (; i + 4 <= n; i += 4) {
        int r0 = csr[o + i + 0];
        int r1 = csr[o + i + 1];
        int r2 = csr[o + i + 2];
        int r3 = csr[o + i + 3];
        uint4 q0 = hsv[(size_t)r0 * 4 + l2];
        uint4 q1 = hsv[(size_t)r1 * 4 + l2];
        uint4 q2 = hsv[(size_t)r2 * 4 + l2];
        uint4 q3 = hsv[(size_t)r3 * 4 + l2];
        ADDQ(q0) ADDQ(q1) ADDQ(q2) ADDQ(q3)
    }
    for (; i < n; i++) {
        uint4 q = hsv[(size_t)csr[o + i] * 4 + l2];
        ADDQ(q)
    }
    #undef ADDQ

    float di = dinv[node];
    float4 b1lo = *(const float4*)(b1 + 8 * l2);
    float4 b1hi = *(const float4*)(b1 + 8 * l2 + 4);
    float act[8];
    act[0] = fmaxf(b1lo.x + a0 * di, 0.f);
    act[1] = fmaxf(b1lo.y + a1 * di, 0.f);
    act[2] = fmaxf(b1lo.z + a2 * di, 0.f);
    act[3] = fmaxf(b1lo.w + a3 * di, 0.f);
    act[4] = fmaxf(b1hi.x + a4 * di, 0.f);
    act[5] = fmaxf(b1hi.y + a5 * di, 0.f);
    act[6] = fmaxf(b1hi.z + a6 * di, 0.f);
    act[7] = fmaxf(b1hi.w + a7 * di, 0.f);

    float p[NCLS];
    #pragma unroll
    for (int c = 0; c < NCLS; c++) {
        float s = 0.f;
        #pragma unroll
        for (int k = 0; k < 8; k++) s = fmaf(act[k], W2s[(8 * l2 + k) * NCLS + c], s);
        p[c] = s;
    }

    #pragma unroll
    for (int d = 1; d < 4; d <<= 1) {
        #pragma unroll
        for (int c = 0; c < NCLS; c++) p[c] += __shfl_xor(p[c], d, 4);
    }

    #pragma unroll
    for (int c = 0; c < NCLS; c++) p[c] += b2s[c];
    float m = p[0];
    #pragma unroll
    for (int c = 1; c < NCLS; c++) m = fmaxf(m, p[c]);
    float se = 0.f;
    #pragma unroll
    for (int c = 0; c < NCLS; c++) se += expf(p[c] - m);
    float lse = m + logf(se);

    #pragma unroll
    for (int q = 0; q < 3; q++) {
        int c = l2 + 4 * q;
        if (c < NCLS) {
            float v = p[0];
            #pragma unroll
            for (int cc = 1; cc < NCLS; cc++) v = (c == cc) ? p[cc] : v;
            out[(size_t)node * NCLS + c] = v - lse;
        }
    }
}

// ---------------------------------------------------------------------------
extern "C" void kernel_launch(void* const* d_in, const int* in_sizes, int n_in,
                              void* d_out, int out_size, void* d_ws, size_t ws_size,
                              hipStream_t stream) {
    const float* feat = (const float*)d_in[0];
    const void*  ei   = d_in[1];
    const float* W1   = (const float*)d_in[2];
    const float* b1   = (const float*)d_in[3];
    const float* W2   = (const float*)d_in[4];
    const float* b2   = (const float*)d_in[5];
    float* out = (float*)d_out;

    char* ws = (char*)d_ws;
    int*      flag   = (int*)(ws + OFF_FLAG);
    int*      gcur   = (int*)(ws + OFF_GCUR);
    int*      bbase  = (int*)(ws + OFF_BB);
    unsigned* w1f    = (unsigned*)(ws + OFF_W1F);
    int*      cnt    = (int*)(ws + OFF_CNT);
    int*      off    = (int*)(ws + OFF_OFF);
    float*    dinv   = (float*)(ws + OFF_DINV);
    int*      csr    = (int*)(ws + OFF_CSR);
    unsigned* binned = (unsigned*)(ws + OFF_BIN);
    unsigned* hs16   = (unsigned*)(ws + OFF_HS);   // overlays binned after k_p2

    k_init<<<1, 1024, 0, stream>>>((const int*)ei, flag, gcur);
    k_w1frag<<<1, 256, 0, stream>>>(W1, w1f);
    k_scat<<<NBLK1, 1024, 0, stream>>>(ei, flag, gcur, binned);
    k_bscan<<<1, 1024, 0, stream>>>(gcur, bbase);
    k_p2<<<NBUCK, 512, 0, stream>>>(binned, gcur, bbase, cnt, off, dinv, csr);

    k_h<<<(N_NODES / 16 + 3) / 4, 256, 0, stream>>>(feat, w1f, dinv,
                                                    (unsigned short*)hs16);
    k_aggout<<<(N_NODES + 63) / 64, 256, 0, stream>>>(off, cnt, csr, hs16, dinv,
                                                      b1, W2, b2, out);
}

// Round 17
// 122.846 us; speedup vs baseline: 5.0710x; 1.0818x over previous
//
#include <hip/hip_runtime.h>
#include <hip/hip_fp16.h>

constexpr int N_NODES = 100000;
constexpr int E_EDGES = 3200000;
constexpr int F_IN    = 256;
constexpr int HID     = 32;
constexpr int NCLS    = 10;

// bucketing: bucket = col >> 7  (128 target nodes per bucket)
constexpr int BUCK_SHIFT = 7;
constexpr int NPB        = 128;                          // nodes per bucket
constexpr int NBUCK      = (N_NODES + NPB - 1) / NPB;    // 782
constexpr int EPB        = 8192;                         // edges per scat block
constexpr int NBLK1      = (E_EDGES + EPB - 1) / EPB;    // 391
constexpr int CAP        = 6144;   // fixed bucket capacity (mean 4092, sigma 64)

// ---------------- ws layout (byte offsets) ----------------
constexpr size_t OFF_FLAG = 0;
constexpr size_t OFF_GCUR = 4u << 10;    // 782 ints
constexpr size_t OFF_BB   = 8u << 10;    // 783 ints dense bucket bases
constexpr size_t OFF_W1F  = 32u << 10;   // 16 KB fragment-ordered bf16 W1
constexpr size_t OFF_CNT  = 4u << 20;
constexpr size_t OFF_OFF  = 5u << 20;
constexpr size_t OFF_DINV = 6u << 20;
constexpr size_t OFF_CSR  = 7u << 20;    // dense, 12.8 MB
constexpr size_t OFF_BIN  = 20u << 20;   // sparse segments, 782*6144*4 = 19.2 MB
constexpr size_t OFF_HS   = 20u << 20;   // fp16 h*dinv, overlays binned after k_p2

typedef __attribute__((ext_vector_type(8))) short bf16x8;
typedef __attribute__((ext_vector_type(4))) float f32x4;

// bf16 helpers (RNE) -- used for the MFMA W1/A fragments only
__device__ __forceinline__ unsigned pack_bf16x2(float a, float b) {
    unsigned ua = __float_as_uint(a), ub = __float_as_uint(b);
    ua = (ua + 0x7FFFu + ((ua >> 16) & 1u)) >> 16;
    ub = (ub + 0x7FFFu + ((ub >> 16) & 1u)) >> 16;
    return ua | (ub << 16);
}
__device__ __forceinline__ __half2 u2h(unsigned u) {
    union { unsigned u; __half2 h; } v; v.u = u; return v.h;
}

__device__ __forceinline__ int load_idx(const void* ei, long long i, int is64) {
    if (is64) return (int)((const long long*)ei)[i];
    return ((const int*)ei)[i];
}

// ---------------------------------------------------------------------------
// init (merged round 16->17): dtype detect + gcur init + W1 -> bf16 MFMA
// B-fragment layout (one launch instead of two).
// ---------------------------------------------------------------------------
__global__ __launch_bounds__(1024) void k_initw(const int* __restrict__ ei32,
                                                int* __restrict__ flag,
                                                int* __restrict__ gcur,
                                                const float* __restrict__ W1,
                                                unsigned* __restrict__ w1f) {
    __shared__ int nz;
    int tid = threadIdx.x;
    if (tid == 0) nz = 0;
    __syncthreads();
    if (ei32[2 * tid + 1] != 0) atomicOr(&nz, 1);
    __syncthreads();
    if (tid == 0) flag[0] = (nz == 0) ? 1 : 0;   // 1 => int64 storage
    if (tid < NBUCK) gcur[tid] = tid * CAP;

    #pragma unroll
    for (int q = 0; q < 4; q++) {
        int i = tid + q * 1024;                  // 4096 u32 entries
        int p    = i & 3;
        int lane = (i >> 2) & 63;
        int f    = i >> 8;
        int ks = f >> 1, t = f & 1;
        int kg = lane >> 4, col = lane & 15;
        int k0 = ks * 32 + kg * 8 + p * 2;
        float w0 = W1[k0 * HID + t * 16 + col];
        float w1 = W1[(k0 + 1) * HID + t * 16 + col];
        w1f[i] = pack_bf16x2(w0, w1);
    }
}

// ---------------------------------------------------------------------------
// ONE-PASS bucketed scatter (EPB 8192, fixed-capacity segments, LDS cursors).
// ---------------------------------------------------------------------------
__global__ __launch_bounds__(1024) void k_scat(const void* __restrict__ ei,
                                               const int* __restrict__ flag,
                                               int* __restrict__ gcur,
                                               unsigned* __restrict__ binned) {
    __shared__ unsigned       sval[EPB];     // 32 KB packed (r<<7 | c&127)
    __shared__ unsigned short sbuck[EPB];    // 16 KB bucket ids
    __shared__ int h[NBUCK];                 // 3.1 KB
    __shared__ int cur[NBUCK];               // 3.1 KB
    int tid = threadIdx.x, blk = blockIdx.x;
    for (int i = tid; i < NBUCK; i += 1024) h[i] = 0;
    __syncthreads();

    int is64 = flag[0];
    int base = blk * EPB;
    int nedge = min(EPB, E_EDGES - base);
    for (int k = tid; k < nedge; k += 1024) {
        int i = base + k;
        int r = load_idx(ei, i, is64);
        int c = load_idx(ei, (long long)E_EDGES + i, is64);
        int b = c >> BUCK_SHIFT;
        sval[k]  = ((unsigned)r << BUCK_SHIFT) | ((unsigned)c & (NPB - 1));
        sbuck[k] = (unsigned short)b;
        atomicAdd(&h[b], 1);
    }
    __syncthreads();

    for (int j = tid; j < NBUCK; j += 1024) {
        int c = h[j];
        cur[j] = (c > 0) ? atomicAdd(&gcur[j], c) : 0;
    }
    __syncthreads();

    for (int k = tid; k < nedge; k += 1024) {
        int d = atomicAdd(&cur[sbuck[k]], 1);
        binned[d] = sval[k];
    }
}

// dense exclusive scan of final bucket counts (gcur[b] - b*CAP) -> bucketBase
__global__ __launch_bounds__(1024) void k_bscan(const int* __restrict__ gcur,
                                                int* __restrict__ bucketBase) {
    __shared__ int s[1024];
    int tid = threadIdx.x;
    int v = (tid < NBUCK) ? (gcur[tid] - tid * CAP) : 0;
    s[tid] = v;
    __syncthreads();
    for (int d = 1; d < 1024; d <<= 1) {
        int t = (tid >= d) ? s[tid - d] : 0;
        __syncthreads();
        s[tid] += t;
        __syncthreads();
    }
    if (tid < NBUCK) bucketBase[tid] = s[tid] - v;
    if (tid == 1023) bucketBase[NBUCK] = s[1023];   // = E_EDGES
}

// ---------------------------------------------------------------------------
// pass 2: per bucket (128 nodes) counting-sort sparse binned segment ->
// dense csr; emits cnt/off/dinv.
// ---------------------------------------------------------------------------
__global__ __launch_bounds__(512) void k_p2(const unsigned* __restrict__ binned,
                                            const int* __restrict__ gcur,
                                            const int* __restrict__ bucketBase,
                                            int* __restrict__ cnt,
                                            int* __restrict__ off,
                                            float* __restrict__ dinv,
                                            int* __restrict__ csr) {
    __shared__ int lcnt[NPB], sc[NPB], lcur[NPB];
    int b = blockIdx.x, tid = threadIdx.x;
    int s = b * CAP, e = gcur[b];        // sparse segment
    int db = bucketBase[b];              // dense base
    if (tid < NPB) lcnt[tid] = 0;
    __syncthreads();
    for (int i = s + tid; i < e; i += 512)
        atomicAdd(&lcnt[binned[i] & (NPB - 1)], 1);
    __syncthreads();
    if (tid < NPB) sc[tid] = lcnt[tid];
    __syncthreads();
    for (int d = 1; d < NPB; d <<= 1) {
        int t = 0;
        if (tid < NPB && tid >= d) t = sc[tid - d];
        __syncthreads();
        if (tid < NPB) sc[tid] += t;
        __syncthreads();
    }
    if (tid < NPB) {
        int o = db + sc[tid] - lcnt[tid];     // dense exclusive
        lcur[tid] = o;
        int node = b * NPB + tid;
        if (node < N_NODES) {
            off[node]  = o;
            cnt[node]  = lcnt[tid];
            dinv[node] = rsqrtf((float)lcnt[tid] + 1.0f);   // +1 self-loop
        }
    }
    __syncthreads();
    for (int i = s + tid; i < e; i += 512) {
        unsigned p = binned[i];
        int pos = atomicAdd(&lcur[p & (NPB - 1)], 1);
        csr[pos] = (int)(p >> BUCK_SHIFT);
    }
}

// ---------------------------------------------------------------------------
// h = feature @ W1 via MFMA bf16; hs = FP16(h * dinv_row), ushort [node][32].
// Round 16->17: output fp16 (packed-add consumable downstream).
// ---------------------------------------------------------------------------
__global__ __launch_bounds__(256) void k_h(const float* __restrict__ feat,
                                           const unsigned* __restrict__ w1f,
                                           const float* __restrict__ dinv,
                                           unsigned short* __restrict__ hs16s) {
    int tid  = threadIdx.x;
    int lane = tid & 63;
    long wid = (long)blockIdx.x * 4 + (tid >> 6);
    int n0 = (int)(wid * 16);
    if (n0 >= N_NODES) return;

    bf16x8 bfrag[16];
    const bf16x8* wv = (const bf16x8*)w1f;
    #pragma unroll
    for (int f = 0; f < 16; f++) bfrag[f] = wv[f * 64 + lane];

    int arow = lane & 15;
    int kg   = lane >> 4;
    const float4* fr = (const float4*)(feat + (size_t)(n0 + arow) * F_IN);

    f32x4 acc0 = {0.f, 0.f, 0.f, 0.f};
    f32x4 acc1 = {0.f, 0.f, 0.f, 0.f};

    #pragma unroll
    for (int ks = 0; ks < 8; ks++) {
        float4 fa = fr[ks * 8 + kg * 2 + 0];
        float4 fb = fr[ks * 8 + kg * 2 + 1];
        unsigned au[4];
        au[0] = pack_bf16x2(fa.x, fa.y);
        au[1] = pack_bf16x2(fa.z, fa.w);
        au[2] = pack_bf16x2(fb.x, fb.y);
        au[3] = pack_bf16x2(fb.z, fb.w);
        bf16x8 af = *(bf16x8*)au;
        acc0 = __builtin_amdgcn_mfma_f32_16x16x32_bf16(af, bfrag[ks * 2 + 0], acc0, 0, 0, 0);
        acc1 = __builtin_amdgcn_mfma_f32_16x16x32_bf16(af, bfrag[ks * 2 + 1], acc1, 0, 0, 0);
    }

    int rb = kg * 4;
    #pragma unroll
    for (int r = 0; r < 4; r++) {
        int node = n0 + rb + r;
        float di = dinv[node];
        hs16s[(size_t)node * HID + arow]      = __half_as_ushort(__float2half(acc0[r] * di));
        hs16s[(size_t)node * HID + 16 + arow] = __half_as_ushort(__float2half(acc1[r] * di));
    }
}

// ---------------------------------------------------------------------------
// FUSED agg + relu + W2 matvec + log_softmax.
// Round 16->17: fp16 hs + packed v_pk_add_f16 accumulation (4 VALU per
// gathered uint4 instead of 16: no unpacking in the loop) + 8-deep unroll
// (128 B in flight per lane). 4 lanes per node; 64 nodes per block.
// ---------------------------------------------------------------------------
__global__ __launch_bounds__(256) void k_aggout(const int* __restrict__ off,
                                                const int* __restrict__ cnt,
                                                const int* __restrict__ csr,
                                                const unsigned* __restrict__ hs16,
                                                const float* __restrict__ dinv,
                                                const float* __restrict__ b1,
                                                const float* __restrict__ W2,
                                                const float* __restrict__ b2,
                                                float* __restrict__ out) {
    __shared__ float W2s[HID * NCLS];   // [k][c]
    __shared__ float b2s[NCLS];
    int tid = threadIdx.x;
    for (int i = tid; i < HID * NCLS; i += 256) W2s[i] = W2[i];
    if (tid < NCLS) b2s[tid] = b2[tid];
    __syncthreads();

    int l2   = tid & 3;                  // quarter-row: hid 8*l2 .. 8*l2+7
    int g    = tid >> 2;                 // 0..63
    int node = blockIdx.x * 64 + g;
    if (node >= N_NODES) return;

    int o = off[node];
    int n = cnt[node];

    const uint4* hsv = (const uint4*)hs16;     // row = 4 uint4
    uint4 ps = hsv[(size_t)node * 4 + l2];     // self-loop term
    __half2 s0 = u2h(ps.x), s1 = u2h(ps.y), s2 = u2h(ps.z), s3 = u2h(ps.w);

    #define ADDQ(Q) \
        s0 = __hadd2(s0, u2h(Q.x)); s1 = __hadd2(s1, u2h(Q.y)); \
        s2 = __hadd2(s2, u2h(Q.z)); s3 = __hadd2(s3, u2h(Q.w));

    int i = 0;
    for (; i + 8 <= n; i += 8) {
        int r0 = csr[o + i + 0];
        int r1 = csr[o + i + 1];
        int r2 = csr[o + i + 2];
        int r3 = csr[o + i + 3];
        int r4 = csr[o + i + 4];
        int r5 = csr[o + i + 5];
        int r6 = csr[o + i + 6];
        int r7 = csr[o + i + 7];
        uint4 q0 = hsv[(size_t)r0 * 4 + l2];
        uint4 q1 = hsv[(size_t)r1 * 4 + l2];
        uint4 q2 = hsv[(size_t)r2 * 4 + l2];
        uint4 q3 = hsv[(size_t)r3 * 4 + l2];
        uint4 q4 = hsv[(size_t)r4 * 4 + l2];
        uint4 q5 = hsv[(size_t)r5 * 4 + l2];
        uint4 q6 = hsv[(size_t)r6 * 4 + l2];
        uint4 q7 = hsv[(size_t)r7 * 4 + l2];
        ADDQ(q0) ADDQ(q1) ADDQ(q2) ADDQ(q3)
        ADDQ(q4) ADDQ(q5) ADDQ(q6) ADDQ(q7)
    }
    for (; i < n; i++) {
        uint4 q = hsv[(size_t)csr[o + i] * 4 + l2];
        ADDQ(q)
    }
    #undef ADDQ

    float2 f0 = __half22float2(s0);
    float2 f1 = __half22float2(s1);
    float2 f2 = __half22float2(s2);
    float2 f3 = __half22float2(s3);

    float di = dinv[node];
    float4 b1lo = *(const float4*)(b1 + 8 * l2);
    float4 b1hi = *(const float4*)(b1 + 8 * l2 + 4);
    float act[8];
    act[0] = fmaxf(b1lo.x + f0.x * di, 0.f);
    act[1] = fmaxf(b1lo.y + f0.y * di, 0.f);
    act[2] = fmaxf(b1lo.z + f1.x * di, 0.f);
    act[3] = fmaxf(b1lo.w + f1.y * di, 0.f);
    act[4] = fmaxf(b1hi.x + f2.x * di, 0.f);
    act[5] = fmaxf(b1hi.y + f2.y * di, 0.f);
    act[6] = fmaxf(b1hi.z + f3.x * di, 0.f);
    act[7] = fmaxf(b1hi.w + f3.y * di, 0.f);

    float p[NCLS];
    #pragma unroll
    for (int c = 0; c < NCLS; c++) {
        float s = 0.f;
        #pragma unroll
        for (int k = 0; k < 8; k++) s = fmaf(act[k], W2s[(8 * l2 + k) * NCLS + c], s);
        p[c] = s;
    }

    #pragma unroll
    for (int d = 1; d < 4; d <<= 1) {
        #pragma unroll
        for (int c = 0; c < NCLS; c++) p[c] += __shfl_xor(p[c], d, 4);
    }

    #pragma unroll
    for (int c = 0; c < NCLS; c++) p[c] += b2s[c];
    float m = p[0];
    #pragma unroll
    for (int c = 1; c < NCLS; c++) m = fmaxf(m, p[c]);
    float se = 0.f;
    #pragma unroll
    for (int c = 0; c < NCLS; c++) se += expf(p[c] - m);
    float lse = m + logf(se);

    #pragma unroll
    for (int q = 0; q < 3; q++) {
        int c = l2 + 4 * q;
        if (c < NCLS) {
            float v = p[0];
            #pragma unroll
            for (int cc = 1; cc < NCLS; cc++) v = (c == cc) ? p[cc] : v;
            out[(size_t)node * NCLS + c] = v - lse;
        }
    }
}

// ---------------------------------------------------------------------------
extern "C" void kernel_launch(void* const* d_in, const int* in_sizes, int n_in,
                              void* d_out, int out_size, void* d_ws, size_t ws_size,
                              hipStream_t stream) {
    const float* feat = (const float*)d_in[0];
    const void*  ei   = d_in[1];
    const float* W1   = (const float*)d_in[2];
    const float* b1   = (const float*)d_in[3];
    const float* W2   = (const float*)d_in[4];
    const float* b2   = (const float*)d_in[5];
    float* out = (float*)d_out;

    char* ws = (char*)d_ws;
    int*      flag   = (int*)(ws + OFF_FLAG);
    int*      gcur   = (int*)(ws + OFF_GCUR);
    int*      bbase  = (int*)(ws + OFF_BB);
    unsigned* w1f    = (unsigned*)(ws + OFF_W1F);
    int*      cnt    = (int*)(ws + OFF_CNT);
    int*      off    = (int*)(ws + OFF_OFF);
    float*    dinv   = (float*)(ws + OFF_DINV);
    int*      csr    = (int*)(ws + OFF_CSR);
    unsigned* binned = (unsigned*)(ws + OFF_BIN);
    unsigned* hs16   = (unsigned*)(ws + OFF_HS);   // overlays binned after k_p2

    k_initw<<<1, 1024, 0, stream>>>((const int*)ei, flag, gcur, W1, w1f);
    k_scat<<<NBLK1, 1024, 0, stream>>>(ei, flag, gcur, binned);
    k_bscan<<<1, 1024, 0, stream>>>(gcur, bbase);
    k_p2<<<NBUCK, 512, 0, stream>>>(binned, gcur, bbase, cnt, off, dinv, csr);

    k_h<<<(N_NODES / 16 + 3) / 4, 256, 0, stream>>>(feat, w1f, dinv,
                                                    (unsigned short*)hs16);
    k_aggout<<<(N_NODES + 63) / 64, 256, 0, stream>>>(off, cnt, csr, hs16, dinv,
                                                      b1, W2, b2, out);
}

// Round 18
// 119.597 us; speedup vs baseline: 5.2088x; 1.0272x over previous
//
#include <hip/hip_runtime.h>
#include <hip/hip_fp16.h>

constexpr int N_NODES = 100000;
constexpr int E_EDGES = 3200000;
constexpr int F_IN    = 256;
constexpr int HID     = 32;
constexpr int NCLS    = 10;

// bucketing: bucket = col >> 7  (128 target nodes per bucket)
constexpr int BUCK_SHIFT = 7;
constexpr int NPB        = 128;                          // nodes per bucket
constexpr int NBUCK      = (N_NODES + NPB - 1) / NPB;    // 782
constexpr int EPB        = 8192;                         // edges per scat block
constexpr int NBLK1      = (E_EDGES + EPB - 1) / EPB;    // 391
constexpr int CAP        = 6144;   // fixed bucket capacity (mean 4092, sigma 64)

// ---------------- ws layout (byte offsets) ----------------
// Round 17->18: csr is now SPARSE (per-bucket segments at b*CAP, 19.2 MB);
// bucketBase/k_bscan deleted. binned at 23MB (19.2 MB); hs16 overlays binned.
constexpr size_t OFF_FLAG = 0;
constexpr size_t OFF_GCUR = 4u << 10;    // 782 ints
constexpr size_t OFF_W1F  = 32u << 10;   // 16 KB fragment-ordered bf16 W1
constexpr size_t OFF_CNT  = 1u << 20;
constexpr size_t OFF_OFF  = 3u << 20;    // 1.5MB gap unused, fine
constexpr size_t OFF_DINV = 4u << 20;
constexpr size_t OFF_CSR  = 5u << 20;    // sparse, 782*6144*4 = 19.2 MB -> ends 24.2MB
constexpr size_t OFF_BIN  = 25u << 20;   // sparse, 19.2 MB -> ends 44.2MB
constexpr size_t OFF_HS   = 25u << 20;   // fp16 h*dinv, overlays binned after k_p2

typedef __attribute__((ext_vector_type(8))) short bf16x8;
typedef __attribute__((ext_vector_type(4))) float f32x4;

// bf16 helpers (RNE) -- used for the MFMA W1/A fragments only
__device__ __forceinline__ unsigned pack_bf16x2(float a, float b) {
    unsigned ua = __float_as_uint(a), ub = __float_as_uint(b);
    ua = (ua + 0x7FFFu + ((ua >> 16) & 1u)) >> 16;
    ub = (ub + 0x7FFFu + ((ub >> 16) & 1u)) >> 16;
    return ua | (ub << 16);
}
__device__ __forceinline__ __half2 u2h(unsigned u) {
    union { unsigned u; __half2 h; } v; v.u = u; return v.h;
}

__device__ __forceinline__ int load_idx(const void* ei, long long i, int is64) {
    if (is64) return (int)((const long long*)ei)[i];
    return ((const int*)ei)[i];
}

// ---------------------------------------------------------------------------
// init: dtype detect + gcur init + W1 -> bf16 MFMA B-fragment layout.
// ---------------------------------------------------------------------------
__global__ __launch_bounds__(1024) void k_initw(const int* __restrict__ ei32,
                                                int* __restrict__ flag,
                                                int* __restrict__ gcur,
                                                const float* __restrict__ W1,
                                                unsigned* __restrict__ w1f) {
    __shared__ int nz;
    int tid = threadIdx.x;
    if (tid == 0) nz = 0;
    __syncthreads();
    if (ei32[2 * tid + 1] != 0) atomicOr(&nz, 1);
    __syncthreads();
    if (tid == 0) flag[0] = (nz == 0) ? 1 : 0;   // 1 => int64 storage
    if (tid < NBUCK) gcur[tid] = tid * CAP;

    #pragma unroll
    for (int q = 0; q < 4; q++) {
        int i = tid + q * 1024;                  // 4096 u32 entries
        int p    = i & 3;
        int lane = (i >> 2) & 63;
        int f    = i >> 8;
        int ks = f >> 1, t = f & 1;
        int kg = lane >> 4, col = lane & 15;
        int k0 = ks * 32 + kg * 8 + p * 2;
        float w0 = W1[k0 * HID + t * 16 + col];
        float w1 = W1[(k0 + 1) * HID + t * 16 + col];
        w1f[i] = pack_bf16x2(w0, w1);
    }
}

// ---------------------------------------------------------------------------
// ONE-PASS bucketed scatter (EPB 8192, fixed-capacity segments, LDS cursors).
// ---------------------------------------------------------------------------
__global__ __launch_bounds__(1024) void k_scat(const void* __restrict__ ei,
                                               const int* __restrict__ flag,
                                               int* __restrict__ gcur,
                                               unsigned* __restrict__ binned) {
    __shared__ unsigned       sval[EPB];     // 32 KB packed (r<<7 | c&127)
    __shared__ unsigned short sbuck[EPB];    // 16 KB bucket ids
    __shared__ int h[NBUCK];                 // 3.1 KB
    __shared__ int cur[NBUCK];               // 3.1 KB
    int tid = threadIdx.x, blk = blockIdx.x;
    for (int i = tid; i < NBUCK; i += 1024) h[i] = 0;
    __syncthreads();

    int is64 = flag[0];
    int base = blk * EPB;
    int nedge = min(EPB, E_EDGES - base);
    for (int k = tid; k < nedge; k += 1024) {
        int i = base + k;
        int r = load_idx(ei, i, is64);
        int c = load_idx(ei, (long long)E_EDGES + i, is64);
        int b = c >> BUCK_SHIFT;
        sval[k]  = ((unsigned)r << BUCK_SHIFT) | ((unsigned)c & (NPB - 1));
        sbuck[k] = (unsigned short)b;
        atomicAdd(&h[b], 1);
    }
    __syncthreads();

    for (int j = tid; j < NBUCK; j += 1024) {
        int c = h[j];
        cur[j] = (c > 0) ? atomicAdd(&gcur[j], c) : 0;
    }
    __syncthreads();

    for (int k = tid; k < nedge; k += 1024) {
        int d = atomicAdd(&cur[sbuck[k]], 1);
        binned[d] = sval[k];
    }
}

// ---------------------------------------------------------------------------
// pass 2 (round 17->18): stage segment in LDS ONCE (was 2 global passes),
// counting-sort to SPARSE csr at b*CAP (dense base / k_bscan deleted).
// Emits cnt/off/dinv. 1024 threads.
// ---------------------------------------------------------------------------
__global__ __launch_bounds__(1024) void k_p2(const unsigned* __restrict__ binned,
                                             const int* __restrict__ gcur,
                                             int* __restrict__ cnt,
                                             int* __restrict__ off,
                                             float* __restrict__ dinv,
                                             int* __restrict__ csr) {
    __shared__ unsigned sval[CAP];           // 24.6 KB staged segment
    __shared__ int lcnt[NPB], sc[NPB], lcur[NPB];
    int b = blockIdx.x, tid = threadIdx.x;
    int s = b * CAP;
    int m = gcur[b] - s;                     // entries in this bucket
    if (tid < NPB) lcnt[tid] = 0;
    __syncthreads();
    for (int i = tid; i < m; i += 1024) {
        unsigned p = binned[s + i];
        sval[i] = p;
        atomicAdd(&lcnt[p & (NPB - 1)], 1);
    }
    __syncthreads();
    if (tid < NPB) sc[tid] = lcnt[tid];
    __syncthreads();
    for (int d = 1; d < NPB; d <<= 1) {
        int t = 0;
        if (tid < NPB && tid >= d) t = sc[tid - d];
        __syncthreads();
        if (tid < NPB) sc[tid] += t;
        __syncthreads();
    }
    if (tid < NPB) {
        int o = s + sc[tid] - lcnt[tid];     // sparse exclusive position
        lcur[tid] = o;
        int node = b * NPB + tid;
        if (node < N_NODES) {
            off[node]  = o;
            cnt[node]  = lcnt[tid];
            dinv[node] = rsqrtf((float)lcnt[tid] + 1.0f);   // +1 self-loop
        }
    }
    __syncthreads();
    for (int i = tid; i < m; i += 1024) {
        unsigned p = sval[i];
        int pos = atomicAdd(&lcur[p & (NPB - 1)], 1);
        csr[pos] = (int)(p >> BUCK_SHIFT);
    }
}

// ---------------------------------------------------------------------------
// h = feature @ W1 via MFMA bf16; hs = FP16(h * dinv_row), ushort [node][32].
// One wave per 16-node batch; no LDS.
// ---------------------------------------------------------------------------
__global__ __launch_bounds__(256) void k_h(const float* __restrict__ feat,
                                           const unsigned* __restrict__ w1f,
                                           const float* __restrict__ dinv,
                                           unsigned short* __restrict__ hs16s) {
    int tid  = threadIdx.x;
    int lane = tid & 63;
    long wid = (long)blockIdx.x * 4 + (tid >> 6);
    int n0 = (int)(wid * 16);
    if (n0 >= N_NODES) return;

    bf16x8 bfrag[16];
    const bf16x8* wv = (const bf16x8*)w1f;
    #pragma unroll
    for (int f = 0; f < 16; f++) bfrag[f] = wv[f * 64 + lane];

    int arow = lane & 15;
    int kg   = lane >> 4;
    const float4* fr = (const float4*)(feat + (size_t)(n0 + arow) * F_IN);

    f32x4 acc0 = {0.f, 0.f, 0.f, 0.f};
    f32x4 acc1 = {0.f, 0.f, 0.f, 0.f};

    #pragma unroll
    for (int ks = 0; ks < 8; ks++) {
        float4 fa = fr[ks * 8 + kg * 2 + 0];
        float4 fb = fr[ks * 8 + kg * 2 + 1];
        unsigned au[4];
        au[0] = pack_bf16x2(fa.x, fa.y);
        au[1] = pack_bf16x2(fa.z, fa.w);
        au[2] = pack_bf16x2(fb.x, fb.y);
        au[3] = pack_bf16x2(fb.z, fb.w);
        bf16x8 af = *(bf16x8*)au;
        acc0 = __builtin_amdgcn_mfma_f32_16x16x32_bf16(af, bfrag[ks * 2 + 0], acc0, 0, 0, 0);
        acc1 = __builtin_amdgcn_mfma_f32_16x16x32_bf16(af, bfrag[ks * 2 + 1], acc1, 0, 0, 0);
    }

    int rb = kg * 4;
    #pragma unroll
    for (int r = 0; r < 4; r++) {
        int node = n0 + rb + r;
        float di = dinv[node];
        hs16s[(size_t)node * HID + arow]      = __half_as_ushort(__float2half(acc0[r] * di));
        hs16s[(size_t)node * HID + 16 + arow] = __half_as_ushort(__float2half(acc1[r] * di));
    }
}

// ---------------------------------------------------------------------------
// FUSED agg + relu + W2 matvec + log_softmax. fp16 hs + packed v_pk_add_f16,
// 8-deep unroll, 4 lanes per node; 64 nodes per block.
// ---------------------------------------------------------------------------
__global__ __launch_bounds__(256) void k_aggout(const int* __restrict__ off,
                                                const int* __restrict__ cnt,
                                                const int* __restrict__ csr,
                                                const unsigned* __restrict__ hs16,
                                                const float* __restrict__ dinv,
                                                const float* __restrict__ b1,
                                                const float* __restrict__ W2,
                                                const float* __restrict__ b2,
                                                float* __restrict__ out) {
    __shared__ float W2s[HID * NCLS];   // [k][c]
    __shared__ float b2s[NCLS];
    int tid = threadIdx.x;
    for (int i = tid; i < HID * NCLS; i += 256) W2s[i] = W2[i];
    if (tid < NCLS) b2s[tid] = b2[tid];
    __syncthreads();

    int l2   = tid & 3;                  // quarter-row: hid 8*l2 .. 8*l2+7
    int g    = tid >> 2;                 // 0..63
    int node = blockIdx.x * 64 + g;
    if (node >= N_NODES) return;

    int o = off[node];
    int n = cnt[node];

    const uint4* hsv = (const uint4*)hs16;     // row = 4 uint4
    uint4 ps = hsv[(size_t)node * 4 + l2];     // self-loop term
    __half2 s0 = u2h(ps.x), s1 = u2h(ps.y), s2 = u2h(ps.z), s3 = u2h(ps.w);

    #define ADDQ(Q) \
        s0 = __hadd2(s0, u2h(Q.x)); s1 = __hadd2(s1, u2h(Q.y)); \
        s2 = __hadd2(s2, u2h(Q.z)); s3 = __hadd2(s3, u2h(Q.w));

    int i = 0;
    for (; i + 8 <= n; i += 8) {
        int r0 = csr[o + i + 0];
        int r1 = csr[o + i + 1];
        int r2 = csr[o + i + 2];
        int r3 = csr[o + i + 3];
        int r4 = csr[o + i + 4];
        int r5 = csr[o + i + 5];
        int r6 = csr[o + i + 6];
        int r7 = csr[o + i + 7];
        uint4 q0 = hsv[(size_t)r0 * 4 + l2];
        uint4 q1 = hsv[(size_t)r1 * 4 + l2];
        uint4 q2 = hsv[(size_t)r2 * 4 + l2];
        uint4 q3 = hsv[(size_t)r3 * 4 + l2];
        uint4 q4 = hsv[(size_t)r4 * 4 + l2];
        uint4 q5 = hsv[(size_t)r5 * 4 + l2];
        uint4 q6 = hsv[(size_t)r6 * 4 + l2];
        uint4 q7 = hsv[(size_t)r7 * 4 + l2];
        ADDQ(q0) ADDQ(q1) ADDQ(q2) ADDQ(q3)
        ADDQ(q4) ADDQ(q5) ADDQ(q6) ADDQ(q7)
    }
    for (; i < n; i++) {
        uint4 q = hsv[(size_t)csr[o + i] * 4 + l2];
        ADDQ(q)
    }
    #undef ADDQ

    float2 f0 = __half22float2(s0);
    float2 f1 = __half22float2(s1);
    float2 f2 = __half22float2(s2);
    float2 f3 = __half22float2(s3);

    float di = dinv[node];
    float4 b1lo = *(const float4*)(b1 + 8 * l2);
    float4 b1hi = *(const float4*)(b1 + 8 * l2 + 4);
    float act[8];
    act[0] = fmaxf(b1lo.x + f0.x * di, 0.f);
    act[1] = fmaxf(b1lo.y + f0.y * di, 0.f);
    act[2] = fmaxf(b1lo.z + f1.x * di, 0.f);
    act[3] = fmaxf(b1lo.w + f1.y * di, 0.f);
    act[4] = fmaxf(b1hi.x + f2.x * di, 0.f);
    act[5] = fmaxf(b1hi.y + f2.y * di, 0.f);
    act[6] = fmaxf(b1hi.z + f3.x * di, 0.f);
    act[7] = fmaxf(b1hi.w + f3.y * di, 0.f);

    float p[NCLS];
    #pragma unroll
    for (int c = 0; c < NCLS; c++) {
        float s = 0.f;
        #pragma unroll
        for (int k = 0; k < 8; k++) s = fmaf(act[k], W2s[(8 * l2 + k) * NCLS + c], s);
        p[c] = s;
    }

    #pragma unroll
    for (int d = 1; d < 4; d <<= 1) {
        #pragma unroll
        for (int c = 0; c < NCLS; c++) p[c] += __shfl_xor(p[c], d, 4);
    }

    #pragma unroll
    for (int c = 0; c < NCLS; c++) p[c] += b2s[c];
    float m = p[0];
    #pragma unroll
    for (int c = 1; c < NCLS; c++) m = fmaxf(m, p[c]);
    float se = 0.f;
    #pragma unroll
    for (int c = 0; c < NCLS; c++) se += expf(p[c] - m);
    float lse = m + logf(se);

    #pragma unroll
    for (int q = 0; q < 3; q++) {
        int c = l2 + 4 * q;
        if (c < NCLS) {
            float v = p[0];
            #pragma unroll
            for (int cc = 1; cc < NCLS; cc++) v = (c == cc) ? p[cc] : v;
            out[(size_t)node * NCLS + c] = v - lse;
        }
    }
}

// ---------------------------------------------------------------------------
extern "C" void kernel_launch(void* const* d_in, const int* in_sizes, int n_in,
                              void* d_out, int out_size, void* d_ws, size_t ws_size,
                              hipStream_t stream) {
    const float* feat = (const float*)d_in[0];
    const void*  ei   = d_in[1];
    const float* W1   = (const float*)d_in[2];
    const float* b1   = (const float*)d_in[3];
    const float* W2   = (const float*)d_in[4];
    const float* b2   = (const float*)d_in[5];
    float* out = (float*)d_out;

    char* ws = (char*)d_ws;
    int*      flag   = (int*)(ws + OFF_FLAG);
    int*      gcur   = (int*)(ws + OFF_GCUR);
    unsigned* w1f    = (unsigned*)(ws + OFF_W1F);
    int*      cnt    = (int*)(ws + OFF_CNT);
    int*      off    = (int*)(ws + OFF_OFF);
    float*    dinv   = (float*)(ws + OFF_DINV);
    int*      csr    = (int*)(ws + OFF_CSR);
    unsigned* binned = (unsigned*)(ws + OFF_BIN);
    unsigned* hs16   = (unsigned*)(ws + OFF_HS);   // overlays binned after k_p2

    k_initw<<<1, 1024, 0, stream>>>((const int*)ei, flag, gcur, W1, w1f);
    k_scat<<<NBLK1, 1024, 0, stream>>>(ei, flag, gcur, binned);
    k_p2<<<NBUCK, 1024, 0, stream>>>(binned, gcur, cnt, off, dinv, csr);

    k_h<<<(N_NODES / 16 + 3) / 4, 256, 0, stream>>>(feat, w1f, dinv,
                                                    (unsigned short*)hs16);
    k_aggout<<<(N_NODES + 63) / 64, 256, 0, stream>>>(off, cnt, csr, hs16, dinv,
                                                      b1, W2, b2, out);
}